// Round 1
// baseline (1483.675 us; speedup 1.0000x reference)
//
#include <hip/hip_runtime.h>

static __device__ __forceinline__ float lky(float x) { return x > 0.f ? x : 0.01f * x; }

constexpr int VC = 42;   // vmid split-K chunks

// ---------------- init ----------------
__global__ void k_init(float* t_max, int* cnt, int* cursor, float* colsum, int N) {
    int i = blockIdx.x * 256 + threadIdx.x;
    if (i < N) { t_max[i] = -1.0f; cnt[i] = 0; cursor[i] = 0; }
    if (i < 224) colsum[i] = 0.0f;
}

// ---------------- per-edge t_max / counts ----------------
__global__ void k_tmax_cnt(const int* __restrict__ src, const float* __restrict__ ts,
                           float* t_max, int* cnt, int E) {
    int e = blockIdx.x * 256 + threadIdx.x;
    if (e >= E) return;
    int s = src[e];
    atomicMax((int*)(t_max + s), __float_as_int(ts[e]));   // ts >= 0, int-monotone
    atomicAdd(cnt + s, 1);
}

// ---------------- exclusive scan over counts (single block) ----------------
__global__ __launch_bounds__(1024) void k_scan(const int* __restrict__ cnt,
                                               int* __restrict__ offsets, int N) {
    __shared__ int wsum[16];
    __shared__ int s_run;
    int t = threadIdx.x;
    int lane = t & 63, wid = t >> 6;
    if (t == 0) s_run = 0;
    __syncthreads();
    int nchunk = (N + 1023) >> 10;
    for (int c = 0; c < nchunk; ++c) {
        int i = (c << 10) + t;
        int v = (i < N) ? cnt[i] : 0;
        int x = v;
        #pragma unroll
        for (int d = 1; d < 64; d <<= 1) {
            int y = __shfl_up(x, d, 64);
            if (lane >= d) x += y;
        }
        if (lane == 63) wsum[wid] = x;
        __syncthreads();
        int wbase = 0;
        #pragma unroll
        for (int w = 0; w < 16; ++w) wbase += (w < wid) ? wsum[w] : 0;
        int run = s_run;
        if (i < N) offsets[i] = run + wbase + x - v;
        __syncthreads();
        if (t == 1023) s_run = run + wbase + x;
        __syncthreads();
    }
    if (t == 0) offsets[N] = s_run;
}

// ---------------- scatter edges into per-node buckets ----------------
__global__ void k_scatter(const int* __restrict__ src, const int* __restrict__ offsets,
                          int* cursor, int* sorted, int E) {
    int e = blockIdx.x * 256 + threadIdx.x;
    if (e >= E) return;
    int s = src[e];
    int pos = offsets[s] + atomicAdd(cursor + s, 1);
    sorted[pos] = e;
}

// ---------------- per-node aggregation: one wave per node ----------------
__global__ __launch_bounds__(256) void k_agg(
        const int* __restrict__ tgt, const float* __restrict__ ts,
        const int* __restrict__ sorted, const int* __restrict__ offsets,
        const float* __restrict__ t_max, const float* __restrict__ memory,
        const float* __restrict__ nodef, const float* __restrict__ lambs,
        float* __restrict__ agg, float* __restrict__ cnt3, int* __restrict__ has_msg, int N) {
    int wid = threadIdx.x >> 6, lane = threadIdx.x & 63;
    int n = blockIdx.x * 4 + wid;
    if (n >= N) return;
    int beg = offsets[n], end = offsets[n + 1];
    float lb0 = lambs[0], lb1 = lambs[1], lb2 = lambs[2];
    float tm = t_max[n];
    float acc[3][4];
    float accc[3];
    #pragma unroll
    for (int l = 0; l < 3; ++l) {
        accc[l] = 0.f;
        #pragma unroll
        for (int k = 0; k < 4; ++k) acc[l][k] = 0.f;
    }
    for (int idx = beg; idx < end; ++idx) {
        int e = sorted[idx];
        int tt = tgt[e];
        float d = tm - ts[e];
        const float* mrow = memory + (long)tt * 195;
        float v0 = mrow[lane]       / mrow[64];
        float v1 = mrow[65 + lane]  / mrow[129];
        float v2 = mrow[130 + lane] / mrow[194];
        float v3 = nodef[(long)tt * 64 + lane];
        float w0 = __expf(-lb0 * d), w1 = __expf(-lb1 * d), w2 = __expf(-lb2 * d);
        acc[0][0] += w0 * v0; acc[0][1] += w0 * v1; acc[0][2] += w0 * v2; acc[0][3] += w0 * v3; accc[0] += w0;
        acc[1][0] += w1 * v0; acc[1][1] += w1 * v1; acc[1][2] += w1 * v2; acc[1][3] += w1 * v3; accc[1] += w1;
        acc[2][0] += w2 * v0; acc[2][1] += w2 * v1; acc[2][2] += w2 * v2; acc[2][3] += w2 * v3; accc[2] += w2;
    }
    long rb = (long)n * 771;
    #pragma unroll
    for (int l = 0; l < 3; ++l) {
        #pragma unroll
        for (int k = 0; k < 4; ++k) agg[rb + l * 257 + k * 64 + lane] = acc[l][k];
        if (lane == 0) { agg[rb + l * 257 + 256] = accc[l]; cnt3[n * 3 + l] = accc[l]; }
    }
    if (lane == 0) has_msg[n] = (end > beg) ? 1 : 0;
}

// ---------------- mf MLP: (N*3,256) -> relu(128) -> relu(64) ----------------
__global__ __launch_bounds__(256) void k_mf(
        const float* __restrict__ agg, const float* __restrict__ W1, const float* __restrict__ b1,
        const float* __restrict__ W2, const float* __restrict__ b2,
        float* __restrict__ msg_feat, int NROWS) {
    __shared__ float sfeat[32][260];
    __shared__ float shh[32][132];
    int row0 = blockIdx.x * 32;
    int t = threadIdx.x;
    #pragma unroll
    for (int k = 0; k < 32; ++k) {
        int idx = t + k * 256;
        int r = idx >> 8, f = idx & 255;
        sfeat[r][f] = (row0 + r < NROWS) ? agg[(long)(row0 + r) * 257 + f] : 0.f;
    }
    __syncthreads();
    int cg = t & 31, rg = t >> 5;
    {   // layer 1: 32 rows x 128 cols, 4r x 4c micro-tile
        int c0 = cg * 4, r0 = rg * 4;
        float acc[4][4];
        #pragma unroll
        for (int i = 0; i < 4; ++i)
            #pragma unroll
            for (int j = 0; j < 4; ++j) acc[i][j] = 0.f;
        for (int f0 = 0; f0 < 256; f0 += 4) {
            float4 a[4];
            #pragma unroll
            for (int i = 0; i < 4; ++i) a[i] = *(const float4*)&sfeat[r0 + i][f0];
            #pragma unroll
            for (int ff = 0; ff < 4; ++ff) {
                float4 w = *(const float4*)&W1[(long)(f0 + ff) * 128 + c0];
                #pragma unroll
                for (int i = 0; i < 4; ++i) {
                    float av = (&a[i].x)[ff];
                    acc[i][0] += av * w.x; acc[i][1] += av * w.y;
                    acc[i][2] += av * w.z; acc[i][3] += av * w.w;
                }
            }
        }
        #pragma unroll
        for (int i = 0; i < 4; ++i)
            #pragma unroll
            for (int j = 0; j < 4; ++j) {
                float h = acc[i][j] + b1[c0 + j];
                shh[r0 + i][c0 + j] = h > 0.f ? h : 0.f;
            }
    }
    __syncthreads();
    {   // layer 2: 32 rows x 64 cols, 4r x 2c micro-tile
        int c0 = cg * 2, r0 = rg * 4;
        float acc[4][2];
        #pragma unroll
        for (int i = 0; i < 4; ++i) { acc[i][0] = 0.f; acc[i][1] = 0.f; }
        for (int f0 = 0; f0 < 128; f0 += 4) {
            float4 a[4];
            #pragma unroll
            for (int i = 0; i < 4; ++i) a[i] = *(const float4*)&shh[r0 + i][f0];
            #pragma unroll
            for (int ff = 0; ff < 4; ++ff) {
                float2 w = *(const float2*)&W2[(long)(f0 + ff) * 64 + c0];
                #pragma unroll
                for (int i = 0; i < 4; ++i) {
                    float av = (&a[i].x)[ff];
                    acc[i][0] += av * w.x; acc[i][1] += av * w.y;
                }
            }
        }
        #pragma unroll
        for (int i = 0; i < 4; ++i) {
            int row = row0 + r0 + i;
            if (row < NROWS) {
                #pragma unroll
                for (int j = 0; j < 2; ++j) {
                    float vv = acc[i][j] + b2[c0 + j];
                    msg_feat[(long)row * 64 + c0 + j] = vv > 0.f ? vv : 0.f;
                }
            }
        }
    }
}

// ---------------- A_r stats: rowsum (axis=1 softmax) + colsum (axis=0 softmax) ----------------
__global__ __launch_bounds__(256) void k_stats(const float* __restrict__ A_r,
        float* __restrict__ rowsum, float* __restrict__ colsum, int N) {
    __shared__ float cp[4][224];
    int lane = threadIdx.x & 63, wid = threadIdx.x >> 6;
    int nbase = blockIdx.x * 32 + wid * 8;
    float part[4] = {0.f, 0.f, 0.f, 0.f};
    for (int k = 0; k < 8; ++k) {
        int n = nbase + k;
        if (n >= N) break;              // uniform per wave
        float rs = 0.f;
        #pragma unroll
        for (int c = 0; c < 4; ++c) {
            int col = c * 64 + lane;
            float e = 0.f;
            if (col < 224) e = __expf(A_r[(long)n * 224 + col]);
            rs += e;
            part[c] += e;
        }
        #pragma unroll
        for (int d = 32; d > 0; d >>= 1) rs += __shfl_xor(rs, d, 64);
        if (lane == 0) rowsum[n] = rs;
    }
    #pragma unroll
    for (int c = 0; c < 4; ++c) {
        int col = c * 64 + lane;
        if (col < 224) cp[wid][col] = part[c];
    }
    __syncthreads();
    for (int col = threadIdx.x; col < 224; col += 256) {
        float s = cp[0][col] + cp[1][col] + cp[2][col] + cp[3][col];
        atomicAdd(colsum + col, s);
    }
}

// ---------------- vmid split-K: vpart[chunk, 224, 768] ----------------
__global__ __launch_bounds__(256) void k_vmid(
        const float* __restrict__ A_r, const float* __restrict__ agg,
        const int* __restrict__ has_msg, float* __restrict__ vpart, int N) {
    __shared__ float sa[8][224];
    __shared__ float sb[8][64];
    int bx = blockIdx.x;
    int tile = bx % 12, chunk = bx / 12;
    int l = tile >> 2, f0t = (tile & 3) * 64;
    int KL = (N + VC - 1) / VC;
    int nbeg = chunk * KL, nend = min(nbeg + KL, N);
    int t = threadIdx.x, lane = t & 63, wid = t >> 6;
    int cg = t & 31, rg = t >> 5;
    int c0 = cg * 2, r0 = rg * 28;
    float acc[28][2];
    #pragma unroll
    for (int i = 0; i < 28; ++i) { acc[i][0] = 0.f; acc[i][1] = 0.f; }
    for (int n0 = nbeg; n0 < nend; n0 += 8) {
        #pragma unroll
        for (int h = 0; h < 2; ++h) {
            int rr = wid + h * 4;
            int n = n0 + rr;
            bool ok = (n < nend);
            int hm = ok ? has_msg[n] : 0;
            #pragma unroll
            for (int c = 0; c < 4; ++c) {
                int col = c * 64 + lane;
                if (col < 224) sa[rr][col] = hm ? __expf(A_r[(long)n * 224 + col]) : 0.f;
            }
            float bv = 0.f;
            if (ok) {
                long rb = ((long)n * 3 + l) * 257;
                float den = agg[rb + 256];
                bv = agg[rb + f0t + lane] / fmaxf(den, 1e-6f);
            }
            sb[rr][lane] = bv;
        }
        __syncthreads();
        #pragma unroll 1
        for (int rr = 0; rr < 8; ++rr) {
            float2 b = *(const float2*)&sb[rr][c0];
            #pragma unroll
            for (int q = 0; q < 7; ++q) {
                float4 a4 = *(const float4*)&sa[rr][r0 + q * 4];
                #pragma unroll
                for (int s = 0; s < 4; ++s) {
                    float av = (&a4.x)[s];
                    acc[q * 4 + s][0] += av * b.x;
                    acc[q * 4 + s][1] += av * b.y;
                }
            }
        }
        __syncthreads();
    }
    long base = (long)chunk * 224 * 768;
    #pragma unroll
    for (int i = 0; i < 28; ++i) {
        long o = base + (long)(r0 + i) * 768 + tile * 64 + c0;
        vpart[o] = acc[i][0];
        vpart[o + 1] = acc[i][1];
    }
}

// ---------------- reduce vpart over chunks, divide by colsum ----------------
__global__ void k_vred(const float* __restrict__ vpart, const float* __restrict__ colsum,
                       float* __restrict__ vmid) {
    int idx = blockIdx.x * 256 + threadIdx.x;
    if (idx >= 224 * 768) return;
    float s = 0.f;
    for (int c = 0; c < VC; ++c) s += vpart[(long)c * (224 * 768) + idx];
    vmid[idx] = s / colsum[idx / 768];
}

// ---------------- ffr MLP (672 rows) + virtual-memory decay -> vemb ----------------
__global__ __launch_bounds__(256) void k_ffr(
        const float* __restrict__ vmid, const float* __restrict__ W1, const float* __restrict__ b1,
        const float* __restrict__ W2, const float* __restrict__ b2,
        const float* __restrict__ vmem, const float* __restrict__ vlast,
        const float* __restrict__ lambs, const float* __restrict__ now_time,
        float* __restrict__ vemb) {
    __shared__ float sin_[16][260];
    __shared__ float svh[16][260];
    int row0 = blockIdx.x * 16;
    int t = threadIdx.x;
    #pragma unroll
    for (int k = 0; k < 16; ++k) {
        int idx = t + k * 256;
        int r = idx >> 8, f = idx & 255;
        sin_[r][f] = vmid[(long)(row0 + r) * 256 + f];
    }
    __syncthreads();
    {   // layer 1: 16 x 256, 4r x 4c
        int cg = t & 63, rg = t >> 6;
        int c0 = cg * 4, r0 = rg * 4;
        float acc[4][4];
        #pragma unroll
        for (int i = 0; i < 4; ++i)
            #pragma unroll
            for (int j = 0; j < 4; ++j) acc[i][j] = 0.f;
        for (int f0 = 0; f0 < 256; f0 += 4) {
            float4 a[4];
            #pragma unroll
            for (int i = 0; i < 4; ++i) a[i] = *(const float4*)&sin_[r0 + i][f0];
            #pragma unroll
            for (int ff = 0; ff < 4; ++ff) {
                float4 w = *(const float4*)&W1[(long)(f0 + ff) * 256 + c0];
                #pragma unroll
                for (int i = 0; i < 4; ++i) {
                    float av = (&a[i].x)[ff];
                    acc[i][0] += av * w.x; acc[i][1] += av * w.y;
                    acc[i][2] += av * w.z; acc[i][3] += av * w.w;
                }
            }
        }
        #pragma unroll
        for (int i = 0; i < 4; ++i)
            #pragma unroll
            for (int j = 0; j < 4; ++j)
                svh[r0 + i][c0 + j] = lky(acc[i][j] + b1[c0 + j]);
    }
    __syncthreads();
    {   // layer 2: 16 x 64, 2r x 2c + decay epilogue
        int cg = t & 31, rg = t >> 5;
        int c0 = cg * 2, r0 = rg * 2;
        float acc[2][2];
        acc[0][0] = acc[0][1] = acc[1][0] = acc[1][1] = 0.f;
        for (int f0 = 0; f0 < 256; f0 += 4) {
            float4 a[2];
            #pragma unroll
            for (int i = 0; i < 2; ++i) a[i] = *(const float4*)&svh[r0 + i][f0];
            #pragma unroll
            for (int ff = 0; ff < 4; ++ff) {
                float2 w = *(const float2*)&W2[(long)(f0 + ff) * 64 + c0];
                #pragma unroll
                for (int i = 0; i < 2; ++i) {
                    float av = (&a[i].x)[ff];
                    acc[i][0] += av * w.x; acc[i][1] += av * w.y;
                }
            }
        }
        float nowv = now_time[0];
        #pragma unroll
        for (int i = 0; i < 2; ++i) {
            int row = row0 + r0 + i;           // row = r*3 + l
            int rr = row / 3, l = row % 3;
            float vd = __expf(-lambs[l] * (nowv - vlast[rr]));
            #pragma unroll
            for (int j = 0; j < 2; ++j) {
                float v = lky(acc[i][j] + b2[c0 + j]);
                int m = c0 + j;
                vemb[(long)rr * 192 + l * 64 + m] = vmem[(long)rr * 192 + l * 64 + m] * vd + v;
            }
        }
    }
}

// ---------------- new_mem -> node_emb ----------------
__global__ void k_newmem(const float* __restrict__ memory, const float* __restrict__ msg_feat,
        const float* __restrict__ cnt3, const float* __restrict__ t_max,
        const float* __restrict__ last_update, const int* __restrict__ has_msg,
        const float* __restrict__ lambs, float* __restrict__ node_emb, int N) {
    int n = blockIdx.x;
    int j = threadIdx.x;                 // 0..191
    int l = j >> 6, m = j & 63;
    int has = has_msg[n];
    float dt = has ? (t_max[n] - last_update[n]) : 0.f;
    float decay = __expf(-lambs[l] * dt);
    long mb = (long)n * 195 + l * 65;
    float num = memory[mb + m];
    float den = memory[mb + 64];
    if (has) {
        num = num * decay + msg_feat[(long)n * 192 + j];
        den = den * decay + cnt3[n * 3 + l];
    }
    node_emb[(long)n * 192 + j] = num / fmaxf(den, 1e-6f);
}

// ---------------- vnode_emb = row-softmax(A_r) @ vemb ----------------
__global__ __launch_bounds__(192) void k_vnode(
        const float* __restrict__ A_r, const float* __restrict__ rowsum,
        const float* __restrict__ vemb, float* __restrict__ vnode_emb, int N) {
    __shared__ float sv[56 * 192];
    __shared__ float sa[32][60];
    int n0 = blockIdx.x * 32;
    int t = threadIdx.x;
    int cg = t % 96, ng = t / 96;
    int c0 = cg * 2;
    float acc[16][2];
    #pragma unroll
    for (int i = 0; i < 16; ++i) { acc[i][0] = 0.f; acc[i][1] = 0.f; }
    for (int rc = 0; rc < 4; ++rc) {
        int r0 = rc * 56;
        for (int k = 0; k < 56; ++k) {
            int idx = t + k * 192;
            sv[idx] = vemb[(long)r0 * 192 + idx];
        }
        for (int idx = t; idx < 32 * 56; idx += 192) {
            int i = idx / 56, rr = idx % 56;
            int n = n0 + i;
            sa[i][rr] = (n < N) ? __expf(A_r[(long)n * 224 + r0 + rr]) : 0.f;
        }
        __syncthreads();
        #pragma unroll 1
        for (int rq = 0; rq < 14; ++rq) {
            float2 v0 = *(const float2*)&sv[(rq * 4 + 0) * 192 + c0];
            float2 v1 = *(const float2*)&sv[(rq * 4 + 1) * 192 + c0];
            float2 v2 = *(const float2*)&sv[(rq * 4 + 2) * 192 + c0];
            float2 v3 = *(const float2*)&sv[(rq * 4 + 3) * 192 + c0];
            #pragma unroll
            for (int i = 0; i < 16; ++i) {
                float4 a4 = *(const float4*)&sa[ng * 16 + i][rq * 4];
                acc[i][0] += a4.x * v0.x + a4.y * v1.x + a4.z * v2.x + a4.w * v3.x;
                acc[i][1] += a4.x * v0.y + a4.y * v1.y + a4.z * v2.y + a4.w * v3.y;
            }
        }
        __syncthreads();
    }
    #pragma unroll
    for (int i = 0; i < 16; ++i) {
        int n = n0 + ng * 16 + i;
        if (n < N) {
            float inv = 1.f / rowsum[n];
            vnode_emb[(long)n * 192 + c0]     = acc[i][0] * inv;
            vnode_emb[(long)n * 192 + c0 + 1] = acc[i][1] * inv;
        }
    }
}

// ---------------- et + st + output blend ----------------
__global__ __launch_bounds__(256) void k_et_st(
        const float* __restrict__ node_emb, const float* __restrict__ vnode_emb,
        const float* __restrict__ etW, const float* __restrict__ etb,
        const float* __restrict__ stW, const float* __restrict__ stb,
        const float* __restrict__ stat, const float* __restrict__ lamb,
        float* __restrict__ out, int N) {
    __shared__ float sdyn[32][196];
    __shared__ float shh[16][132];
    int n0 = blockIdx.x * 16;
    int t = threadIdx.x;
    for (int k = 0; k < 24; ++k) {
        int idx = t + k * 256;
        int r = idx / 192, f = idx % 192;
        int n = n0 + (r & 15);
        const float* srcp = (r < 16) ? node_emb : vnode_emb;
        sdyn[r][f] = (n < N) ? srcp[(long)n * 192 + f] : 0.f;
    }
    __syncthreads();
    int cg = t & 31, rg = t >> 5;
    {   // et: 32 rows x 64 cols, 4r x 2c
        int c0 = cg * 2, r0 = rg * 4;
        float acc[4][2];
        #pragma unroll
        for (int i = 0; i < 4; ++i) { acc[i][0] = 0.f; acc[i][1] = 0.f; }
        for (int f0 = 0; f0 < 192; f0 += 4) {
            float4 a[4];
            #pragma unroll
            for (int i = 0; i < 4; ++i) a[i] = *(const float4*)&sdyn[r0 + i][f0];
            #pragma unroll
            for (int ff = 0; ff < 4; ++ff) {
                float2 w = *(const float2*)&etW[(long)(f0 + ff) * 64 + c0];
                #pragma unroll
                for (int i = 0; i < 4; ++i) {
                    float av = (&a[i].x)[ff];
                    acc[i][0] += av * w.x; acc[i][1] += av * w.y;
                }
            }
        }
        #pragma unroll
        for (int i = 0; i < 4; ++i) {
            int row = r0 + i;
            #pragma unroll
            for (int j = 0; j < 2; ++j)
                shh[row & 15][(row >> 4) * 64 + c0 + j] = lky(acc[i][j] + etb[c0 + j]);
        }
    }
    __syncthreads();
    {   // st: 16 x 128, 2n x 4c + blend
        int c0 = cg * 4, r0 = rg * 2;
        float acc[2][4];
        #pragma unroll
        for (int i = 0; i < 2; ++i)
            #pragma unroll
            for (int j = 0; j < 4; ++j) acc[i][j] = 0.f;
        for (int f0 = 0; f0 < 128; f0 += 4) {
            float4 a[2];
            #pragma unroll
            for (int i = 0; i < 2; ++i) a[i] = *(const float4*)&shh[r0 + i][f0];
            #pragma unroll
            for (int ff = 0; ff < 4; ++ff) {
                float4 w = *(const float4*)&stW[(long)(f0 + ff) * 128 + c0];
                #pragma unroll
                for (int i = 0; i < 2; ++i) {
                    float av = (&a[i].x)[ff];
                    acc[i][0] += av * w.x; acc[i][1] += av * w.y;
                    acc[i][2] += av * w.z; acc[i][3] += av * w.w;
                }
            }
        }
        float lam = lamb[0];
        #pragma unroll
        for (int i = 0; i < 2; ++i) {
            int n = n0 + r0 + i;
            if (n < N) {
                #pragma unroll
                for (int j = 0; j < 4; ++j) {
                    float v = lky(acc[i][j] + stb[c0 + j]);
                    out[(long)n * 128 + c0 + j] =
                        lam * stat[(long)n * 128 + c0 + j] + (1.f - lam) * v;
                }
            }
        }
    }
}

extern "C" void kernel_launch(void* const* d_in, const int* in_sizes, int n_in,
                              void* d_out, int out_size, void* d_ws, size_t ws_size,
                              hipStream_t stream) {
    const int*   src        = (const int*)d_in[0];
    const int*   tgt        = (const int*)d_in[1];
    const float* ts         = (const float*)d_in[2];
    const float* now_time   = (const float*)d_in[3];
    const float* nodef      = (const float*)d_in[5];
    const float* memory     = (const float*)d_in[6];
    const float* last_upd   = (const float*)d_in[7];
    const float* vmem       = (const float*)d_in[8];
    const float* vlast      = (const float*)d_in[9];
    const float* A_r        = (const float*)d_in[10];
    const float* static_emb = (const float*)d_in[11];
    const float* lamb       = (const float*)d_in[12];
    const float* lambs      = (const float*)d_in[13];
    const float* mf_W1      = (const float*)d_in[14];
    const float* mf_b1      = (const float*)d_in[15];
    const float* mf_W2      = (const float*)d_in[16];
    const float* mf_b2      = (const float*)d_in[17];
    const float* ffr_W1     = (const float*)d_in[18];
    const float* ffr_b1     = (const float*)d_in[19];
    const float* ffr_W2     = (const float*)d_in[20];
    const float* ffr_b2     = (const float*)d_in[21];
    const float* et_W       = (const float*)d_in[22];
    const float* et_b       = (const float*)d_in[23];
    const float* st_W       = (const float*)d_in[24];
    const float* st_b       = (const float*)d_in[25];

    int E = in_sizes[0];
    int N = in_sizes[7];

    float* ws = (float*)d_ws;
    size_t off = 0;
    auto alloc = [&](size_t nf) { float* p = ws + off; off += (nf + 63) & ~(size_t)63; return p; };
    float* agg      = alloc((size_t)N * 771);
    float* msg_feat = alloc((size_t)N * 192);
    float* vpart    = alloc((size_t)VC * 224 * 768);
    float* vmid     = alloc(224 * 768);
    float* vemb     = alloc(224 * 192);
    float* t_max    = alloc(N);
    float* rowsum   = alloc(N);
    float* cnt3     = alloc((size_t)N * 3);
    float* colsum   = alloc(256);
    int*   cnt      = (int*)alloc(N);
    int*   offsets  = (int*)alloc(N + 1);
    int*   cursor   = (int*)alloc(N);
    int*   sorted   = (int*)alloc(E);
    int*   has_msg  = (int*)alloc(N);
    // reuse the agg region after k_vmid consumed it:
    float* node_emb  = agg;
    float* vnode_emb = agg + (size_t)N * 192;

    k_init<<<(N + 255) / 256, 256, 0, stream>>>(t_max, cnt, cursor, colsum, N);
    k_tmax_cnt<<<(E + 255) / 256, 256, 0, stream>>>(src, ts, t_max, cnt, E);
    k_scan<<<1, 1024, 0, stream>>>(cnt, offsets, N);
    k_scatter<<<(E + 255) / 256, 256, 0, stream>>>(src, offsets, cursor, sorted, E);
    k_agg<<<(N + 3) / 4, 256, 0, stream>>>(tgt, ts, sorted, offsets, t_max, memory, nodef,
                                           lambs, agg, cnt3, has_msg, N);
    k_mf<<<(N * 3 + 31) / 32, 256, 0, stream>>>(agg, mf_W1, mf_b1, mf_W2, mf_b2, msg_feat, N * 3);
    k_stats<<<(N + 31) / 32, 256, 0, stream>>>(A_r, rowsum, colsum, N);
    k_vmid<<<12 * VC, 256, 0, stream>>>(A_r, agg, has_msg, vpart, N);
    k_vred<<<(224 * 768 + 255) / 256, 256, 0, stream>>>(vpart, colsum, vmid);
    k_ffr<<<42, 256, 0, stream>>>(vmid, ffr_W1, ffr_b1, ffr_W2, ffr_b2, vmem, vlast,
                                  lambs, now_time, vemb);
    k_newmem<<<N, 192, 0, stream>>>(memory, msg_feat, cnt3, t_max, last_upd, has_msg,
                                    lambs, node_emb, N);
    k_vnode<<<(N + 31) / 32, 192, 0, stream>>>(A_r, rowsum, vemb, vnode_emb, N);
    k_et_st<<<(N + 15) / 16, 256, 0, stream>>>(node_emb, vnode_emb, et_W, et_b, st_W, st_b,
                                               static_emb, lamb, (float*)d_out, N);
}

// Round 3
// 858.630 us; speedup vs baseline: 1.7280x; 1.7280x over previous
//
#include <hip/hip_runtime.h>

static __device__ __forceinline__ float lky(float x) { return x > 0.f ? x : 0.01f * x; }

static __device__ __forceinline__ unsigned short f2bf(float x) {
    unsigned int u = __float_as_uint(x);
    unsigned int r = (u + 0x7FFFu + ((u >> 16) & 1u)) >> 16;
    return (unsigned short)r;
}
static __device__ __forceinline__ float bf2f(unsigned short x) {
    return __uint_as_float((unsigned int)x << 16);
}

typedef __attribute__((ext_vector_type(8))) short short8;
typedef __attribute__((ext_vector_type(4))) float f32x4;

constexpr int SN  = 50048;   // padded node count (multiple of 64)
constexpr int KLV = 608;     // K(nodes) per split-K chunk (multiple of 32)
constexpr int VCM = 83;      // ceil(SN/KLV)

// ---------------- init ----------------
__global__ void k_init(float* t_max, int* cnt, int* cursor, float* colsum, int N) {
    int i = blockIdx.x * 256 + threadIdx.x;
    if (i < N) { t_max[i] = -1.0f; cnt[i] = 0; cursor[i] = 0; }
    if (i < 224) colsum[i] = 0.0f;
}

// ---------------- per-edge t_max / counts ----------------
__global__ void k_tmax_cnt(const int* __restrict__ src, const float* __restrict__ ts,
                           float* t_max, int* cnt, int E) {
    int e = blockIdx.x * 256 + threadIdx.x;
    if (e >= E) return;
    int s = src[e];
    atomicMax((int*)(t_max + s), __float_as_int(ts[e]));   // ts >= 0, int-monotone
    atomicAdd(cnt + s, 1);
}

// ---------------- exclusive scan over counts (single block) ----------------
__global__ __launch_bounds__(1024) void k_scan(const int* __restrict__ cnt,
                                               int* __restrict__ offsets, int N) {
    __shared__ int wsum[16];
    __shared__ int s_run;
    int t = threadIdx.x;
    int lane = t & 63, wid = t >> 6;
    if (t == 0) s_run = 0;
    __syncthreads();
    int nchunk = (N + 1023) >> 10;
    for (int c = 0; c < nchunk; ++c) {
        int i = (c << 10) + t;
        int v = (i < N) ? cnt[i] : 0;
        int x = v;
        #pragma unroll
        for (int d = 1; d < 64; d <<= 1) {
            int y = __shfl_up(x, d, 64);
            if (lane >= d) x += y;
        }
        if (lane == 63) wsum[wid] = x;
        __syncthreads();
        int wbase = 0;
        #pragma unroll
        for (int w = 0; w < 16; ++w) wbase += (w < wid) ? wsum[w] : 0;
        int run = s_run;
        if (i < N) offsets[i] = run + wbase + x - v;
        __syncthreads();
        if (t == 1023) s_run = run + wbase + x;
        __syncthreads();
    }
    if (t == 0) offsets[N] = s_run;
}

// ---------------- scatter edges into per-node buckets ----------------
__global__ void k_scatter(const int* __restrict__ src, const int* __restrict__ offsets,
                          int* cursor, int* sorted, int E) {
    int e = blockIdx.x * 256 + threadIdx.x;
    if (e >= E) return;
    int s = src[e];
    int pos = offsets[s] + atomicAdd(cursor + s, 1);
    sorted[pos] = e;
}

// ---------------- A_r pass: rowsum, colsum, masked transposed bf16 AexpT ----------------
__global__ __launch_bounds__(256) void k_aexp(
        const float* __restrict__ A_r, const int* __restrict__ offsets,
        float* __restrict__ rowsum, float* __restrict__ colsum,
        unsigned short* __restrict__ AexpT, int N) {
    __shared__ float sA[32][226];
    __shared__ int soff[33];
    int t = threadIdx.x;
    int n0 = blockIdx.x * 32;
    for (int idx = t; idx < 32 * 224; idx += 256) {
        int n = idx / 224, c = idx % 224;
        int gn = n0 + n;
        float e = (gn < N) ? __expf(A_r[(long)gn * 224 + c]) : 0.f;
        sA[n][c] = e;
    }
    if (t < 33) soff[t] = offsets[min(n0 + t, N)];
    __syncthreads();
    // rowsum: 8 lanes per node
    {
        int n = t >> 3, l8 = t & 7;
        float s = 0.f;
        for (int c = l8; c < 224; c += 8) s += sA[n][c];
        #pragma unroll
        for (int d = 1; d < 8; d <<= 1) s += __shfl_xor(s, d, 64);
        if (l8 == 0 && n0 + n < N) rowsum[n0 + n] = s;
    }
    // colsum partials
    if (t < 224) {
        float s = 0.f;
        #pragma unroll
        for (int n = 0; n < 32; ++n) s += sA[n][t];
        atomicAdd(colsum + t, s);
    }
    // masked transpose write
    if (t < 224) {
        int r = t;
        unsigned int wbuf[16];
        #pragma unroll
        for (int k = 0; k < 16; ++k) {
            int n_a = 2 * k, n_b = 2 * k + 1;
            float va = (soff[n_a + 1] > soff[n_a]) ? sA[n_a][r] : 0.f;
            float vb = (soff[n_b + 1] > soff[n_b]) ? sA[n_b][r] : 0.f;
            wbuf[k] = (unsigned int)f2bf(va) | ((unsigned int)f2bf(vb) << 16);
        }
        unsigned short* dst = AexpT + (size_t)r * SN + n0;
        #pragma unroll
        for (int k = 0; k < 4; ++k) *(uint4*)(dst + k * 8) = *(uint4*)&wbuf[k * 4];
    }
}

// ---------------- per-node aggregation: one wave per node, bf16 output ----------------
__global__ __launch_bounds__(256) void k_agg(
        const int* __restrict__ tgt, const float* __restrict__ ts,
        const int* __restrict__ sorted, const int* __restrict__ offsets,
        const float* __restrict__ t_max, const float* __restrict__ memory,
        const float* __restrict__ nodef, const float* __restrict__ lambs,
        unsigned short* __restrict__ aggb, float* __restrict__ cnt3,
        int* __restrict__ has_msg, int N) {
    int wid = threadIdx.x >> 6, lane = threadIdx.x & 63;
    int n = blockIdx.x * 4 + wid;      // n < SN (grid = SN/4)
    size_t rb = (size_t)n * 3;
    if (n >= N) {                       // zero-fill padding rows
        #pragma unroll
        for (int l = 0; l < 3; ++l) {
            unsigned short* row = aggb + (rb + l) * 256;
            #pragma unroll
            for (int k = 0; k < 4; ++k) row[k * 64 + lane] = 0;
            if (lane == 0) cnt3[rb + l] = 0.f;
        }
        return;
    }
    int beg = offsets[n], end = offsets[n + 1];
    float lb0 = lambs[0], lb1 = lambs[1], lb2 = lambs[2];
    float tm = t_max[n];
    float acc[3][4];
    float accc[3];
    #pragma unroll
    for (int l = 0; l < 3; ++l) {
        accc[l] = 0.f;
        #pragma unroll
        for (int k = 0; k < 4; ++k) acc[l][k] = 0.f;
    }
    for (int idx = beg; idx < end; ++idx) {
        int e = sorted[idx];
        int tt = tgt[e];
        float d = tm - ts[e];
        const float* mrow = memory + (long)tt * 195;
        float v0 = mrow[lane]       / mrow[64];
        float v1 = mrow[65 + lane]  / mrow[129];
        float v2 = mrow[130 + lane] / mrow[194];
        float v3 = nodef[(long)tt * 64 + lane];
        float w0 = __expf(-lb0 * d), w1 = __expf(-lb1 * d), w2 = __expf(-lb2 * d);
        acc[0][0] += w0 * v0; acc[0][1] += w0 * v1; acc[0][2] += w0 * v2; acc[0][3] += w0 * v3; accc[0] += w0;
        acc[1][0] += w1 * v0; acc[1][1] += w1 * v1; acc[1][2] += w1 * v2; acc[1][3] += w1 * v3; accc[1] += w1;
        acc[2][0] += w2 * v0; acc[2][1] += w2 * v1; acc[2][2] += w2 * v2; acc[2][3] += w2 * v3; accc[2] += w2;
    }
    #pragma unroll
    for (int l = 0; l < 3; ++l) {
        unsigned short* row = aggb + (rb + l) * 256;
        #pragma unroll
        for (int k = 0; k < 4; ++k) row[k * 64 + lane] = f2bf(acc[l][k]);
        if (lane == 0) cnt3[rb + l] = accc[l];
    }
    if (lane == 0) has_msg[n] = (end > beg) ? 1 : 0;
}

// ---------------- mf MLP: (3N,256) bf16 -> relu(128) -> relu(64) ----------------
__global__ __launch_bounds__(256) void k_mf(
        const unsigned short* __restrict__ aggb, const float* __restrict__ W1,
        const float* __restrict__ b1, const float* __restrict__ W2, const float* __restrict__ b2,
        float* __restrict__ msg_feat, int NROWS) {
    __shared__ float sfeat[32][260];
    __shared__ float shh[32][132];
    int row0 = blockIdx.x * 32;
    int t = threadIdx.x;
    {   // stage 32 rows x 256 bf16 -> f32 LDS (padding rows are zeroed in aggb)
        int r = t >> 3, seg = t & 7;
        const uint4* p = (const uint4*)(aggb + (size_t)(row0 + r) * 256 + seg * 32);
        #pragma unroll
        for (int u = 0; u < 4; ++u) {
            uint4 v = p[u];
            const unsigned short* sp = (const unsigned short*)&v;
            #pragma unroll
            for (int j = 0; j < 8; ++j)
                sfeat[r][seg * 32 + u * 8 + j] = bf2f(sp[j]);
        }
    }
    __syncthreads();
    int cg = t & 31, rg = t >> 5;
    {   // layer 1: 32 rows x 128 cols, 4r x 4c micro-tile
        int c0 = cg * 4, r0 = rg * 4;
        float acc[4][4];
        #pragma unroll
        for (int i = 0; i < 4; ++i)
            #pragma unroll
            for (int j = 0; j < 4; ++j) acc[i][j] = 0.f;
        for (int f0 = 0; f0 < 256; f0 += 4) {
            float4 a[4];
            #pragma unroll
            for (int i = 0; i < 4; ++i) a[i] = *(const float4*)&sfeat[r0 + i][f0];
            #pragma unroll
            for (int ff = 0; ff < 4; ++ff) {
                float4 w = *(const float4*)&W1[(long)(f0 + ff) * 128 + c0];
                #pragma unroll
                for (int i = 0; i < 4; ++i) {
                    float av = (&a[i].x)[ff];
                    acc[i][0] += av * w.x; acc[i][1] += av * w.y;
                    acc[i][2] += av * w.z; acc[i][3] += av * w.w;
                }
            }
        }
        #pragma unroll
        for (int i = 0; i < 4; ++i)
            #pragma unroll
            for (int j = 0; j < 4; ++j) {
                float h = acc[i][j] + b1[c0 + j];
                shh[r0 + i][c0 + j] = h > 0.f ? h : 0.f;
            }
    }
    __syncthreads();
    {   // layer 2: 32 rows x 64 cols, 4r x 2c micro-tile
        int c0 = cg * 2, r0 = rg * 4;
        float acc[4][2];
        #pragma unroll
        for (int i = 0; i < 4; ++i) { acc[i][0] = 0.f; acc[i][1] = 0.f; }
        for (int f0 = 0; f0 < 128; f0 += 4) {
            float4 a[4];
            #pragma unroll
            for (int i = 0; i < 4; ++i) a[i] = *(const float4*)&shh[r0 + i][f0];
            #pragma unroll
            for (int ff = 0; ff < 4; ++ff) {
                float2 w = *(const float2*)&W2[(long)(f0 + ff) * 64 + c0];
                #pragma unroll
                for (int i = 0; i < 4; ++i) {
                    float av = (&a[i].x)[ff];
                    acc[i][0] += av * w.x; acc[i][1] += av * w.y;
                }
            }
        }
        #pragma unroll
        for (int i = 0; i < 4; ++i) {
            int row = row0 + r0 + i;
            if (row < NROWS) {
                #pragma unroll
                for (int j = 0; j < 2; ++j) {
                    float vv = acc[i][j] + b2[c0 + j];
                    msg_feat[(long)row * 64 + c0 + j] = vv > 0.f ? vv : 0.f;
                }
            }
        }
    }
}

// ---------------- vmid via bf16 MFMA, split-K; B gathered from bf16 agg ----------------
__global__ __launch_bounds__(256) void k_vmid_mfma(
        const unsigned short* __restrict__ AexpT, const unsigned short* __restrict__ aggb,
        const float* __restrict__ cnt3, float* __restrict__ vpart) {
    __shared__ unsigned short As[112 * 40];   // 112 rows x 32 shorts (stride 40)
    __shared__ float sDinv[32];
    int bx = blockIdx.x;
    int chunk = bx / 12, tile = bx % 12;
    int r0 = (tile & 1) * 112;
    int ft = tile >> 1;                 // 0..5
    int l = ft >> 1, fo = (ft & 1) * 128;
    int t = threadIdx.x, lane = t & 63, w = t >> 6;
    int lr = lane & 15, kg = lane >> 4;
    f32x4 acc[7][2];
    #pragma unroll
    for (int q = 0; q < 7; ++q) {
        acc[q][0] = (f32x4){0.f, 0.f, 0.f, 0.f};
        acc[q][1] = (f32x4){0.f, 0.f, 0.f, 0.f};
    }
    int nbeg = chunk * KLV;
    int nsteps = min(KLV, SN - nbeg) >> 5;
    int colbase = fo + w * 32 + lr;
    for (int s = 0; s < nsteps; ++s) {
        int n0 = nbeg + s * 32;
        if (t < 224) {                   // stage A: full 32 shorts per row
            int srow = t >> 1, sseg = t & 1;
            const uint4* ap = (const uint4*)(AexpT + (size_t)(r0 + srow) * SN + n0) + sseg * 2;
            uint4 v0 = ap[0];
            uint4 v1 = ap[1];
            *(uint4*)&As[srow * 40 + sseg * 16]     = v0;
            *(uint4*)&As[srow * 40 + sseg * 16 + 8] = v1;
        } else {                          // stage 1/den for 32 nodes
            int k = t - 224;
            sDinv[k] = 1.f / fmaxf(cnt3[(size_t)(n0 + k) * 3 + l], 1e-6f);
        }
        __syncthreads();
        short8 b0, b1;
        #pragma unroll
        for (int j = 0; j < 8; ++j) {
            int kk = kg * 8 + j;
            float dv = sDinv[kk];
            const unsigned short* brow = aggb + ((size_t)(n0 + kk) * 3 + l) * 256 + colbase;
            b0[j] = (short)f2bf(bf2f(brow[0])  * dv);
            b1[j] = (short)f2bf(bf2f(brow[16]) * dv);
        }
        #pragma unroll
        for (int q = 0; q < 7; ++q) {
            short8 af = *(const short8*)&As[(q * 16 + lr) * 40 + kg * 8];
            acc[q][0] = __builtin_amdgcn_mfma_f32_16x16x32_bf16(af, b0, acc[q][0], 0, 0, 0);
            acc[q][1] = __builtin_amdgcn_mfma_f32_16x16x32_bf16(af, b1, acc[q][1], 0, 0, 0);
        }
        __syncthreads();
    }
    float* outp = vpart + (size_t)chunk * 172032;
    #pragma unroll
    for (int q = 0; q < 7; ++q) {
        int row = r0 + q * 16 + kg * 4;
        #pragma unroll
        for (int p = 0; p < 2; ++p) {
            int col = l * 256 + fo + w * 32 + p * 16 + lr;
            #pragma unroll
            for (int j = 0; j < 4; ++j)
                outp[(size_t)(row + j) * 768 + col] = acc[q][p][j];
        }
    }
}

// ---------------- reduce vpart over chunks, divide by colsum ----------------
__global__ void k_vred(const float* __restrict__ vpart, const float* __restrict__ colsum,
                       float* __restrict__ vmid) {
    int idx = blockIdx.x * 256 + threadIdx.x;
    if (idx >= 224 * 768) return;
    float s = 0.f;
    for (int c = 0; c < VCM; ++c) s += vpart[(long)c * (224 * 768) + idx];
    vmid[idx] = s / colsum[idx / 768];
}

// ---------------- ffr MLP (672 rows) + virtual-memory decay -> vemb ----------------
__global__ __launch_bounds__(256) void k_ffr(
        const float* __restrict__ vmid, const float* __restrict__ W1, const float* __restrict__ b1,
        const float* __restrict__ W2, const float* __restrict__ b2,
        const float* __restrict__ vmem, const float* __restrict__ vlast,
        const float* __restrict__ lambs, const float* __restrict__ now_time,
        float* __restrict__ vemb) {
    __shared__ float sin_[16][260];
    __shared__ float svh[16][260];
    int row0 = blockIdx.x * 16;
    int t = threadIdx.x;
    #pragma unroll
    for (int k = 0; k < 16; ++k) {
        int idx = t + k * 256;
        int r = idx >> 8, f = idx & 255;
        sin_[r][f] = vmid[(long)(row0 + r) * 256 + f];
    }
    __syncthreads();
    {   // layer 1: 16 x 256, 4r x 4c
        int cg = t & 63, rg = t >> 6;
        int c0 = cg * 4, r0 = rg * 4;
        float acc[4][4];
        #pragma unroll
        for (int i = 0; i < 4; ++i)
            #pragma unroll
            for (int j = 0; j < 4; ++j) acc[i][j] = 0.f;
        for (int f0 = 0; f0 < 256; f0 += 4) {
            float4 a[4];
            #pragma unroll
            for (int i = 0; i < 4; ++i) a[i] = *(const float4*)&sin_[r0 + i][f0];
            #pragma unroll
            for (int ff = 0; ff < 4; ++ff) {
                float4 w = *(const float4*)&W1[(long)(f0 + ff) * 256 + c0];
                #pragma unroll
                for (int i = 0; i < 4; ++i) {
                    float av = (&a[i].x)[ff];
                    acc[i][0] += av * w.x; acc[i][1] += av * w.y;
                    acc[i][2] += av * w.z; acc[i][3] += av * w.w;
                }
            }
        }
        #pragma unroll
        for (int i = 0; i < 4; ++i)
            #pragma unroll
            for (int j = 0; j < 4; ++j)
                svh[r0 + i][c0 + j] = lky(acc[i][j] + b1[c0 + j]);
    }
    __syncthreads();
    {   // layer 2: 16 x 64, 2r x 2c + decay epilogue
        int cg = t & 31, rg = t >> 5;
        int c0 = cg * 2, r0 = rg * 2;
        float acc[2][2];
        acc[0][0] = acc[0][1] = acc[1][0] = acc[1][1] = 0.f;
        for (int f0 = 0; f0 < 256; f0 += 4) {
            float4 a[2];
            #pragma unroll
            for (int i = 0; i < 2; ++i) a[i] = *(const float4*)&svh[r0 + i][f0];
            #pragma unroll
            for (int ff = 0; ff < 4; ++ff) {
                float2 w = *(const float2*)&W2[(long)(f0 + ff) * 64 + c0];
                #pragma unroll
                for (int i = 0; i < 2; ++i) {
                    float av = (&a[i].x)[ff];
                    acc[i][0] += av * w.x; acc[i][1] += av * w.y;
                }
            }
        }
        float nowv = now_time[0];
        #pragma unroll
        for (int i = 0; i < 2; ++i) {
            int row = row0 + r0 + i;           // row = r*3 + l
            int rr = row / 3, l = row % 3;
            float vd = __expf(-lambs[l] * (nowv - vlast[rr]));
            #pragma unroll
            for (int j = 0; j < 2; ++j) {
                float v = lky(acc[i][j] + b2[c0 + j]);
                int m = c0 + j;
                vemb[(long)rr * 192 + l * 64 + m] = vmem[(long)rr * 192 + l * 64 + m] * vd + v;
            }
        }
    }
}

// ---------------- new_mem -> node_emb ----------------
__global__ void k_newmem(const float* __restrict__ memory, const float* __restrict__ msg_feat,
        const float* __restrict__ cnt3, const float* __restrict__ t_max,
        const float* __restrict__ last_update, const int* __restrict__ has_msg,
        const float* __restrict__ lambs, float* __restrict__ node_emb, int N) {
    int n = blockIdx.x;
    int j = threadIdx.x;                 // 0..191
    int l = j >> 6, m = j & 63;
    int has = has_msg[n];
    float dt = has ? (t_max[n] - last_update[n]) : 0.f;
    float decay = __expf(-lambs[l] * dt);
    long mb = (long)n * 195 + l * 65;
    float num = memory[mb + m];
    float den = memory[mb + 64];
    if (has) {
        num = num * decay + msg_feat[(long)n * 192 + j];
        den = den * decay + cnt3[(size_t)n * 3 + l];
    }
    node_emb[(long)n * 192 + j] = num / fmaxf(den, 1e-6f);
}

// ---------------- vnode_emb = row-softmax(A_r) @ vemb ----------------
__global__ __launch_bounds__(192) void k_vnode(
        const float* __restrict__ A_r, const float* __restrict__ rowsum,
        const float* __restrict__ vemb, float* __restrict__ vnode_emb, int N) {
    __shared__ float sv[56 * 192];
    __shared__ float sa[32][60];
    int n0 = blockIdx.x * 32;
    int t = threadIdx.x;
    int cg = t % 96, ng = t / 96;
    int c0 = cg * 2;
    float acc[16][2];
    #pragma unroll
    for (int i = 0; i < 16; ++i) { acc[i][0] = 0.f; acc[i][1] = 0.f; }
    for (int rc = 0; rc < 4; ++rc) {
        int r0 = rc * 56;
        for (int k = 0; k < 56; ++k) {
            int idx = t + k * 192;
            sv[idx] = vemb[(long)r0 * 192 + idx];
        }
        for (int idx = t; idx < 32 * 56; idx += 192) {
            int i = idx / 56, rr = idx % 56;
            int n = n0 + i;
            sa[i][rr] = (n < N) ? __expf(A_r[(long)n * 224 + r0 + rr]) : 0.f;
        }
        __syncthreads();
        #pragma unroll 1
        for (int rq = 0; rq < 14; ++rq) {
            float2 v0 = *(const float2*)&sv[(rq * 4 + 0) * 192 + c0];
            float2 v1 = *(const float2*)&sv[(rq * 4 + 1) * 192 + c0];
            float2 v2 = *(const float2*)&sv[(rq * 4 + 2) * 192 + c0];
            float2 v3 = *(const float2*)&sv[(rq * 4 + 3) * 192 + c0];
            #pragma unroll
            for (int i = 0; i < 16; ++i) {
                float4 a4 = *(const float4*)&sa[ng * 16 + i][rq * 4];
                acc[i][0] += a4.x * v0.x + a4.y * v1.x + a4.z * v2.x + a4.w * v3.x;
                acc[i][1] += a4.x * v0.y + a4.y * v1.y + a4.z * v2.y + a4.w * v3.y;
            }
        }
        __syncthreads();
    }
    #pragma unroll
    for (int i = 0; i < 16; ++i) {
        int n = n0 + ng * 16 + i;
        if (n < N) {
            float inv = 1.f / rowsum[n];
            vnode_emb[(long)n * 192 + c0]     = acc[i][0] * inv;
            vnode_emb[(long)n * 192 + c0 + 1] = acc[i][1] * inv;
        }
    }
}

// ---------------- et + st + output blend ----------------
__global__ __launch_bounds__(256) void k_et_st(
        const float* __restrict__ node_emb, const float* __restrict__ vnode_emb,
        const float* __restrict__ etW, const float* __restrict__ etb,
        const float* __restrict__ stW, const float* __restrict__ stb,
        const float* __restrict__ stat, const float* __restrict__ lamb,
        float* __restrict__ out, int N) {
    __shared__ float sdyn[32][196];
    __shared__ float shh[16][132];
    int n0 = blockIdx.x * 16;
    int t = threadIdx.x;
    for (int k = 0; k < 24; ++k) {
        int idx = t + k * 256;
        int r = idx / 192, f = idx % 192;
        int n = n0 + (r & 15);
        const float* srcp = (r < 16) ? node_emb : vnode_emb;
        sdyn[r][f] = (n < N) ? srcp[(long)n * 192 + f] : 0.f;
    }
    __syncthreads();
    int cg = t & 31, rg = t >> 5;
    {   // et: 32 rows x 64 cols, 4r x 2c
        int c0 = cg * 2, r0 = rg * 4;
        float acc[4][2];
        #pragma unroll
        for (int i = 0; i < 4; ++i) { acc[i][0] = 0.f; acc[i][1] = 0.f; }
        for (int f0 = 0; f0 < 192; f0 += 4) {
            float4 a[4];
            #pragma unroll
            for (int i = 0; i < 4; ++i) a[i] = *(const float4*)&sdyn[r0 + i][f0];
            #pragma unroll
            for (int ff = 0; ff < 4; ++ff) {
                float2 w = *(const float2*)&etW[(long)(f0 + ff) * 64 + c0];
                #pragma unroll
                for (int i = 0; i < 4; ++i) {
                    float av = (&a[i].x)[ff];
                    acc[i][0] += av * w.x; acc[i][1] += av * w.y;
                }
            }
        }
        #pragma unroll
        for (int i = 0; i < 4; ++i) {
            int row = r0 + i;
            #pragma unroll
            for (int j = 0; j < 2; ++j)
                shh[row & 15][(row >> 4) * 64 + c0 + j] = lky(acc[i][j] + etb[c0 + j]);
        }
    }
    __syncthreads();
    {   // st: 16 x 128, 2n x 4c + blend
        int c0 = cg * 4, r0 = rg * 2;
        float acc[2][4];
        #pragma unroll
        for (int i = 0; i < 2; ++i)
            #pragma unroll
            for (int j = 0; j < 4; ++j) acc[i][j] = 0.f;
        for (int f0 = 0; f0 < 128; f0 += 4) {
            float4 a[2];
            #pragma unroll
            for (int i = 0; i < 2; ++i) a[i] = *(const float4*)&shh[r0 + i][f0];
            #pragma unroll
            for (int ff = 0; ff < 4; ++ff) {
                float4 w = *(const float4*)&stW[(long)(f0 + ff) * 128 + c0];
                #pragma unroll
                for (int i = 0; i < 2; ++i) {
                    float av = (&a[i].x)[ff];
                    acc[i][0] += av * w.x; acc[i][1] += av * w.y;
                    acc[i][2] += av * w.z; acc[i][3] += av * w.w;
                }
            }
        }
        float lam = lamb[0];
        #pragma unroll
        for (int i = 0; i < 2; ++i) {
            int n = n0 + r0 + i;
            if (n < N) {
                #pragma unroll
                for (int j = 0; j < 4; ++j) {
                    float v = lky(acc[i][j] + stb[c0 + j]);
                    out[(long)n * 128 + c0 + j] =
                        lam * stat[(long)n * 128 + c0 + j] + (1.f - lam) * v;
                }
            }
        }
    }
}

extern "C" void kernel_launch(void* const* d_in, const int* in_sizes, int n_in,
                              void* d_out, int out_size, void* d_ws, size_t ws_size,
                              hipStream_t stream) {
    const int*   src        = (const int*)d_in[0];
    const int*   tgt        = (const int*)d_in[1];
    const float* ts         = (const float*)d_in[2];
    const float* now_time   = (const float*)d_in[3];
    const float* nodef      = (const float*)d_in[5];
    const float* memory     = (const float*)d_in[6];
    const float* last_upd   = (const float*)d_in[7];
    const float* vmem       = (const float*)d_in[8];
    const float* vlast      = (const float*)d_in[9];
    const float* A_r        = (const float*)d_in[10];
    const float* static_emb = (const float*)d_in[11];
    const float* lamb       = (const float*)d_in[12];
    const float* lambs      = (const float*)d_in[13];
    const float* mf_W1      = (const float*)d_in[14];
    const float* mf_b1      = (const float*)d_in[15];
    const float* mf_W2      = (const float*)d_in[16];
    const float* mf_b2      = (const float*)d_in[17];
    const float* ffr_W1     = (const float*)d_in[18];
    const float* ffr_b1     = (const float*)d_in[19];
    const float* ffr_W2     = (const float*)d_in[20];
    const float* ffr_b2     = (const float*)d_in[21];
    const float* et_W       = (const float*)d_in[22];
    const float* et_b       = (const float*)d_in[23];
    const float* st_W       = (const float*)d_in[24];
    const float* st_b       = (const float*)d_in[25];

    int E = in_sizes[0];
    int N = in_sizes[7];

    float* ws = (float*)d_ws;
    size_t off = 0;
    auto alloc = [&](size_t nf) { float* p = ws + off; off += (nf + 63) & ~(size_t)63; return p; };
    unsigned short* aggb = (unsigned short*)alloc((size_t)SN * 384);   // SN*3 rows x 256 bf16
    float* msg_feat = alloc((size_t)N * 192);
    unsigned short* AexpT = (unsigned short*)alloc((size_t)224 * SN / 2);
    float* vpart    = alloc((size_t)VCM * 224 * 768);
    float* vmid     = alloc(224 * 768);
    float* vemb     = alloc(224 * 192);
    float* t_max    = alloc(N);
    float* rowsum   = alloc(N);
    float* cnt3     = alloc((size_t)SN * 3);
    float* colsum   = alloc(256);
    int*   cnt      = (int*)alloc(N);
    int*   offsets  = (int*)alloc(N + 1);
    int*   cursor   = (int*)alloc(N);
    int*   sorted   = (int*)alloc(E);
    int*   has_msg  = (int*)alloc(N);
    if (off * sizeof(float) > ws_size) return;   // workspace guard (fails loudly in validation)

    // overlays: aggb region (SN*384 floats) is dead after k_vmid_mfma;
    // node_emb + vnode_emb need N*384 floats <= SN*384.
    float* node_emb  = (float*)aggb;
    float* vnode_emb = node_emb + (size_t)N * 192;

    k_init<<<(N + 255) / 256, 256, 0, stream>>>(t_max, cnt, cursor, colsum, N);
    k_tmax_cnt<<<(E + 255) / 256, 256, 0, stream>>>(src, ts, t_max, cnt, E);
    k_scan<<<1, 1024, 0, stream>>>(cnt, offsets, N);
    k_scatter<<<(E + 255) / 256, 256, 0, stream>>>(src, offsets, cursor, sorted, E);
    k_aexp<<<SN / 32, 256, 0, stream>>>(A_r, offsets, rowsum, colsum, AexpT, N);
    k_agg<<<SN / 4, 256, 0, stream>>>(tgt, ts, sorted, offsets, t_max, memory, nodef,
                                      lambs, aggb, cnt3, has_msg, N);
    k_mf<<<(N * 3 + 31) / 32, 256, 0, stream>>>(aggb, mf_W1, mf_b1, mf_W2, mf_b2, msg_feat, N * 3);
    k_vmid_mfma<<<12 * VCM, 256, 0, stream>>>(AexpT, aggb, cnt3, vpart);
    k_vred<<<(224 * 768 + 255) / 256, 256, 0, stream>>>(vpart, colsum, vmid);
    k_ffr<<<42, 256, 0, stream>>>(vmid, ffr_W1, ffr_b1, ffr_W2, ffr_b2, vmem, vlast,
                                  lambs, now_time, vemb);
    k_newmem<<<N, 192, 0, stream>>>(memory, msg_feat, cnt3, t_max, last_upd, has_msg,
                                    lambs, node_emb, N);
    k_vnode<<<(N + 31) / 32, 192, 0, stream>>>(A_r, rowsum, vemb, vnode_emb, N);
    k_et_st<<<(N + 15) / 16, 256, 0, stream>>>(node_emb, vnode_emb, et_W, et_b, st_W, st_b,
                                               static_emb, lamb, (float*)d_out, N);
}

// Round 4
// 457.315 us; speedup vs baseline: 3.2443x; 1.8775x over previous
//
#include <hip/hip_runtime.h>

static __device__ __forceinline__ float lky(float x) { return x > 0.f ? x : 0.01f * x; }

static __device__ __forceinline__ unsigned short f2bf(float x) {
    unsigned int u = __float_as_uint(x);
    unsigned int r = (u + 0x7FFFu + ((u >> 16) & 1u)) >> 16;
    return (unsigned short)r;
}
static __device__ __forceinline__ float bf2f(unsigned short x) {
    return __uint_as_float((unsigned int)x << 16);
}

typedef __attribute__((ext_vector_type(8))) short short8;
typedef __attribute__((ext_vector_type(4))) float f32x4;

constexpr int SN  = 50048;   // padded node count (multiple of 64)
constexpr int KLV = 1216;    // K(nodes) per split-K chunk (multiple of 32)
constexpr int VCM = 42;      // ceil(SN/KLV)

// ---------------- init ----------------
__global__ void k_init(float* t_max, int* cnt, int* cursor, float* colsum, int N) {
    int i = blockIdx.x * 256 + threadIdx.x;
    if (i < N) { t_max[i] = -1.0f; cnt[i] = 0; cursor[i] = 0; }
    if (i < 224) colsum[i] = 0.0f;
}

// ---------------- weight transpose to bf16: dst[c*K+k] = src[k*C+c] ----------------
__global__ void k_tbf(const float* __restrict__ src, unsigned short* __restrict__ dst,
                      int K, int C) {
    int i = blockIdx.x * 256 + threadIdx.x;
    if (i >= K * C) return;
    int c = i / K, k = i % K;
    dst[i] = f2bf(src[k * C + c]);
}

// ---------------- per-edge t_max / counts ----------------
__global__ void k_tmax_cnt(const int* __restrict__ src, const float* __restrict__ ts,
                           float* t_max, int* cnt, int E) {
    int e = blockIdx.x * 256 + threadIdx.x;
    if (e >= E) return;
    int s = src[e];
    atomicMax((int*)(t_max + s), __float_as_int(ts[e]));   // ts >= 0, int-monotone
    atomicAdd(cnt + s, 1);
}

// ---------------- exclusive scan over counts (single block) ----------------
__global__ __launch_bounds__(1024) void k_scan(const int* __restrict__ cnt,
                                               int* __restrict__ offsets, int N) {
    __shared__ int wsum[16];
    __shared__ int s_run;
    int t = threadIdx.x;
    int lane = t & 63, wid = t >> 6;
    if (t == 0) s_run = 0;
    __syncthreads();
    int nchunk = (N + 1023) >> 10;
    for (int c = 0; c < nchunk; ++c) {
        int i = (c << 10) + t;
        int v = (i < N) ? cnt[i] : 0;
        int x = v;
        #pragma unroll
        for (int d = 1; d < 64; d <<= 1) {
            int y = __shfl_up(x, d, 64);
            if (lane >= d) x += y;
        }
        if (lane == 63) wsum[wid] = x;
        __syncthreads();
        int wbase = 0;
        #pragma unroll
        for (int w = 0; w < 16; ++w) wbase += (w < wid) ? wsum[w] : 0;
        int run = s_run;
        if (i < N) offsets[i] = run + wbase + x - v;
        __syncthreads();
        if (t == 1023) s_run = run + wbase + x;
        __syncthreads();
    }
    if (t == 0) offsets[N] = s_run;
}

// ---------------- scatter edges into per-node buckets ----------------
__global__ void k_scatter(const int* __restrict__ src, const int* __restrict__ offsets,
                          int* cursor, int* sorted, int E) {
    int e = blockIdx.x * 256 + threadIdx.x;
    if (e >= E) return;
    int s = src[e];
    int pos = offsets[s] + atomicAdd(cursor + s, 1);
    sorted[pos] = e;
}

// ---------------- A_r pass: rowsum, colsum, masked AexpT + unmasked Aexp_rm ----------------
__global__ __launch_bounds__(256) void k_aexp(
        const float* __restrict__ A_r, const int* __restrict__ offsets,
        float* __restrict__ rowsum, float* __restrict__ colsum,
        unsigned short* __restrict__ AexpT, unsigned short* __restrict__ Aexp_rm, int N) {
    __shared__ float sA[32][226];
    __shared__ int soff[33];
    int t = threadIdx.x;
    int n0 = blockIdx.x * 32;
    for (int idx = t; idx < 32 * 224; idx += 256) {
        int n = idx / 224, c = idx % 224;
        int gn = n0 + n;
        float e = (gn < N) ? __expf(A_r[(long)gn * 224 + c]) : 0.f;
        sA[n][c] = e;
    }
    if (t < 33) soff[t] = offsets[min(n0 + t, N)];
    __syncthreads();
    // rowsum: 8 lanes per node
    {
        int n = t >> 3, l8 = t & 7;
        float s = 0.f;
        for (int c = l8; c < 224; c += 8) s += sA[n][c];
        #pragma unroll
        for (int d = 1; d < 8; d <<= 1) s += __shfl_xor(s, d, 64);
        if (l8 == 0 && n0 + n < N) rowsum[n0 + n] = s;
    }
    if (t < 224) {
        // colsum partials
        float s = 0.f;
        #pragma unroll
        for (int n = 0; n < 32; ++n) s += sA[n][t];
        atomicAdd(colsum + t, s);
        // unmasked row-major bf16 (coalesced: 224 threads write one row at a time)
        #pragma unroll 4
        for (int r = 0; r < 32; ++r)
            Aexp_rm[(size_t)(n0 + r) * 224 + t] = f2bf(sA[r][t]);
        // masked transposed bf16
        unsigned int wbuf[16];
        #pragma unroll
        for (int k = 0; k < 16; ++k) {
            int n_a = 2 * k, n_b = 2 * k + 1;
            float va = (soff[n_a + 1] > soff[n_a]) ? sA[n_a][t] : 0.f;
            float vb = (soff[n_b + 1] > soff[n_b]) ? sA[n_b][t] : 0.f;
            wbuf[k] = (unsigned int)f2bf(va) | ((unsigned int)f2bf(vb) << 16);
        }
        unsigned short* dst = AexpT + (size_t)t * SN + n0;
        #pragma unroll
        for (int k = 0; k < 4; ++k) *(uint4*)(dst + k * 8) = *(uint4*)&wbuf[k * 4];
    }
}

// ---------------- per-node aggregation: one wave per node, bf16 output ----------------
__global__ __launch_bounds__(256) void k_agg(
        const int* __restrict__ tgt, const float* __restrict__ ts,
        const int* __restrict__ sorted, const int* __restrict__ offsets,
        const float* __restrict__ t_max, const float* __restrict__ memory,
        const float* __restrict__ nodef, const float* __restrict__ lambs,
        unsigned short* __restrict__ aggb, float* __restrict__ cnt3,
        int* __restrict__ has_msg, int N) {
    int wid = threadIdx.x >> 6, lane = threadIdx.x & 63;
    int n = blockIdx.x * 4 + wid;      // n < SN (grid = SN/4)
    size_t rb = (size_t)n * 3;
    if (n >= N) {                       // zero-fill padding rows
        #pragma unroll
        for (int l = 0; l < 3; ++l) {
            unsigned short* row = aggb + (rb + l) * 256;
            #pragma unroll
            for (int k = 0; k < 4; ++k) row[k * 64 + lane] = 0;
            if (lane == 0) cnt3[rb + l] = 0.f;
        }
        return;
    }
    int beg = offsets[n], end = offsets[n + 1];
    float lb0 = lambs[0], lb1 = lambs[1], lb2 = lambs[2];
    float tm = t_max[n];
    float acc[3][4];
    float accc[3];
    #pragma unroll
    for (int l = 0; l < 3; ++l) {
        accc[l] = 0.f;
        #pragma unroll
        for (int k = 0; k < 4; ++k) acc[l][k] = 0.f;
    }
    for (int idx = beg; idx < end; ++idx) {
        int e = sorted[idx];
        int tt = tgt[e];
        float d = tm - ts[e];
        const float* mrow = memory + (long)tt * 195;
        float v0 = mrow[lane]       / mrow[64];
        float v1 = mrow[65 + lane]  / mrow[129];
        float v2 = mrow[130 + lane] / mrow[194];
        float v3 = nodef[(long)tt * 64 + lane];
        float w0 = __expf(-lb0 * d), w1 = __expf(-lb1 * d), w2 = __expf(-lb2 * d);
        acc[0][0] += w0 * v0; acc[0][1] += w0 * v1; acc[0][2] += w0 * v2; acc[0][3] += w0 * v3; accc[0] += w0;
        acc[1][0] += w1 * v0; acc[1][1] += w1 * v1; acc[1][2] += w1 * v2; acc[1][3] += w1 * v3; accc[1] += w1;
        acc[2][0] += w2 * v0; acc[2][1] += w2 * v1; acc[2][2] += w2 * v2; acc[2][3] += w2 * v3; accc[2] += w2;
    }
    #pragma unroll
    for (int l = 0; l < 3; ++l) {
        unsigned short* row = aggb + (rb + l) * 256;
        #pragma unroll
        for (int k = 0; k < 4; ++k) row[k * 64 + lane] = f2bf(acc[l][k]);
        if (lane == 0) cnt3[rb + l] = accc[l];
    }
    if (lane == 0) has_msg[n] = (end > beg) ? 1 : 0;
}

// ---------------- mf MLP via MFMA: (3N,256) bf16 -> relu(128) -> relu(64) ----------------
__global__ __launch_bounds__(256) void k_mf_mfma(
        const unsigned short* __restrict__ aggb,
        const unsigned short* __restrict__ W1T, const float* __restrict__ b1,
        const unsigned short* __restrict__ W2T, const float* __restrict__ b2,
        float* __restrict__ msg_feat, int NROWS) {
    __shared__ unsigned short As[64 * 264];
    __shared__ unsigned short Hs[64 * 136];
    int t = threadIdx.x, lane = t & 63, w = t >> 6;
    int lr = lane & 15, kg = lane >> 4;
    int row0 = blockIdx.x * 64;
    {   // stage A: 64 rows x 256 bf16, 4 threads/row
        int r = t >> 2, s4 = t & 3;
        const uint4* src = (const uint4*)(aggb + (size_t)(row0 + r) * 256 + s4 * 64);
        uint4* dst = (uint4*)(As + r * 264 + s4 * 64);
        #pragma unroll
        for (int u = 0; u < 8; ++u) dst[u] = src[u];
    }
    __syncthreads();
    // layer 1: wave w -> cols [w*32, w*32+32)
    int n0 = w * 32;
    f32x4 acc[4][2];
    #pragma unroll
    for (int m = 0; m < 4; ++m) {
        acc[m][0] = (f32x4){0.f, 0.f, 0.f, 0.f};
        acc[m][1] = (f32x4){0.f, 0.f, 0.f, 0.f};
    }
    for (int kk = 0; kk < 8; ++kk) {
        short8 bf0 = *(const short8*)(W1T + (size_t)(n0 + lr) * 256 + kk * 32 + kg * 8);
        short8 bf1 = *(const short8*)(W1T + (size_t)(n0 + 16 + lr) * 256 + kk * 32 + kg * 8);
        #pragma unroll
        for (int m = 0; m < 4; ++m) {
            short8 af = *(const short8*)(As + (m * 16 + lr) * 264 + kk * 32 + kg * 8);
            acc[m][0] = __builtin_amdgcn_mfma_f32_16x16x32_bf16(af, bf0, acc[m][0], 0, 0, 0);
            acc[m][1] = __builtin_amdgcn_mfma_f32_16x16x32_bf16(af, bf1, acc[m][1], 0, 0, 0);
        }
    }
    float bb0 = b1[n0 + lr], bb1 = b1[n0 + 16 + lr];
    #pragma unroll
    for (int m = 0; m < 4; ++m)
        #pragma unroll
        for (int j = 0; j < 4; ++j) {
            int row = m * 16 + kg * 4 + j;
            Hs[row * 136 + n0 + lr]      = f2bf(fmaxf(acc[m][0][j] + bb0, 0.f));
            Hs[row * 136 + n0 + 16 + lr] = f2bf(fmaxf(acc[m][1][j] + bb1, 0.f));
        }
    __syncthreads();
    // layer 2: wave w -> cols [w*16, w*16+16)
    int c0 = w * 16;
    f32x4 a2[4];
    #pragma unroll
    for (int m = 0; m < 4; ++m) a2[m] = (f32x4){0.f, 0.f, 0.f, 0.f};
    for (int kk = 0; kk < 4; ++kk) {
        short8 bf = *(const short8*)(W2T + (size_t)(c0 + lr) * 128 + kk * 32 + kg * 8);
        #pragma unroll
        for (int m = 0; m < 4; ++m) {
            short8 af = *(const short8*)(Hs + (m * 16 + lr) * 136 + kk * 32 + kg * 8);
            a2[m] = __builtin_amdgcn_mfma_f32_16x16x32_bf16(af, bf, a2[m], 0, 0, 0);
        }
    }
    float b2v = b2[c0 + lr];
    #pragma unroll
    for (int m = 0; m < 4; ++m)
        #pragma unroll
        for (int j = 0; j < 4; ++j) {
            int row = row0 + m * 16 + kg * 4 + j;
            if (row < NROWS)
                msg_feat[(size_t)row * 64 + c0 + lr] = fmaxf(a2[m][j] + b2v, 0.f);
        }
}

// ---------------- vmid via bf16 MFMA, split-K; B gathered from bf16 agg ----------------
__global__ __launch_bounds__(256) void k_vmid_mfma(
        const unsigned short* __restrict__ AexpT, const unsigned short* __restrict__ aggb,
        const float* __restrict__ cnt3, float* __restrict__ vpart) {
    __shared__ unsigned short As[112 * 40];   // 112 rows x 32 shorts (stride 40)
    __shared__ float sDinv[32];
    int bx = blockIdx.x;
    int chunk = bx / 12, tile = bx % 12;
    int r0 = (tile & 1) * 112;
    int ft = tile >> 1;                 // 0..5
    int l = ft >> 1, fo = (ft & 1) * 128;
    int t = threadIdx.x, lane = t & 63, w = t >> 6;
    int lr = lane & 15, kg = lane >> 4;
    f32x4 acc[7][2];
    #pragma unroll
    for (int q = 0; q < 7; ++q) {
        acc[q][0] = (f32x4){0.f, 0.f, 0.f, 0.f};
        acc[q][1] = (f32x4){0.f, 0.f, 0.f, 0.f};
    }
    int nbeg = chunk * KLV;
    int nsteps = min(KLV, SN - nbeg) >> 5;
    int colbase = fo + w * 32 + lr;
    for (int s = 0; s < nsteps; ++s) {
        int n0 = nbeg + s * 32;
        if (t < 224) {                   // stage A: full 32 shorts per row
            int srow = t >> 1, sseg = t & 1;
            const uint4* ap = (const uint4*)(AexpT + (size_t)(r0 + srow) * SN + n0) + sseg * 2;
            uint4 v0 = ap[0];
            uint4 v1 = ap[1];
            *(uint4*)&As[srow * 40 + sseg * 16]     = v0;
            *(uint4*)&As[srow * 40 + sseg * 16 + 8] = v1;
        } else {                          // stage 1/den for 32 nodes
            int k = t - 224;
            sDinv[k] = 1.f / fmaxf(cnt3[(size_t)(n0 + k) * 3 + l], 1e-6f);
        }
        __syncthreads();
        short8 b0, b1;
        #pragma unroll
        for (int j = 0; j < 8; ++j) {
            int kk = kg * 8 + j;
            float dv = sDinv[kk];
            const unsigned short* brow = aggb + ((size_t)(n0 + kk) * 3 + l) * 256 + colbase;
            b0[j] = (short)f2bf(bf2f(brow[0])  * dv);
            b1[j] = (short)f2bf(bf2f(brow[16]) * dv);
        }
        #pragma unroll
        for (int q = 0; q < 7; ++q) {
            short8 af = *(const short8*)&As[(q * 16 + lr) * 40 + kg * 8];
            acc[q][0] = __builtin_amdgcn_mfma_f32_16x16x32_bf16(af, b0, acc[q][0], 0, 0, 0);
            acc[q][1] = __builtin_amdgcn_mfma_f32_16x16x32_bf16(af, b1, acc[q][1], 0, 0, 0);
        }
        __syncthreads();
    }
    float* outp = vpart + (size_t)chunk * 172032;
    #pragma unroll
    for (int q = 0; q < 7; ++q) {
        int row = r0 + q * 16 + kg * 4;
        #pragma unroll
        for (int p = 0; p < 2; ++p) {
            int col = l * 256 + fo + w * 32 + p * 16 + lr;
            #pragma unroll
            for (int j = 0; j < 4; ++j)
                outp[(size_t)(row + j) * 768 + col] = acc[q][p][j];
        }
    }
}

// ---------------- reduce vpart over chunks, divide by colsum ----------------
__global__ void k_vred(const float* __restrict__ vpart, const float* __restrict__ colsum,
                       float* __restrict__ vmid) {
    int idx = blockIdx.x * 256 + threadIdx.x;
    if (idx >= 224 * 768) return;
    float s = 0.f;
    for (int c = 0; c < VCM; ++c) s += vpart[(long)c * (224 * 768) + idx];
    vmid[idx] = s / colsum[idx / 768];
}

// ---------------- ffr MLP (672 rows) + virtual-memory decay -> vembT (bf16) ----------------
__global__ __launch_bounds__(256) void k_ffr(
        const float* __restrict__ vmid, const float* __restrict__ W1, const float* __restrict__ b1,
        const float* __restrict__ W2, const float* __restrict__ b2,
        const float* __restrict__ vmem, const float* __restrict__ vlast,
        const float* __restrict__ lambs, const float* __restrict__ now_time,
        unsigned short* __restrict__ vembT) {
    __shared__ float sin_[16][260];
    __shared__ float svh[16][260];
    int row0 = blockIdx.x * 16;
    int t = threadIdx.x;
    #pragma unroll
    for (int k = 0; k < 16; ++k) {
        int idx = t + k * 256;
        int r = idx >> 8, f = idx & 255;
        sin_[r][f] = vmid[(long)(row0 + r) * 256 + f];
    }
    __syncthreads();
    {   // layer 1: 16 x 256, 4r x 4c
        int cg = t & 63, rg = t >> 6;
        int c0 = cg * 4, r0 = rg * 4;
        float acc[4][4];
        #pragma unroll
        for (int i = 0; i < 4; ++i)
            #pragma unroll
            for (int j = 0; j < 4; ++j) acc[i][j] = 0.f;
        for (int f0 = 0; f0 < 256; f0 += 4) {
            float4 a[4];
            #pragma unroll
            for (int i = 0; i < 4; ++i) a[i] = *(const float4*)&sin_[r0 + i][f0];
            #pragma unroll
            for (int ff = 0; ff < 4; ++ff) {
                float4 w = *(const float4*)&W1[(long)(f0 + ff) * 256 + c0];
                #pragma unroll
                for (int i = 0; i < 4; ++i) {
                    float av = (&a[i].x)[ff];
                    acc[i][0] += av * w.x; acc[i][1] += av * w.y;
                    acc[i][2] += av * w.z; acc[i][3] += av * w.w;
                }
            }
        }
        #pragma unroll
        for (int i = 0; i < 4; ++i)
            #pragma unroll
            for (int j = 0; j < 4; ++j)
                svh[r0 + i][c0 + j] = lky(acc[i][j] + b1[c0 + j]);
    }
    __syncthreads();
    {   // layer 2: 16 x 64, 2r x 2c + decay epilogue
        int cg = t & 31, rg = t >> 5;
        int c0 = cg * 2, r0 = rg * 2;
        float acc[2][2];
        acc[0][0] = acc[0][1] = acc[1][0] = acc[1][1] = 0.f;
        for (int f0 = 0; f0 < 256; f0 += 4) {
            float4 a[2];
            #pragma unroll
            for (int i = 0; i < 2; ++i) a[i] = *(const float4*)&svh[r0 + i][f0];
            #pragma unroll
            for (int ff = 0; ff < 4; ++ff) {
                float2 w = *(const float2*)&W2[(long)(f0 + ff) * 64 + c0];
                #pragma unroll
                for (int i = 0; i < 2; ++i) {
                    float av = (&a[i].x)[ff];
                    acc[i][0] += av * w.x; acc[i][1] += av * w.y;
                }
            }
        }
        float nowv = now_time[0];
        #pragma unroll
        for (int i = 0; i < 2; ++i) {
            int row = row0 + r0 + i;           // row = rr*3 + l
            int rr = row / 3, l = row % 3;
            float vd = __expf(-lambs[l] * (nowv - vlast[rr]));
            #pragma unroll
            for (int j = 0; j < 2; ++j) {
                float v = lky(acc[i][j] + b2[c0 + j]);
                int m = c0 + j;
                vembT[(size_t)(l * 64 + m) * 224 + rr] =
                    f2bf(vmem[(long)rr * 192 + l * 64 + m] * vd + v);
            }
        }
    }
}

// ---------------- new_mem -> node_emb (bf16) ----------------
__global__ void k_newmem(const float* __restrict__ memory, const float* __restrict__ msg_feat,
        const float* __restrict__ cnt3, const float* __restrict__ t_max,
        const float* __restrict__ last_update, const int* __restrict__ has_msg,
        const float* __restrict__ lambs, unsigned short* __restrict__ node_emb, int N) {
    int n = blockIdx.x;
    int j = threadIdx.x;                 // 0..191
    int l = j >> 6, m = j & 63;
    int has = has_msg[n];
    float dt = has ? (t_max[n] - last_update[n]) : 0.f;
    float decay = __expf(-lambs[l] * dt);
    long mb = (long)n * 195 + l * 65;
    float num = memory[mb + m];
    float den = memory[mb + 64];
    if (has) {
        num = num * decay + msg_feat[(long)n * 192 + j];
        den = den * decay + cnt3[(size_t)n * 3 + l];
    }
    node_emb[(size_t)n * 192 + j] = f2bf(num / fmaxf(den, 1e-6f));
}

// ---------------- vnode_emb = row-softmax(A_r) @ v_emb via MFMA ----------------
__global__ __launch_bounds__(256) void k_vnode_mfma(
        const unsigned short* __restrict__ Aexp_rm, const unsigned short* __restrict__ vembT,
        const float* __restrict__ rowsum, unsigned short* __restrict__ vnode_emb, int N) {
    __shared__ unsigned short As[64 * 232];
    __shared__ float sRS[64];
    int t = threadIdx.x, lane = t & 63, w = t >> 6;
    int lr = lane & 15, kg = lane >> 4;
    int row0 = blockIdx.x * 64;
    {
        int r = t >> 2, sg = t & 3;
        const uint4* src = (const uint4*)(Aexp_rm + (size_t)(row0 + r) * 224 + sg * 56);
        uint4* dst = (uint4*)(As + r * 232 + sg * 56);
        #pragma unroll
        for (int u = 0; u < 7; ++u) dst[u] = src[u];
    }
    if (t < 64) sRS[t] = rowsum[min(row0 + t, N - 1)];
    __syncthreads();
    int n0 = w * 48;                      // 192 cols / 4 waves
    f32x4 acc[4][3];
    #pragma unroll
    for (int m = 0; m < 4; ++m)
        #pragma unroll
        for (int nt = 0; nt < 3; ++nt) acc[m][nt] = (f32x4){0.f, 0.f, 0.f, 0.f};
    for (int kk = 0; kk < 7; ++kk) {
        short8 bf[3];
        #pragma unroll
        for (int nt = 0; nt < 3; ++nt)
            bf[nt] = *(const short8*)(vembT + (size_t)(n0 + nt * 16 + lr) * 224 + kk * 32 + kg * 8);
        #pragma unroll
        for (int m = 0; m < 4; ++m) {
            short8 af = *(const short8*)(As + (m * 16 + lr) * 232 + kk * 32 + kg * 8);
            #pragma unroll
            for (int nt = 0; nt < 3; ++nt)
                acc[m][nt] = __builtin_amdgcn_mfma_f32_16x16x32_bf16(af, bf[nt], acc[m][nt], 0, 0, 0);
        }
    }
    #pragma unroll
    for (int m = 0; m < 4; ++m)
        #pragma unroll
        for (int j = 0; j < 4; ++j) {
            int row = row0 + m * 16 + kg * 4 + j;
            if (row < N) {
                float inv = 1.f / sRS[row - row0];
                #pragma unroll
                for (int nt = 0; nt < 3; ++nt)
                    vnode_emb[(size_t)row * 192 + n0 + nt * 16 + lr] = f2bf(acc[m][nt][j] * inv);
            }
        }
}

// ---------------- et + st + output blend via MFMA ----------------
__global__ __launch_bounds__(256) void k_et_st_mfma(
        const unsigned short* __restrict__ ne, const unsigned short* __restrict__ ve,
        const unsigned short* __restrict__ etWT, const float* __restrict__ etb,
        const unsigned short* __restrict__ stWT, const float* __restrict__ stb,
        const float* __restrict__ stat, const float* __restrict__ lamb,
        float* __restrict__ out, int N) {
    __shared__ unsigned short As[128 * 200];   // rows 0-63: node, 64-127: vnode
    __shared__ unsigned short Hs[64 * 136];    // st input [64 rows][128 cols]
    int t = threadIdx.x, lane = t & 63, w = t >> 6;
    int lr = lane & 15, kg = lane >> 4;
    int row0 = blockIdx.x * 64;
    {
        int r = t >> 2, sg = t & 3;
        const uint4* sn = (const uint4*)(ne + (size_t)(row0 + r) * 192 + sg * 48);
        const uint4* sv = (const uint4*)(ve + (size_t)(row0 + r) * 192 + sg * 48);
        uint4* dn = (uint4*)(As + (size_t)r * 200 + sg * 48);
        uint4* dv = (uint4*)(As + (size_t)(64 + r) * 200 + sg * 48);
        #pragma unroll
        for (int u = 0; u < 6; ++u) { dn[u] = sn[u]; dv[u] = sv[u]; }
    }
    __syncthreads();
    // et layer: wave w -> cols [w*16, w*16+16), both halves; K=192
    int c0 = w * 16;
    f32x4 acc[2][4];
    #pragma unroll
    for (int h = 0; h < 2; ++h)
        #pragma unroll
        for (int m = 0; m < 4; ++m) acc[h][m] = (f32x4){0.f, 0.f, 0.f, 0.f};
    for (int kk = 0; kk < 6; ++kk) {
        short8 bf = *(const short8*)(etWT + (size_t)(c0 + lr) * 192 + kk * 32 + kg * 8);
        #pragma unroll
        for (int h = 0; h < 2; ++h)
            #pragma unroll
            for (int m = 0; m < 4; ++m) {
                short8 af = *(const short8*)(As + (size_t)(h * 64 + m * 16 + lr) * 200 + kk * 32 + kg * 8);
                acc[h][m] = __builtin_amdgcn_mfma_f32_16x16x32_bf16(af, bf, acc[h][m], 0, 0, 0);
            }
    }
    float bb = etb[c0 + lr];
    #pragma unroll
    for (int h = 0; h < 2; ++h)
        #pragma unroll
        for (int m = 0; m < 4; ++m)
            #pragma unroll
            for (int j = 0; j < 4; ++j)
                Hs[(m * 16 + kg * 4 + j) * 136 + h * 64 + c0 + lr] = f2bf(lky(acc[h][m][j] + bb));
    __syncthreads();
    // st layer: wave w -> cols [w*32, w*32+32); K=128
    int c0s = w * 32;
    f32x4 a2[4][2];
    #pragma unroll
    for (int m = 0; m < 4; ++m) { a2[m][0] = (f32x4){0.f,0.f,0.f,0.f}; a2[m][1] = (f32x4){0.f,0.f,0.f,0.f}; }
    for (int kk = 0; kk < 4; ++kk) {
        short8 bf0 = *(const short8*)(stWT + (size_t)(c0s + lr) * 128 + kk * 32 + kg * 8);
        short8 bf1 = *(const short8*)(stWT + (size_t)(c0s + 16 + lr) * 128 + kk * 32 + kg * 8);
        #pragma unroll
        for (int m = 0; m < 4; ++m) {
            short8 af = *(const short8*)(Hs + (m * 16 + lr) * 136 + kk * 32 + kg * 8);
            a2[m][0] = __builtin_amdgcn_mfma_f32_16x16x32_bf16(af, bf0, a2[m][0], 0, 0, 0);
            a2[m][1] = __builtin_amdgcn_mfma_f32_16x16x32_bf16(af, bf1, a2[m][1], 0, 0, 0);
        }
    }
    float lam = lamb[0];
    float sb0 = stb[c0s + lr], sb1 = stb[c0s + 16 + lr];
    #pragma unroll
    for (int m = 0; m < 4; ++m)
        #pragma unroll
        for (int j = 0; j < 4; ++j) {
            int n = row0 + m * 16 + kg * 4 + j;
            if (n < N) {
                int ca = c0s + lr, cb = c0s + 16 + lr;
                float va = lky(a2[m][0][j] + sb0);
                float vb = lky(a2[m][1][j] + sb1);
                out[(size_t)n * 128 + ca] = lam * stat[(size_t)n * 128 + ca] + (1.f - lam) * va;
                out[(size_t)n * 128 + cb] = lam * stat[(size_t)n * 128 + cb] + (1.f - lam) * vb;
            }
        }
}

extern "C" void kernel_launch(void* const* d_in, const int* in_sizes, int n_in,
                              void* d_out, int out_size, void* d_ws, size_t ws_size,
                              hipStream_t stream) {
    const int*   src        = (const int*)d_in[0];
    const int*   tgt        = (const int*)d_in[1];
    const float* ts         = (const float*)d_in[2];
    const float* now_time   = (const float*)d_in[3];
    const float* nodef      = (const float*)d_in[5];
    const float* memory     = (const float*)d_in[6];
    const float* last_upd   = (const float*)d_in[7];
    const float* vmem       = (const float*)d_in[8];
    const float* vlast      = (const float*)d_in[9];
    const float* A_r        = (const float*)d_in[10];
    const float* static_emb = (const float*)d_in[11];
    const float* lamb       = (const float*)d_in[12];
    const float* lambs      = (const float*)d_in[13];
    const float* mf_W1      = (const float*)d_in[14];
    const float* mf_b1      = (const float*)d_in[15];
    const float* mf_W2      = (const float*)d_in[16];
    const float* mf_b2      = (const float*)d_in[17];
    const float* ffr_W1     = (const float*)d_in[18];
    const float* ffr_b1     = (const float*)d_in[19];
    const float* ffr_W2     = (const float*)d_in[20];
    const float* ffr_b2     = (const float*)d_in[21];
    const float* et_W       = (const float*)d_in[22];
    const float* et_b       = (const float*)d_in[23];
    const float* st_W       = (const float*)d_in[24];
    const float* st_b       = (const float*)d_in[25];

    int E = in_sizes[0];
    int N = in_sizes[7];

    float* ws = (float*)d_ws;
    size_t off = 0;
    auto alloc = [&](size_t nf) { float* p = ws + off; off += (nf + 63) & ~(size_t)63; return p; };
    unsigned short* aggb  = (unsigned short*)alloc((size_t)SN * 384);     // SN*3 rows x 256 bf16
    float* msg_feat = alloc((size_t)N * 192);
    unsigned short* AexpT   = (unsigned short*)alloc((size_t)224 * SN / 2);
    unsigned short* Aexp_rm = (unsigned short*)alloc((size_t)SN * 224 / 2);
    float* vpart    = alloc((size_t)VCM * 172032);
    float* vmid     = alloc(224 * 768);
    unsigned short* vembT = (unsigned short*)alloc((size_t)192 * 224 / 2 + 64);
    float* t_max    = alloc(N);
    float* rowsum   = alloc(N);
    float* cnt3     = alloc((size_t)SN * 3);
    float* colsum   = alloc(256);
    unsigned short* W1T  = (unsigned short*)alloc(128 * 256 / 2);
    unsigned short* W2T  = (unsigned short*)alloc(64 * 128 / 2);
    unsigned short* etWT = (unsigned short*)alloc(64 * 192 / 2);
    unsigned short* stWT = (unsigned short*)alloc(128 * 128 / 2);
    int*   cnt      = (int*)alloc(N);
    int*   offsets  = (int*)alloc(N + 1);
    int*   cursor   = (int*)alloc(N);
    int*   sorted   = (int*)alloc(E);
    int*   has_msg  = (int*)alloc(N);
    if (off * sizeof(float) > ws_size) return;   // workspace guard

    // overlays: aggb region (SN*384 floats) is dead after k_mf_mfma + k_vmid_mfma;
    // node_emb + vnode_emb (bf16, N*384 shorts total) fit easily.
    unsigned short* node_emb  = (unsigned short*)aggb;
    unsigned short* vnode_emb = node_emb + (size_t)N * 192;

    k_init<<<(N + 255) / 256, 256, 0, stream>>>(t_max, cnt, cursor, colsum, N);
    k_tbf<<<(256 * 128 + 255) / 256, 256, 0, stream>>>(mf_W1, W1T, 256, 128);
    k_tbf<<<(128 * 64 + 255) / 256, 256, 0, stream>>>(mf_W2, W2T, 128, 64);
    k_tbf<<<(192 * 64 + 255) / 256, 256, 0, stream>>>(et_W, etWT, 192, 64);
    k_tbf<<<(128 * 128 + 255) / 256, 256, 0, stream>>>(st_W, stWT, 128, 128);
    k_tmax_cnt<<<(E + 255) / 256, 256, 0, stream>>>(src, ts, t_max, cnt, E);
    k_scan<<<1, 1024, 0, stream>>>(cnt, offsets, N);
    k_scatter<<<(E + 255) / 256, 256, 0, stream>>>(src, offsets, cursor, sorted, E);
    k_aexp<<<SN / 32, 256, 0, stream>>>(A_r, offsets, rowsum, colsum, AexpT, Aexp_rm, N);
    k_agg<<<SN / 4, 256, 0, stream>>>(tgt, ts, sorted, offsets, t_max, memory, nodef,
                                      lambs, aggb, cnt3, has_msg, N);
    k_mf_mfma<<<SN * 3 / 64, 256, 0, stream>>>(aggb, W1T, mf_b1, W2T, mf_b2, msg_feat, N * 3);
    k_vmid_mfma<<<12 * VCM, 256, 0, stream>>>(AexpT, aggb, cnt3, vpart);
    k_vred<<<(224 * 768 + 255) / 256, 256, 0, stream>>>(vpart, colsum, vmid);
    k_ffr<<<42, 256, 0, stream>>>(vmid, ffr_W1, ffr_b1, ffr_W2, ffr_b2, vmem, vlast,
                                  lambs, now_time, vembT);
    k_newmem<<<N, 192, 0, stream>>>(memory, msg_feat, cnt3, t_max, last_upd, has_msg,
                                    lambs, node_emb, N);
    k_vnode_mfma<<<SN / 64, 256, 0, stream>>>(Aexp_rm, vembT, rowsum, vnode_emb, N);
    k_et_st_mfma<<<SN / 64, 256, 0, stream>>>(node_emb, vnode_emb, etWT, et_b, stWT, st_b,
                                              static_emb, lamb, (float*)d_out, N);
}

// Round 5
// 430.973 us; speedup vs baseline: 3.4426x; 1.0611x over previous
//
#include <hip/hip_runtime.h>

static __device__ __forceinline__ float lky(float x) { return x > 0.f ? x : 0.01f * x; }

static __device__ __forceinline__ unsigned short f2bf(float x) {
    unsigned int u = __float_as_uint(x);
    unsigned int r = (u + 0x7FFFu + ((u >> 16) & 1u)) >> 16;
    return (unsigned short)r;
}
static __device__ __forceinline__ float bf2f(unsigned short x) {
    return __uint_as_float((unsigned int)x << 16);
}
static __device__ __forceinline__ unsigned int pack2bf(float lo, float hi) {
    return (unsigned int)f2bf(lo) | ((unsigned int)f2bf(hi) << 16);
}

typedef __attribute__((ext_vector_type(8))) short short8;
typedef __attribute__((ext_vector_type(4))) float f32x4;

constexpr int SN  = 50048;   // padded node count (multiple of 64)
constexpr int KLV = 1216;    // K(nodes) per split-K chunk (multiple of 32)
constexpr int VCM = 42;      // ceil(SN/KLV)

// ---------------- init ----------------
__global__ void k_init(float* t_max, int* cnt, int* cursor, float* colsum, int N) {
    int i = blockIdx.x * 256 + threadIdx.x;
    if (i < N) { t_max[i] = -1.0f; cnt[i] = 0; cursor[i] = 0; }
    if (i < 224) colsum[i] = 0.0f;
}

// ---------------- weight transpose to bf16: dst[c*K+k] = src[k*C+c] ----------------
__global__ void k_tbf(const float* __restrict__ src, unsigned short* __restrict__ dst,
                      int K, int C) {
    int i = blockIdx.x * 256 + threadIdx.x;
    if (i >= K * C) return;
    int c = i / K, k = i % K;
    dst[i] = f2bf(src[k * C + c]);
}

// ---------------- per-edge t_max / counts ----------------
__global__ void k_tmax_cnt(const int* __restrict__ src, const float* __restrict__ ts,
                           float* t_max, int* cnt, int E) {
    int e = blockIdx.x * 256 + threadIdx.x;
    if (e >= E) return;
    int s = src[e];
    atomicMax((int*)(t_max + s), __float_as_int(ts[e]));   // ts >= 0, int-monotone
    atomicAdd(cnt + s, 1);
}

// ---------------- exclusive scan over counts (single block) ----------------
__global__ __launch_bounds__(1024) void k_scan(const int* __restrict__ cnt,
                                               int* __restrict__ offsets, int N) {
    __shared__ int wsum[16];
    __shared__ int s_run;
    int t = threadIdx.x;
    int lane = t & 63, wid = t >> 6;
    if (t == 0) s_run = 0;
    __syncthreads();
    int nchunk = (N + 1023) >> 10;
    for (int c = 0; c < nchunk; ++c) {
        int i = (c << 10) + t;
        int v = (i < N) ? cnt[i] : 0;
        int x = v;
        #pragma unroll
        for (int d = 1; d < 64; d <<= 1) {
            int y = __shfl_up(x, d, 64);
            if (lane >= d) x += y;
        }
        if (lane == 63) wsum[wid] = x;
        __syncthreads();
        int wbase = 0;
        #pragma unroll
        for (int w = 0; w < 16; ++w) wbase += (w < wid) ? wsum[w] : 0;
        int run = s_run;
        if (i < N) offsets[i] = run + wbase + x - v;
        __syncthreads();
        if (t == 1023) s_run = run + wbase + x;
        __syncthreads();
    }
    if (t == 0) offsets[N] = s_run;
}

// ---------------- scatter edges into per-node buckets ----------------
__global__ void k_scatter(const int* __restrict__ src, const int* __restrict__ offsets,
                          int* cursor, int* sorted, int E) {
    int e = blockIdx.x * 256 + threadIdx.x;
    if (e >= E) return;
    int s = src[e];
    int pos = offsets[s] + atomicAdd(cursor + s, 1);
    sorted[pos] = e;
}

// ---------------- precompute normalized target embedding, bf16 [N][256] ----------------
__global__ __launch_bounds__(256) void k_prep(
        const float* __restrict__ memory, const float* __restrict__ nodef,
        unsigned int* __restrict__ temb, int N) {
    int wid = threadIdx.x >> 6, lane = threadIdx.x & 63;
    int n = blockIdx.x * 4 + wid;
    if (n >= N) return;
    const float* mrow = memory + (size_t)n * 195;
    float d0 = mrow[64], d1 = mrow[129], d2 = mrow[194];
    // half A: features 2*lane, 2*lane+1 (l0 for lane<32, l1 for lane>=32)
    int f = 2 * lane;
    float den = (f < 64) ? d0 : d1;
    int offA = (f < 64) ? f : f + 1;
    float va0 = mrow[offA] / den;
    float va1 = mrow[offA + 1] / den;
    // half B: features 128+2*lane (l2 for lane<32, nodef for lane>=32)
    float vb0, vb1;
    if (lane < 32) {
        vb0 = mrow[130 + 2 * lane] / d2;
        vb1 = mrow[131 + 2 * lane] / d2;
    } else {
        const float* nf = nodef + (size_t)n * 64 + 2 * (lane - 32);
        vb0 = nf[0]; vb1 = nf[1];
    }
    temb[(size_t)n * 128 + lane]      = pack2bf(va0, va1);
    temb[(size_t)n * 128 + 64 + lane] = pack2bf(vb0, vb1);
}

// ---------------- A_r pass: rowsum, colsum, bf16 Aexp_rm + AexpT (unmasked) ----------------
__global__ __launch_bounds__(256) void k_aexp(
        const float* __restrict__ A_r,
        float* __restrict__ rowsum, float* __restrict__ colsum,
        unsigned short* __restrict__ AexpT, unsigned short* __restrict__ Aexp_rm, int N) {
    __shared__ unsigned short sE[64][226];   // stride 226 shorts -> 2-way banks (free)
    int t = threadIdx.x, lane = t & 63, w = t >> 6;
    int n0 = blockIdx.x * 64;
    // each wave handles 16 nodes
    for (int i = 0; i < 16; ++i) {
        int n = w * 16 + i;
        int gn = n0 + n;
        float e0 = 0.f, e1 = 0.f, e2 = 0.f, e3 = 0.f;
        if (gn < N) {
            const float* row = A_r + (size_t)gn * 224;
            e0 = __expf(row[lane]);
            e1 = __expf(row[64 + lane]);
            e2 = __expf(row[128 + lane]);
            if (lane < 32) e3 = __expf(row[192 + lane]);
        }
        sE[n][lane]       = f2bf(e0);
        sE[n][64 + lane]  = f2bf(e1);
        sE[n][128 + lane] = f2bf(e2);
        if (lane < 32) sE[n][192 + lane] = f2bf(e3);
        float rs = e0 + e1 + e2 + e3;
        #pragma unroll
        for (int d = 32; d > 0; d >>= 1) rs += __shfl_xor(rs, d, 64);
        if (lane == 0 && gn < N) rowsum[gn] = rs;
    }
    __syncthreads();
    // colsum partials
    if (t < 224) {
        float s = 0.f;
        #pragma unroll 8
        for (int r = 0; r < 64; ++r) s += bf2f(sE[r][t]);
        atomicAdd(colsum + t, s);
    }
    // row-major write, packed uints, coalesced
    {
        unsigned int* dst = (unsigned int*)Aexp_rm;
        for (int i = t; i < 64 * 112; i += 256) {
            int n = i / 112, cp = i % 112;
            unsigned int v = *(const unsigned int*)&sE[n][2 * cp];
            dst[(size_t)(n0 + n) * 112 + cp] = v;
        }
    }
    // transposed write: wave-coalesced 128B runs per r-row
    {
        unsigned int* dst = (unsigned int*)AexpT;
        for (int u = t; u < 224 * 32; u += 256) {
            int r = u >> 5, np = u & 31;
            unsigned int lo = sE[2 * np][r];
            unsigned int hi = sE[2 * np + 1][r];
            dst[(size_t)r * (SN / 2) + (n0 >> 1) + np] = lo | (hi << 16);
        }
    }
}

// ---------------- per-node aggregation: one wave per node, bf16 temb gather ----------------
__global__ __launch_bounds__(256) void k_agg(
        const int* __restrict__ tgt, const float* __restrict__ ts,
        const int* __restrict__ sorted, const int* __restrict__ offsets,
        const float* __restrict__ t_max, const unsigned int* __restrict__ temb,
        const float* __restrict__ lambs,
        unsigned int* __restrict__ aggb, float* __restrict__ cnt3,
        int* __restrict__ has_msg, int N) {
    int wid = threadIdx.x >> 6, lane = threadIdx.x & 63;
    int n = blockIdx.x * 4 + wid;      // n < SN (grid = SN/4)
    size_t rb = (size_t)n * 3;
    if (n >= N) {                       // zero-fill padding rows
        #pragma unroll
        for (int l = 0; l < 3; ++l) {
            unsigned int* row = aggb + (rb + l) * 128;
            row[lane] = 0; row[64 + lane] = 0;
            if (lane == 0) cnt3[rb + l] = 0.f;
        }
        return;
    }
    int beg = offsets[n], end = offsets[n + 1];
    float lb0 = lambs[0], lb1 = lambs[1], lb2 = lambs[2];
    float tm = t_max[n];
    float aa0[3], aa1[3], ab0[3], ab1[3], accc[3];
    #pragma unroll
    for (int l = 0; l < 3; ++l) { aa0[l] = aa1[l] = ab0[l] = ab1[l] = accc[l] = 0.f; }
    for (int idx = beg; idx < end; ++idx) {
        int e = sorted[idx];
        int tt = tgt[e];
        float d = tm - ts[e];
        unsigned int ua = temb[(size_t)tt * 128 + lane];
        unsigned int ub = temb[(size_t)tt * 128 + 64 + lane];
        float a0 = __uint_as_float(ua << 16);
        float a1 = __uint_as_float(ua & 0xffff0000u);
        float b0 = __uint_as_float(ub << 16);
        float b1 = __uint_as_float(ub & 0xffff0000u);
        float w0 = __expf(-lb0 * d), w1 = __expf(-lb1 * d), w2 = __expf(-lb2 * d);
        aa0[0] += w0 * a0; aa1[0] += w0 * a1; ab0[0] += w0 * b0; ab1[0] += w0 * b1; accc[0] += w0;
        aa0[1] += w1 * a0; aa1[1] += w1 * a1; ab0[1] += w1 * b0; ab1[1] += w1 * b1; accc[1] += w1;
        aa0[2] += w2 * a0; aa1[2] += w2 * a1; ab0[2] += w2 * b0; ab1[2] += w2 * b1; accc[2] += w2;
    }
    #pragma unroll
    for (int l = 0; l < 3; ++l) {
        unsigned int* row = aggb + (rb + l) * 128;
        row[lane]      = pack2bf(aa0[l], aa1[l]);
        row[64 + lane] = pack2bf(ab0[l], ab1[l]);
        if (lane == 0) cnt3[rb + l] = accc[l];
    }
    if (lane == 0) has_msg[n] = (end > beg) ? 1 : 0;
}

// ---------------- mf MLP via MFMA: (3N,256) bf16 -> relu(128) -> relu(64) bf16 ----------------
__global__ __launch_bounds__(256) void k_mf_mfma(
        const unsigned short* __restrict__ aggb,
        const unsigned short* __restrict__ W1T, const float* __restrict__ b1,
        const unsigned short* __restrict__ W2T, const float* __restrict__ b2,
        unsigned short* __restrict__ msg_feat, int NROWS) {
    __shared__ unsigned short As[64 * 264];
    __shared__ unsigned short Hs[64 * 136];
    int t = threadIdx.x, lane = t & 63, w = t >> 6;
    int lr = lane & 15, kg = lane >> 4;
    int row0 = blockIdx.x * 64;
    {   // stage A: 64 rows x 256 bf16, 4 threads/row
        int r = t >> 2, s4 = t & 3;
        const uint4* src = (const uint4*)(aggb + (size_t)(row0 + r) * 256 + s4 * 64);
        uint4* dst = (uint4*)(As + r * 264 + s4 * 64);
        #pragma unroll
        for (int u = 0; u < 8; ++u) dst[u] = src[u];
    }
    __syncthreads();
    // layer 1: wave w -> cols [w*32, w*32+32)
    int n0 = w * 32;
    f32x4 acc[4][2];
    #pragma unroll
    for (int m = 0; m < 4; ++m) {
        acc[m][0] = (f32x4){0.f, 0.f, 0.f, 0.f};
        acc[m][1] = (f32x4){0.f, 0.f, 0.f, 0.f};
    }
    for (int kk = 0; kk < 8; ++kk) {
        short8 bf0 = *(const short8*)(W1T + (size_t)(n0 + lr) * 256 + kk * 32 + kg * 8);
        short8 bf1 = *(const short8*)(W1T + (size_t)(n0 + 16 + lr) * 256 + kk * 32 + kg * 8);
        #pragma unroll
        for (int m = 0; m < 4; ++m) {
            short8 af = *(const short8*)(As + (m * 16 + lr) * 264 + kk * 32 + kg * 8);
            acc[m][0] = __builtin_amdgcn_mfma_f32_16x16x32_bf16(af, bf0, acc[m][0], 0, 0, 0);
            acc[m][1] = __builtin_amdgcn_mfma_f32_16x16x32_bf16(af, bf1, acc[m][1], 0, 0, 0);
        }
    }
    float bb0 = b1[n0 + lr], bb1 = b1[n0 + 16 + lr];
    #pragma unroll
    for (int m = 0; m < 4; ++m)
        #pragma unroll
        for (int j = 0; j < 4; ++j) {
            int row = m * 16 + kg * 4 + j;
            Hs[row * 136 + n0 + lr]      = f2bf(fmaxf(acc[m][0][j] + bb0, 0.f));
            Hs[row * 136 + n0 + 16 + lr] = f2bf(fmaxf(acc[m][1][j] + bb1, 0.f));
        }
    __syncthreads();
    // layer 2: wave w -> cols [w*16, w*16+16)
    int c0 = w * 16;
    f32x4 a2[4];
    #pragma unroll
    for (int m = 0; m < 4; ++m) a2[m] = (f32x4){0.f, 0.f, 0.f, 0.f};
    for (int kk = 0; kk < 4; ++kk) {
        short8 bf = *(const short8*)(W2T + (size_t)(c0 + lr) * 128 + kk * 32 + kg * 8);
        #pragma unroll
        for (int m = 0; m < 4; ++m) {
            short8 af = *(const short8*)(Hs + (m * 16 + lr) * 136 + kk * 32 + kg * 8);
            a2[m] = __builtin_amdgcn_mfma_f32_16x16x32_bf16(af, bf, a2[m], 0, 0, 0);
        }
    }
    float b2v = b2[c0 + lr];
    #pragma unroll
    for (int m = 0; m < 4; ++m)
        #pragma unroll
        for (int j = 0; j < 4; ++j) {
            int row = row0 + m * 16 + kg * 4 + j;
            if (row < NROWS)
                msg_feat[(size_t)row * 64 + c0 + lr] = f2bf(fmaxf(a2[m][j] + b2v, 0.f));
        }
}

// ---------------- vmid via bf16 MFMA, split-K; B gathered from bf16 agg ----------------
__global__ __launch_bounds__(256) void k_vmid_mfma(
        const unsigned short* __restrict__ AexpT, const unsigned short* __restrict__ aggb,
        const float* __restrict__ cnt3, float* __restrict__ vpart) {
    __shared__ unsigned short As[112 * 40];   // 112 rows x 32 shorts (stride 40)
    __shared__ float sDinv[32];
    int bx = blockIdx.x;
    int chunk = bx / 12, tile = bx % 12;
    int r0 = (tile & 1) * 112;
    int ft = tile >> 1;                 // 0..5
    int l = ft >> 1, fo = (ft & 1) * 128;
    int t = threadIdx.x, lane = t & 63, w = t >> 6;
    int lr = lane & 15, kg = lane >> 4;
    f32x4 acc[7][2];
    #pragma unroll
    for (int q = 0; q < 7; ++q) {
        acc[q][0] = (f32x4){0.f, 0.f, 0.f, 0.f};
        acc[q][1] = (f32x4){0.f, 0.f, 0.f, 0.f};
    }
    int nbeg = chunk * KLV;
    int nsteps = min(KLV, SN - nbeg) >> 5;
    int colbase = fo + w * 32 + lr;
    for (int s = 0; s < nsteps; ++s) {
        int n0 = nbeg + s * 32;
        if (t < 224) {                   // stage A: full 32 shorts per row
            int srow = t >> 1, sseg = t & 1;
            const uint4* ap = (const uint4*)(AexpT + (size_t)(r0 + srow) * SN + n0) + sseg * 2;
            uint4 v0 = ap[0];
            uint4 v1 = ap[1];
            *(uint4*)&As[srow * 40 + sseg * 16]     = v0;
            *(uint4*)&As[srow * 40 + sseg * 16 + 8] = v1;
        } else {                          // stage 1/den for 32 nodes
            int k = t - 224;
            sDinv[k] = 1.f / fmaxf(cnt3[(size_t)(n0 + k) * 3 + l], 1e-6f);
        }
        __syncthreads();
        short8 b0, b1;
        #pragma unroll
        for (int j = 0; j < 8; ++j) {
            int kk = kg * 8 + j;
            float dv = sDinv[kk];
            const unsigned short* brow = aggb + ((size_t)(n0 + kk) * 3 + l) * 256 + colbase;
            b0[j] = (short)f2bf(bf2f(brow[0])  * dv);
            b1[j] = (short)f2bf(bf2f(brow[16]) * dv);
        }
        #pragma unroll
        for (int q = 0; q < 7; ++q) {
            short8 af = *(const short8*)&As[(q * 16 + lr) * 40 + kg * 8];
            acc[q][0] = __builtin_amdgcn_mfma_f32_16x16x32_bf16(af, b0, acc[q][0], 0, 0, 0);
            acc[q][1] = __builtin_amdgcn_mfma_f32_16x16x32_bf16(af, b1, acc[q][1], 0, 0, 0);
        }
        __syncthreads();
    }
    float* outp = vpart + (size_t)chunk * 172032;
    #pragma unroll
    for (int q = 0; q < 7; ++q) {
        int row = r0 + q * 16 + kg * 4;
        #pragma unroll
        for (int p = 0; p < 2; ++p) {
            int col = l * 256 + fo + w * 32 + p * 16 + lr;
            #pragma unroll
            for (int j = 0; j < 4; ++j)
                outp[(size_t)(row + j) * 768 + col] = acc[q][p][j];
        }
    }
}

// ---------------- reduce vpart over chunks, divide by colsum ----------------
__global__ void k_vred(const float* __restrict__ vpart, const float* __restrict__ colsum,
                       float* __restrict__ vmid) {
    int idx = blockIdx.x * 256 + threadIdx.x;
    if (idx >= 224 * 768) return;
    float s = 0.f;
    for (int c = 0; c < VCM; ++c) s += vpart[(long)c * (224 * 768) + idx];
    vmid[idx] = s / colsum[idx / 768];
}

// ---------------- ffr MLP (672 rows) + virtual-memory decay -> vembT (bf16) ----------------
__global__ __launch_bounds__(256) void k_ffr(
        const float* __restrict__ vmid, const float* __restrict__ W1, const float* __restrict__ b1,
        const float* __restrict__ W2, const float* __restrict__ b2,
        const float* __restrict__ vmem, const float* __restrict__ vlast,
        const float* __restrict__ lambs, const float* __restrict__ now_time,
        unsigned short* __restrict__ vembT) {
    __shared__ float sin_[16][260];
    __shared__ float svh[16][260];
    int row0 = blockIdx.x * 16;
    int t = threadIdx.x;
    #pragma unroll
    for (int k = 0; k < 16; ++k) {
        int idx = t + k * 256;
        int r = idx >> 8, f = idx & 255;
        sin_[r][f] = vmid[(long)(row0 + r) * 256 + f];
    }
    __syncthreads();
    {   // layer 1: 16 x 256, 4r x 4c
        int cg = t & 63, rg = t >> 6;
        int c0 = cg * 4, r0 = rg * 4;
        float acc[4][4];
        #pragma unroll
        for (int i = 0; i < 4; ++i)
            #pragma unroll
            for (int j = 0; j < 4; ++j) acc[i][j] = 0.f;
        for (int f0 = 0; f0 < 256; f0 += 4) {
            float4 a[4];
            #pragma unroll
            for (int i = 0; i < 4; ++i) a[i] = *(const float4*)&sin_[r0 + i][f0];
            #pragma unroll
            for (int ff = 0; ff < 4; ++ff) {
                float4 w = *(const float4*)&W1[(long)(f0 + ff) * 256 + c0];
                #pragma unroll
                for (int i = 0; i < 4; ++i) {
                    float av = (&a[i].x)[ff];
                    acc[i][0] += av * w.x; acc[i][1] += av * w.y;
                    acc[i][2] += av * w.z; acc[i][3] += av * w.w;
                }
            }
        }
        #pragma unroll
        for (int i = 0; i < 4; ++i)
            #pragma unroll
            for (int j = 0; j < 4; ++j)
                svh[r0 + i][c0 + j] = lky(acc[i][j] + b1[c0 + j]);
    }
    __syncthreads();
    {   // layer 2: 16 x 64, 2r x 2c + decay epilogue
        int cg = t & 31, rg = t >> 5;
        int c0 = cg * 2, r0 = rg * 2;
        float acc[2][2];
        acc[0][0] = acc[0][1] = acc[1][0] = acc[1][1] = 0.f;
        for (int f0 = 0; f0 < 256; f0 += 4) {
            float4 a[2];
            #pragma unroll
            for (int i = 0; i < 2; ++i) a[i] = *(const float4*)&svh[r0 + i][f0];
            #pragma unroll
            for (int ff = 0; ff < 4; ++ff) {
                float2 w = *(const float2*)&W2[(long)(f0 + ff) * 64 + c0];
                #pragma unroll
                for (int i = 0; i < 2; ++i) {
                    float av = (&a[i].x)[ff];
                    acc[i][0] += av * w.x; acc[i][1] += av * w.y;
                }
            }
        }
        float nowv = now_time[0];
        #pragma unroll
        for (int i = 0; i < 2; ++i) {
            int row = row0 + r0 + i;           // row = rr*3 + l
            int rr = row / 3, l = row % 3;
            float vd = __expf(-lambs[l] * (nowv - vlast[rr]));
            #pragma unroll
            for (int j = 0; j < 2; ++j) {
                float v = lky(acc[i][j] + b2[c0 + j]);
                int m = c0 + j;
                vembT[(size_t)(l * 64 + m) * 224 + rr] =
                    f2bf(vmem[(long)rr * 192 + l * 64 + m] * vd + v);
            }
        }
    }
}

// ---------------- new_mem -> node_emb (bf16) ----------------
__global__ void k_newmem(const float* __restrict__ memory,
        const unsigned short* __restrict__ msg_feat,
        const float* __restrict__ cnt3, const float* __restrict__ t_max,
        const float* __restrict__ last_update, const int* __restrict__ has_msg,
        const float* __restrict__ lambs, unsigned short* __restrict__ node_emb, int N) {
    int n = blockIdx.x;
    int j = threadIdx.x;                 // 0..191
    int l = j >> 6, m = j & 63;
    int has = has_msg[n];
    float dt = has ? (t_max[n] - last_update[n]) : 0.f;
    float decay = __expf(-lambs[l] * dt);
    long mb = (long)n * 195 + l * 65;
    float num = memory[mb + m];
    float den = memory[mb + 64];
    if (has) {
        num = num * decay + bf2f(msg_feat[(size_t)n * 192 + j]);
        den = den * decay + cnt3[(size_t)n * 3 + l];
    }
    node_emb[(size_t)n * 192 + j] = f2bf(num / fmaxf(den, 1e-6f));
}

// ---------------- vnode_emb = row-softmax(A_r) @ v_emb via MFMA ----------------
__global__ __launch_bounds__(256) void k_vnode_mfma(
        const unsigned short* __restrict__ Aexp_rm, const unsigned short* __restrict__ vembT,
        const float* __restrict__ rowsum, unsigned short* __restrict__ vnode_emb, int N) {
    __shared__ unsigned short As[64 * 232];
    __shared__ float sRS[64];
    int t = threadIdx.x, lane = t & 63, w = t >> 6;
    int lr = lane & 15, kg = lane >> 4;
    int row0 = blockIdx.x * 64;
    {
        int r = t >> 2, sg = t & 3;
        const uint4* src = (const uint4*)(Aexp_rm + (size_t)(row0 + r) * 224 + sg * 56);
        uint4* dst = (uint4*)(As + r * 232 + sg * 56);
        #pragma unroll
        for (int u = 0; u < 7; ++u) dst[u] = src[u];
    }
    if (t < 64) sRS[t] = rowsum[min(row0 + t, N - 1)];
    __syncthreads();
    int n0 = w * 48;                      // 192 cols / 4 waves
    f32x4 acc[4][3];
    #pragma unroll
    for (int m = 0; m < 4; ++m)
        #pragma unroll
        for (int nt = 0; nt < 3; ++nt) acc[m][nt] = (f32x4){0.f, 0.f, 0.f, 0.f};
    for (int kk = 0; kk < 7; ++kk) {
        short8 bf[3];
        #pragma unroll
        for (int nt = 0; nt < 3; ++nt)
            bf[nt] = *(const short8*)(vembT + (size_t)(n0 + nt * 16 + lr) * 224 + kk * 32 + kg * 8);
        #pragma unroll
        for (int m = 0; m < 4; ++m) {
            short8 af = *(const short8*)(As + (m * 16 + lr) * 232 + kk * 32 + kg * 8);
            #pragma unroll
            for (int nt = 0; nt < 3; ++nt)
                acc[m][nt] = __builtin_amdgcn_mfma_f32_16x16x32_bf16(af, bf[nt], acc[m][nt], 0, 0, 0);
        }
    }
    #pragma unroll
    for (int m = 0; m < 4; ++m)
        #pragma unroll
        for (int j = 0; j < 4; ++j) {
            int row = row0 + m * 16 + kg * 4 + j;
            if (row < N) {
                float inv = 1.f / sRS[row - row0];
                #pragma unroll
                for (int nt = 0; nt < 3; ++nt)
                    vnode_emb[(size_t)row * 192 + n0 + nt * 16 + lr] = f2bf(acc[m][nt][j] * inv);
            }
        }
}

// ---------------- et + st + output blend via MFMA ----------------
__global__ __launch_bounds__(256) void k_et_st_mfma(
        const unsigned short* __restrict__ ne, const unsigned short* __restrict__ ve,
        const unsigned short* __restrict__ etWT, const float* __restrict__ etb,
        const unsigned short* __restrict__ stWT, const float* __restrict__ stb,
        const float* __restrict__ stat, const float* __restrict__ lamb,
        float* __restrict__ out, int N) {
    __shared__ unsigned short As[128 * 200];   // rows 0-63: node, 64-127: vnode
    __shared__ unsigned short Hs[64 * 136];    // st input [64 rows][128 cols]
    int t = threadIdx.x, lane = t & 63, w = t >> 6;
    int lr = lane & 15, kg = lane >> 4;
    int row0 = blockIdx.x * 64;
    {
        int r = t >> 2, sg = t & 3;
        const uint4* sn = (const uint4*)(ne + (size_t)(row0 + r) * 192 + sg * 48);
        const uint4* sv = (const uint4*)(ve + (size_t)(row0 + r) * 192 + sg * 48);
        uint4* dn = (uint4*)(As + (size_t)r * 200 + sg * 48);
        uint4* dv = (uint4*)(As + (size_t)(64 + r) * 200 + sg * 48);
        #pragma unroll
        for (int u = 0; u < 6; ++u) { dn[u] = sn[u]; dv[u] = sv[u]; }
    }
    __syncthreads();
    // et layer: wave w -> cols [w*16, w*16+16), both halves; K=192
    int c0 = w * 16;
    f32x4 acc[2][4];
    #pragma unroll
    for (int h = 0; h < 2; ++h)
        #pragma unroll
        for (int m = 0; m < 4; ++m) acc[h][m] = (f32x4){0.f, 0.f, 0.f, 0.f};
    for (int kk = 0; kk < 6; ++kk) {
        short8 bf = *(const short8*)(etWT + (size_t)(c0 + lr) * 192 + kk * 32 + kg * 8);
        #pragma unroll
        for (int h = 0; h < 2; ++h)
            #pragma unroll
            for (int m = 0; m < 4; ++m) {
                short8 af = *(const short8*)(As + (size_t)(h * 64 + m * 16 + lr) * 200 + kk * 32 + kg * 8);
                acc[h][m] = __builtin_amdgcn_mfma_f32_16x16x32_bf16(af, bf, acc[h][m], 0, 0, 0);
            }
    }
    float bb = etb[c0 + lr];
    #pragma unroll
    for (int h = 0; h < 2; ++h)
        #pragma unroll
        for (int m = 0; m < 4; ++m)
            #pragma unroll
            for (int j = 0; j < 4; ++j)
                Hs[(m * 16 + kg * 4 + j) * 136 + h * 64 + c0 + lr] = f2bf(lky(acc[h][m][j] + bb));
    __syncthreads();
    // st layer: wave w -> cols [w*32, w*32+32); K=128
    int c0s = w * 32;
    f32x4 a2[4][2];
    #pragma unroll
    for (int m = 0; m < 4; ++m) { a2[m][0] = (f32x4){0.f,0.f,0.f,0.f}; a2[m][1] = (f32x4){0.f,0.f,0.f,0.f}; }
    for (int kk = 0; kk < 4; ++kk) {
        short8 bf0 = *(const short8*)(stWT + (size_t)(c0s + lr) * 128 + kk * 32 + kg * 8);
        short8 bf1 = *(const short8*)(stWT + (size_t)(c0s + 16 + lr) * 128 + kk * 32 + kg * 8);
        #pragma unroll
        for (int m = 0; m < 4; ++m) {
            short8 af = *(const short8*)(Hs + (m * 16 + lr) * 136 + kk * 32 + kg * 8);
            a2[m][0] = __builtin_amdgcn_mfma_f32_16x16x32_bf16(af, bf0, a2[m][0], 0, 0, 0);
            a2[m][1] = __builtin_amdgcn_mfma_f32_16x16x32_bf16(af, bf1, a2[m][1], 0, 0, 0);
        }
    }
    float lam = lamb[0];
    float sb0 = stb[c0s + lr], sb1 = stb[c0s + 16 + lr];
    #pragma unroll
    for (int m = 0; m < 4; ++m)
        #pragma unroll
        for (int j = 0; j < 4; ++j) {
            int n = row0 + m * 16 + kg * 4 + j;
            if (n < N) {
                int ca = c0s + lr, cb = c0s + 16 + lr;
                float va = lky(a2[m][0][j] + sb0);
                float vb = lky(a2[m][1][j] + sb1);
                out[(size_t)n * 128 + ca] = lam * stat[(size_t)n * 128 + ca] + (1.f - lam) * va;
                out[(size_t)n * 128 + cb] = lam * stat[(size_t)n * 128 + cb] + (1.f - lam) * vb;
            }
        }
}

extern "C" void kernel_launch(void* const* d_in, const int* in_sizes, int n_in,
                              void* d_out, int out_size, void* d_ws, size_t ws_size,
                              hipStream_t stream) {
    const int*   src        = (const int*)d_in[0];
    const int*   tgt        = (const int*)d_in[1];
    const float* ts         = (const float*)d_in[2];
    const float* now_time   = (const float*)d_in[3];
    const float* nodef      = (const float*)d_in[5];
    const float* memory     = (const float*)d_in[6];
    const float* last_upd   = (const float*)d_in[7];
    const float* vmem       = (const float*)d_in[8];
    const float* vlast      = (const float*)d_in[9];
    const float* A_r        = (const float*)d_in[10];
    const float* static_emb = (const float*)d_in[11];
    const float* lamb       = (const float*)d_in[12];
    const float* lambs      = (const float*)d_in[13];
    const float* mf_W1      = (const float*)d_in[14];
    const float* mf_b1      = (const float*)d_in[15];
    const float* mf_W2      = (const float*)d_in[16];
    const float* mf_b2      = (const float*)d_in[17];
    const float* ffr_W1     = (const float*)d_in[18];
    const float* ffr_b1     = (const float*)d_in[19];
    const float* ffr_W2     = (const float*)d_in[20];
    const float* ffr_b2     = (const float*)d_in[21];
    const float* et_W       = (const float*)d_in[22];
    const float* et_b       = (const float*)d_in[23];
    const float* st_W       = (const float*)d_in[24];
    const float* st_b       = (const float*)d_in[25];

    int E = in_sizes[0];
    int N = in_sizes[7];

    float* ws = (float*)d_ws;
    size_t off = 0;
    auto alloc = [&](size_t nf) { float* p = ws + off; off += (nf + 63) & ~(size_t)63; return p; };
    unsigned short* aggb  = (unsigned short*)alloc((size_t)SN * 384);     // SN*3 rows x 256 bf16
    unsigned short* msg_feat = (unsigned short*)alloc((size_t)N * 96);    // bf16
    unsigned short* AexpT   = (unsigned short*)alloc((size_t)224 * SN / 2);
    unsigned short* Aexp_rm = (unsigned short*)alloc((size_t)SN * 224 / 2);
    float* tv_union = alloc((size_t)VCM * 172032);      // temb (N*128) then vpart (VCM*172032)
    float* vmid     = alloc(224 * 768);
    unsigned short* vembT = (unsigned short*)alloc((size_t)192 * 224 / 2 + 64);
    float* t_max    = alloc(N);
    float* rowsum   = alloc(N);
    float* cnt3     = alloc((size_t)SN * 3);
    float* colsum   = alloc(256);
    unsigned short* W1T  = (unsigned short*)alloc(128 * 256 / 2);
    unsigned short* W2T  = (unsigned short*)alloc(64 * 128 / 2);
    unsigned short* etWT = (unsigned short*)alloc(64 * 192 / 2);
    unsigned short* stWT = (unsigned short*)alloc(128 * 128 / 2);
    int*   cnt      = (int*)alloc(N);
    int*   offsets  = (int*)alloc(N + 1);
    int*   cursor   = (int*)alloc(N);
    int*   sorted   = (int*)alloc(E);
    int*   has_msg  = (int*)alloc(N);
    if (off * sizeof(float) > ws_size) return;   // workspace guard

    unsigned int* temb = (unsigned int*)tv_union;   // live: k_prep..k_agg
    float* vpart = tv_union;                        // live: k_vmid_mfma..k_vred
    // overlays: aggb region is dead after k_mf_mfma + k_vmid_mfma
    unsigned short* node_emb  = (unsigned short*)aggb;
    unsigned short* vnode_emb = node_emb + (size_t)N * 192;

    k_init<<<(N + 255) / 256, 256, 0, stream>>>(t_max, cnt, cursor, colsum, N);
    k_tbf<<<(256 * 128 + 255) / 256, 256, 0, stream>>>(mf_W1, W1T, 256, 128);
    k_tbf<<<(128 * 64 + 255) / 256, 256, 0, stream>>>(mf_W2, W2T, 128, 64);
    k_tbf<<<(192 * 64 + 255) / 256, 256, 0, stream>>>(et_W, etWT, 192, 64);
    k_tbf<<<(128 * 128 + 255) / 256, 256, 0, stream>>>(st_W, stWT, 128, 128);
    k_tmax_cnt<<<(E + 255) / 256, 256, 0, stream>>>(src, ts, t_max, cnt, E);
    k_scan<<<1, 1024, 0, stream>>>(cnt, offsets, N);
    k_scatter<<<(E + 255) / 256, 256, 0, stream>>>(src, offsets, cursor, sorted, E);
    k_prep<<<(N + 3) / 4, 256, 0, stream>>>(memory, nodef, temb, N);
    k_aexp<<<SN / 64, 256, 0, stream>>>(A_r, rowsum, colsum, AexpT, Aexp_rm, N);
    k_agg<<<SN / 4, 256, 0, stream>>>(tgt, ts, sorted, offsets, t_max, temb,
                                      lambs, (unsigned int*)aggb, cnt3, has_msg, N);
    k_mf_mfma<<<SN * 3 / 64, 256, 0, stream>>>(aggb, W1T, mf_b1, W2T, mf_b2, msg_feat, N * 3);
    k_vmid_mfma<<<12 * VCM, 256, 0, stream>>>(AexpT, aggb, cnt3, vpart);
    k_vred<<<(224 * 768 + 255) / 256, 256, 0, stream>>>(vpart, colsum, vmid);
    k_ffr<<<42, 256, 0, stream>>>(vmid, ffr_W1, ffr_b1, ffr_W2, ffr_b2, vmem, vlast,
                                  lambs, now_time, vembT);
    k_newmem<<<N, 192, 0, stream>>>(memory, msg_feat, cnt3, t_max, last_upd, has_msg,
                                    lambs, node_emb, N);
    k_vnode_mfma<<<SN / 64, 256, 0, stream>>>(Aexp_rm, vembT, rowsum, vnode_emb, N);
    k_et_st_mfma<<<SN / 64, 256, 0, stream>>>(node_emb, vnode_emb, etWT, et_b, stWT, st_b,
                                              static_emb, lamb, (float*)d_out, N);
}

// Round 6
// 425.147 us; speedup vs baseline: 3.4898x; 1.0137x over previous
//
#include <hip/hip_runtime.h>

static __device__ __forceinline__ float lky(float x) { return x > 0.f ? x : 0.01f * x; }

static __device__ __forceinline__ unsigned short f2bf(float x) {
    unsigned int u = __float_as_uint(x);
    unsigned int r = (u + 0x7FFFu + ((u >> 16) & 1u)) >> 16;
    return (unsigned short)r;
}
static __device__ __forceinline__ float bf2f(unsigned short x) {
    return __uint_as_float((unsigned int)x << 16);
}
static __device__ __forceinline__ unsigned int pack2bf(float lo, float hi) {
    return (unsigned int)f2bf(lo) | ((unsigned int)f2bf(hi) << 16);
}

typedef __attribute__((ext_vector_type(8))) short short8;
typedef __attribute__((ext_vector_type(4))) float f32x4;

constexpr int SN  = 50048;   // padded node count (multiple of 64)
constexpr int KLV = 608;     // K(nodes) per split-K chunk (multiple of 32)
constexpr int VCM = 83;      // ceil(SN/KLV)

// ---------------- init ----------------
__global__ void k_init(float* t_max, int* cnt, int* cursor, float* colsum, int N) {
    int i = blockIdx.x * 256 + threadIdx.x;
    if (i < N) { t_max[i] = -1.0f; cnt[i] = 0; cursor[i] = 0; }
    if (i < 224) colsum[i] = 0.0f;
}

// ---------------- weight transpose to bf16: dst[c*K+k] = src[k*C+c] ----------------
__global__ void k_tbf(const float* __restrict__ src, unsigned short* __restrict__ dst,
                      int K, int C) {
    int i = blockIdx.x * 256 + threadIdx.x;
    if (i >= K * C) return;
    int c = i / K, k = i % K;
    dst[i] = f2bf(src[k * C + c]);
}

// ---------------- per-edge t_max / counts ----------------
__global__ void k_tmax_cnt(const int* __restrict__ src, const float* __restrict__ ts,
                           float* t_max, int* cnt, int E) {
    int e = blockIdx.x * 256 + threadIdx.x;
    if (e >= E) return;
    int s = src[e];
    atomicMax((int*)(t_max + s), __float_as_int(ts[e]));   // ts >= 0, int-monotone
    atomicAdd(cnt + s, 1);
}

// ---------------- exclusive scan over counts (single block) ----------------
__global__ __launch_bounds__(1024) void k_scan(const int* __restrict__ cnt,
                                               int* __restrict__ offsets, int N) {
    __shared__ int wsum[16];
    __shared__ int s_run;
    int t = threadIdx.x;
    int lane = t & 63, wid = t >> 6;
    if (t == 0) s_run = 0;
    __syncthreads();
    int nchunk = (N + 1023) >> 10;
    for (int c = 0; c < nchunk; ++c) {
        int i = (c << 10) + t;
        int v = (i < N) ? cnt[i] : 0;
        int x = v;
        #pragma unroll
        for (int d = 1; d < 64; d <<= 1) {
            int y = __shfl_up(x, d, 64);
            if (lane >= d) x += y;
        }
        if (lane == 63) wsum[wid] = x;
        __syncthreads();
        int wbase = 0;
        #pragma unroll
        for (int w = 0; w < 16; ++w) wbase += (w < wid) ? wsum[w] : 0;
        int run = s_run;
        if (i < N) offsets[i] = run + wbase + x - v;
        __syncthreads();
        if (t == 1023) s_run = run + wbase + x;
        __syncthreads();
    }
    if (t == 0) offsets[N] = s_run;
}

// ---------------- scatter edges into per-node buckets ----------------
__global__ void k_scatter(const int* __restrict__ src, const int* __restrict__ offsets,
                          int* cursor, int* sorted, int E) {
    int e = blockIdx.x * 256 + threadIdx.x;
    if (e >= E) return;
    int s = src[e];
    int pos = offsets[s] + atomicAdd(cursor + s, 1);
    sorted[pos] = e;
}

// ---------------- precompute normalized target embedding, bf16 [N][256] ----------------
__global__ __launch_bounds__(256) void k_prep(
        const float* __restrict__ memory, const float* __restrict__ nodef,
        unsigned int* __restrict__ temb, int N) {
    int wid = threadIdx.x >> 6, lane = threadIdx.x & 63;
    int n = blockIdx.x * 4 + wid;
    if (n >= N) return;
    const float* mrow = memory + (size_t)n * 195;
    float d0 = mrow[64], d1 = mrow[129], d2 = mrow[194];
    // half A: features 2*lane, 2*lane+1 (l0 for lane<32, l1 for lane>=32)
    int f = 2 * lane;
    float den = (f < 64) ? d0 : d1;
    int offA = (f < 64) ? f : f + 1;
    float va0 = mrow[offA] / den;
    float va1 = mrow[offA + 1] / den;
    // half B: features 128+2*lane (l2 for lane<32, nodef for lane>=32)
    float vb0, vb1;
    if (lane < 32) {
        vb0 = mrow[130 + 2 * lane] / d2;
        vb1 = mrow[131 + 2 * lane] / d2;
    } else {
        const float* nf = nodef + (size_t)n * 64 + 2 * (lane - 32);
        vb0 = nf[0]; vb1 = nf[1];
    }
    temb[(size_t)n * 128 + lane]      = pack2bf(va0, va1);
    temb[(size_t)n * 128 + 64 + lane] = pack2bf(vb0, vb1);
}

// ---------------- A_r pass: rowsum, colsum, bf16 Aexp_rm + AexpT (unmasked) ----------------
__global__ __launch_bounds__(256) void k_aexp(
        const float* __restrict__ A_r,
        float* __restrict__ rowsum, float* __restrict__ colsum,
        unsigned short* __restrict__ AexpT, unsigned short* __restrict__ Aexp_rm, int N) {
    __shared__ unsigned short sE[64][226];   // stride 226 shorts -> 2-way banks (free)
    int t = threadIdx.x, lane = t & 63, w = t >> 6;
    int n0 = blockIdx.x * 64;
    // each wave handles 16 nodes
    for (int i = 0; i < 16; ++i) {
        int n = w * 16 + i;
        int gn = n0 + n;
        float e0 = 0.f, e1 = 0.f, e2 = 0.f, e3 = 0.f;
        if (gn < N) {
            const float* row = A_r + (size_t)gn * 224;
            e0 = __expf(row[lane]);
            e1 = __expf(row[64 + lane]);
            e2 = __expf(row[128 + lane]);
            if (lane < 32) e3 = __expf(row[192 + lane]);
        }
        sE[n][lane]       = f2bf(e0);
        sE[n][64 + lane]  = f2bf(e1);
        sE[n][128 + lane] = f2bf(e2);
        if (lane < 32) sE[n][192 + lane] = f2bf(e3);
        float rs = e0 + e1 + e2 + e3;
        #pragma unroll
        for (int d = 32; d > 0; d >>= 1) rs += __shfl_xor(rs, d, 64);
        if (lane == 0 && gn < N) rowsum[gn] = rs;
    }
    __syncthreads();
    // colsum partials
    if (t < 224) {
        float s = 0.f;
        #pragma unroll 8
        for (int r = 0; r < 64; ++r) s += bf2f(sE[r][t]);
        atomicAdd(colsum + t, s);
    }
    // row-major write, packed uints, coalesced
    {
        unsigned int* dst = (unsigned int*)Aexp_rm;
        for (int i = t; i < 64 * 112; i += 256) {
            int n = i / 112, cp = i % 112;
            unsigned int v = *(const unsigned int*)&sE[n][2 * cp];
            dst[(size_t)(n0 + n) * 112 + cp] = v;
        }
    }
    // transposed write: wave-coalesced 128B runs per r-row
    {
        unsigned int* dst = (unsigned int*)AexpT;
        for (int u = t; u < 224 * 32; u += 256) {
            int r = u >> 5, np = u & 31;
            unsigned int lo = sE[2 * np][r];
            unsigned int hi = sE[2 * np + 1][r];
            dst[(size_t)r * (SN / 2) + (n0 >> 1) + np] = lo | (hi << 16);
        }
    }
}

// ---------------- per-node aggregation: one wave per node, bf16 temb gather ----------------
__global__ __launch_bounds__(256) void k_agg(
        const int* __restrict__ tgt, const float* __restrict__ ts,
        const int* __restrict__ sorted, const int* __restrict__ offsets,
        const float* __restrict__ t_max, const unsigned int* __restrict__ temb,
        const float* __restrict__ lambs,
        unsigned int* __restrict__ aggb, float* __restrict__ cnt3,
        int* __restrict__ has_msg, int N) {
    int wid = threadIdx.x >> 6, lane = threadIdx.x & 63;
    int n = blockIdx.x * 4 + wid;      // n < SN (grid = SN/4)
    size_t rb = (size_t)n * 3;
    if (n >= N) {                       // zero-fill padding rows
        #pragma unroll
        for (int l = 0; l < 3; ++l) {
            unsigned int* row = aggb + (rb + l) * 128;
            row[lane] = 0; row[64 + lane] = 0;
            if (lane == 0) cnt3[rb + l] = 0.f;
        }
        return;
    }
    int beg = offsets[n], end = offsets[n + 1];
    float lb0 = lambs[0], lb1 = lambs[1], lb2 = lambs[2];
    float tm = t_max[n];
    float aa0[3], aa1[3], ab0[3], ab1[3], accc[3];
    #pragma unroll
    for (int l = 0; l < 3; ++l) { aa0[l] = aa1[l] = ab0[l] = ab1[l] = accc[l] = 0.f; }
    for (int idx = beg; idx < end; ++idx) {
        int e = sorted[idx];
        int tt = tgt[e];
        float d = tm - ts[e];
        unsigned int ua = temb[(size_t)tt * 128 + lane];
        unsigned int ub = temb[(size_t)tt * 128 + 64 + lane];
        float a0 = __uint_as_float(ua << 16);
        float a1 = __uint_as_float(ua & 0xffff0000u);
        float b0 = __uint_as_float(ub << 16);
        float b1 = __uint_as_float(ub & 0xffff0000u);
        float w0 = __expf(-lb0 * d), w1 = __expf(-lb1 * d), w2 = __expf(-lb2 * d);
        aa0[0] += w0 * a0; aa1[0] += w0 * a1; ab0[0] += w0 * b0; ab1[0] += w0 * b1; accc[0] += w0;
        aa0[1] += w1 * a0; aa1[1] += w1 * a1; ab0[1] += w1 * b0; ab1[1] += w1 * b1; accc[1] += w1;
        aa0[2] += w2 * a0; aa1[2] += w2 * a1; ab0[2] += w2 * b0; ab1[2] += w2 * b1; accc[2] += w2;
    }
    #pragma unroll
    for (int l = 0; l < 3; ++l) {
        unsigned int* row = aggb + (rb + l) * 128;
        row[lane]      = pack2bf(aa0[l], aa1[l]);
        row[64 + lane] = pack2bf(ab0[l], ab1[l]);
        if (lane == 0) cnt3[rb + l] = accc[l];
    }
    if (lane == 0) has_msg[n] = (end > beg) ? 1 : 0;
}

// ---------------- mf MLP via MFMA: (3N,256) bf16 -> relu(128) -> relu(64) bf16 ----------------
__global__ __launch_bounds__(256) void k_mf_mfma(
        const unsigned short* __restrict__ aggb,
        const unsigned short* __restrict__ W1T, const float* __restrict__ b1,
        const unsigned short* __restrict__ W2T, const float* __restrict__ b2,
        unsigned short* __restrict__ msg_feat, int NROWS) {
    __shared__ unsigned short As[64 * 264];
    __shared__ unsigned short Hs[64 * 136];
    int t = threadIdx.x, lane = t & 63, w = t >> 6;
    int lr = lane & 15, kg = lane >> 4;
    int row0 = blockIdx.x * 64;
    {   // stage A: 64 rows x 256 bf16, 4 threads/row
        int r = t >> 2, s4 = t & 3;
        const uint4* src = (const uint4*)(aggb + (size_t)(row0 + r) * 256 + s4 * 64);
        uint4* dst = (uint4*)(As + r * 264 + s4 * 64);
        #pragma unroll
        for (int u = 0; u < 8; ++u) dst[u] = src[u];
    }
    __syncthreads();
    // layer 1: wave w -> cols [w*32, w*32+32)
    int n0 = w * 32;
    f32x4 acc[4][2];
    #pragma unroll
    for (int m = 0; m < 4; ++m) {
        acc[m][0] = (f32x4){0.f, 0.f, 0.f, 0.f};
        acc[m][1] = (f32x4){0.f, 0.f, 0.f, 0.f};
    }
    for (int kk = 0; kk < 8; ++kk) {
        short8 bf0 = *(const short8*)(W1T + (size_t)(n0 + lr) * 256 + kk * 32 + kg * 8);
        short8 bf1 = *(const short8*)(W1T + (size_t)(n0 + 16 + lr) * 256 + kk * 32 + kg * 8);
        #pragma unroll
        for (int m = 0; m < 4; ++m) {
            short8 af = *(const short8*)(As + (m * 16 + lr) * 264 + kk * 32 + kg * 8);
            acc[m][0] = __builtin_amdgcn_mfma_f32_16x16x32_bf16(af, bf0, acc[m][0], 0, 0, 0);
            acc[m][1] = __builtin_amdgcn_mfma_f32_16x16x32_bf16(af, bf1, acc[m][1], 0, 0, 0);
        }
    }
    float bb0 = b1[n0 + lr], bb1 = b1[n0 + 16 + lr];
    #pragma unroll
    for (int m = 0; m < 4; ++m)
        #pragma unroll
        for (int j = 0; j < 4; ++j) {
            int row = m * 16 + kg * 4 + j;
            Hs[row * 136 + n0 + lr]      = f2bf(fmaxf(acc[m][0][j] + bb0, 0.f));
            Hs[row * 136 + n0 + 16 + lr] = f2bf(fmaxf(acc[m][1][j] + bb1, 0.f));
        }
    __syncthreads();
    // layer 2: wave w -> cols [w*16, w*16+16)
    int c0 = w * 16;
    f32x4 a2[4];
    #pragma unroll
    for (int m = 0; m < 4; ++m) a2[m] = (f32x4){0.f, 0.f, 0.f, 0.f};
    for (int kk = 0; kk < 4; ++kk) {
        short8 bf = *(const short8*)(W2T + (size_t)(c0 + lr) * 128 + kk * 32 + kg * 8);
        #pragma unroll
        for (int m = 0; m < 4; ++m) {
            short8 af = *(const short8*)(Hs + (m * 16 + lr) * 136 + kk * 32 + kg * 8);
            a2[m] = __builtin_amdgcn_mfma_f32_16x16x32_bf16(af, bf, a2[m], 0, 0, 0);
        }
    }
    float b2v = b2[c0 + lr];
    #pragma unroll
    for (int m = 0; m < 4; ++m)
        #pragma unroll
        for (int j = 0; j < 4; ++j) {
            int row = row0 + m * 16 + kg * 4 + j;
            if (row < NROWS)
                msg_feat[(size_t)row * 64 + c0 + lr] = f2bf(fmaxf(a2[m][j] + b2v, 0.f));
        }
}

// ---------------- vmid via bf16 MFMA, split-K; B LDS-staged (transposed, XOR-swizzled) ----------------
__global__ __launch_bounds__(256) void k_vmid_mfma(
        const unsigned short* __restrict__ AexpT, const unsigned short* __restrict__ aggb,
        const float* __restrict__ cnt3, float* __restrict__ vpart) {
    __shared__ unsigned short As[112 * 40];   // 112 rows x 32 shorts (stride 40 = 80B, uniform banks)
    __shared__ unsigned int BsT[128 * 20];    // [col][np-uint] stride 20; np ^= ((col>>3)&3)<<2
    int bx = blockIdx.x;
    int chunk = bx / 12, tile = bx % 12;
    int r0 = (tile & 1) * 112;
    int ft = tile >> 1;                 // 0..5
    int l = ft >> 1, fo = (ft & 1) * 128;
    int t = threadIdx.x, lane = t & 63, w = t >> 6;
    int lr = lane & 15, kg = lane >> 4;
    int np = t >> 4, sg = t & 15;       // B staging: node-pair, col-segment(8 cols)
    f32x4 acc[7][2];
    #pragma unroll
    for (int q = 0; q < 7; ++q) {
        acc[q][0] = (f32x4){0.f, 0.f, 0.f, 0.f};
        acc[q][1] = (f32x4){0.f, 0.f, 0.f, 0.f};
    }
    int nbeg = chunk * KLV;
    int nsteps = min(KLV, SN - nbeg) >> 5;
    // B fragment read bases (uint index); swizzle keeps 4 uints contiguous & 16B aligned
    int c0 = w * 32 + lr, c1 = c0 + 16;
    int rb0 = c0 * 20 + (kg ^ ((c0 >> 3) & 3)) * 4;
    int rb1 = c1 * 20 + (kg ^ ((c1 >> 3) & 3)) * 4;
    int swz = np ^ ((sg & 3) << 2);
    for (int s = 0; s < nsteps; ++s) {
        int n0 = nbeg + s * 32;
        if (t < 224) {                   // stage A: 2 threads/row, 32 shorts/row
            int srow = t >> 1, sseg = t & 1;
            const uint4* ap = (const uint4*)(AexpT + (size_t)(r0 + srow) * SN + n0) + sseg * 2;
            uint4 v0 = ap[0];
            uint4 v1 = ap[1];
            *(uint4*)&As[srow * 40 + sseg * 16]     = v0;
            *(uint4*)&As[srow * 40 + sseg * 16 + 8] = v1;
        }
        {   // stage B: nodes (2np, 2np+1) x cols [sg*8, sg*8+8), scaled by 1/den, k-pair packed
            int na = n0 + 2 * np;
            size_t ra = ((size_t)na * 3 + l) * 256 + fo + sg * 8;
            uint4 va = *(const uint4*)(aggb + ra);
            uint4 vb = *(const uint4*)(aggb + ra + 768);
            float da = 1.f / fmaxf(cnt3[(size_t)na * 3 + l], 1e-6f);
            float db = 1.f / fmaxf(cnt3[(size_t)na * 3 + l + 3], 1e-6f);
            const unsigned short* pa = (const unsigned short*)&va;
            const unsigned short* pb = (const unsigned short*)&vb;
            unsigned int* dst = BsT + sg * 160 + swz;
            #pragma unroll
            for (int j = 0; j < 8; ++j)
                dst[j * 20] = pack2bf(bf2f(pa[j]) * da, bf2f(pb[j]) * db);
        }
        __syncthreads();
        short8 b0 = *(const short8*)((const unsigned short*)(BsT + rb0));
        short8 b1 = *(const short8*)((const unsigned short*)(BsT + rb1));
        #pragma unroll
        for (int q = 0; q < 7; ++q) {
            short8 af = *(const short8*)&As[(q * 16 + lr) * 40 + kg * 8];
            acc[q][0] = __builtin_amdgcn_mfma_f32_16x16x32_bf16(af, b0, acc[q][0], 0, 0, 0);
            acc[q][1] = __builtin_amdgcn_mfma_f32_16x16x32_bf16(af, b1, acc[q][1], 0, 0, 0);
        }
        __syncthreads();
    }
    float* outp = vpart + (size_t)chunk * 172032;
    #pragma unroll
    for (int q = 0; q < 7; ++q) {
        int row = r0 + q * 16 + kg * 4;
        #pragma unroll
        for (int p = 0; p < 2; ++p) {
            int col = l * 256 + fo + w * 32 + p * 16 + lr;
            #pragma unroll
            for (int j = 0; j < 4; ++j)
                outp[(size_t)(row + j) * 768 + col] = acc[q][p][j];
        }
    }
}

// ---------------- reduce vpart over chunks, divide by colsum ----------------
__global__ void k_vred(const float* __restrict__ vpart, const float* __restrict__ colsum,
                       float* __restrict__ vmid) {
    int idx = blockIdx.x * 256 + threadIdx.x;
    if (idx >= 224 * 768) return;
    float s = 0.f;
    for (int c = 0; c < VCM; ++c) s += vpart[(long)c * (224 * 768) + idx];
    vmid[idx] = s / colsum[idx / 768];
}

// ---------------- ffr MLP (672 rows) + virtual-memory decay -> vembT (bf16) ----------------
__global__ __launch_bounds__(256) void k_ffr(
        const float* __restrict__ vmid, const float* __restrict__ W1, const float* __restrict__ b1,
        const float* __restrict__ W2, const float* __restrict__ b2,
        const float* __restrict__ vmem, const float* __restrict__ vlast,
        const float* __restrict__ lambs, const float* __restrict__ now_time,
        unsigned short* __restrict__ vembT) {
    __shared__ float sin_[16][260];
    __shared__ float svh[16][260];
    int row0 = blockIdx.x * 16;
    int t = threadIdx.x;
    #pragma unroll
    for (int k = 0; k < 16; ++k) {
        int idx = t + k * 256;
        int r = idx >> 8, f = idx & 255;
        sin_[r][f] = vmid[(long)(row0 + r) * 256 + f];
    }
    __syncthreads();
    {   // layer 1: 16 x 256, 4r x 4c
        int cg = t & 63, rg = t >> 6;
        int c0 = cg * 4, r0 = rg * 4;
        float acc[4][4];
        #pragma unroll
        for (int i = 0; i < 4; ++i)
            #pragma unroll
            for (int j = 0; j < 4; ++j) acc[i][j] = 0.f;
        for (int f0 = 0; f0 < 256; f0 += 4) {
            float4 a[4];
            #pragma unroll
            for (int i = 0; i < 4; ++i) a[i] = *(const float4*)&sin_[r0 + i][f0];
            #pragma unroll
            for (int ff = 0; ff < 4; ++ff) {
                float4 w = *(const float4*)&W1[(long)(f0 + ff) * 256 + c0];
                #pragma unroll
                for (int i = 0; i < 4; ++i) {
                    float av = (&a[i].x)[ff];
                    acc[i][0] += av * w.x; acc[i][1] += av * w.y;
                    acc[i][2] += av * w.z; acc[i][3] += av * w.w;
                }
            }
        }
        #pragma unroll
        for (int i = 0; i < 4; ++i)
            #pragma unroll
            for (int j = 0; j < 4; ++j)
                svh[r0 + i][c0 + j] = lky(acc[i][j] + b1[c0 + j]);
    }
    __syncthreads();
    {   // layer 2: 16 x 64, 2r x 2c + decay epilogue
        int cg = t & 31, rg = t >> 5;
        int c0 = cg * 2, r0 = rg * 2;
        float acc[2][2];
        acc[0][0] = acc[0][1] = acc[1][0] = acc[1][1] = 0.f;
        for (int f0 = 0; f0 < 256; f0 += 4) {
            float4 a[2];
            #pragma unroll
            for (int i = 0; i < 2; ++i) a[i] = *(const float4*)&svh[r0 + i][f0];
            #pragma unroll
            for (int ff = 0; ff < 4; ++ff) {
                float2 w = *(const float2*)&W2[(long)(f0 + ff) * 64 + c0];
                #pragma unroll
                for (int i = 0; i < 2; ++i) {
                    float av = (&a[i].x)[ff];
                    acc[i][0] += av * w.x; acc[i][1] += av * w.y;
                }
            }
        }
        float nowv = now_time[0];
        #pragma unroll
        for (int i = 0; i < 2; ++i) {
            int row = row0 + r0 + i;           // row = rr*3 + l
            int rr = row / 3, l = row % 3;
            float vd = __expf(-lambs[l] * (nowv - vlast[rr]));
            #pragma unroll
            for (int j = 0; j < 2; ++j) {
                float v = lky(acc[i][j] + b2[c0 + j]);
                int m = c0 + j;
                vembT[(size_t)(l * 64 + m) * 224 + rr] =
                    f2bf(vmem[(long)rr * 192 + l * 64 + m] * vd + v);
            }
        }
    }
}

// ---------------- new_mem -> node_emb (bf16) ----------------
__global__ void k_newmem(const float* __restrict__ memory,
        const unsigned short* __restrict__ msg_feat,
        const float* __restrict__ cnt3, const float* __restrict__ t_max,
        const float* __restrict__ last_update, const int* __restrict__ has_msg,
        const float* __restrict__ lambs, unsigned short* __restrict__ node_emb, int N) {
    int n = blockIdx.x;
    int j = threadIdx.x;                 // 0..191
    int l = j >> 6, m = j & 63;
    int has = has_msg[n];
    float dt = has ? (t_max[n] - last_update[n]) : 0.f;
    float decay = __expf(-lambs[l] * dt);
    long mb = (long)n * 195 + l * 65;
    float num = memory[mb + m];
    float den = memory[mb + 64];
    if (has) {
        num = num * decay + bf2f(msg_feat[(size_t)n * 192 + j]);
        den = den * decay + cnt3[(size_t)n * 3 + l];
    }
    node_emb[(size_t)n * 192 + j] = f2bf(num / fmaxf(den, 1e-6f));
}

// ---------------- vnode_emb = row-softmax(A_r) @ v_emb via MFMA ----------------
__global__ __launch_bounds__(256) void k_vnode_mfma(
        const unsigned short* __restrict__ Aexp_rm, const unsigned short* __restrict__ vembT,
        const float* __restrict__ rowsum, unsigned short* __restrict__ vnode_emb, int N) {
    __shared__ unsigned short As[64 * 232];
    __shared__ float sRS[64];
    int t = threadIdx.x, lane = t & 63, w = t >> 6;
    int lr = lane & 15, kg = lane >> 4;
    int row0 = blockIdx.x * 64;
    {
        int r = t >> 2, sg = t & 3;
        const uint4* src = (const uint4*)(Aexp_rm + (size_t)(row0 + r) * 224 + sg * 56);
        uint4* dst = (uint4*)(As + r * 232 + sg * 56);
        #pragma unroll
        for (int u = 0; u < 7; ++u) dst[u] = src[u];
    }
    if (t < 64) sRS[t] = rowsum[min(row0 + t, N - 1)];
    __syncthreads();
    int n0 = w * 48;                      // 192 cols / 4 waves
    f32x4 acc[4][3];
    #pragma unroll
    for (int m = 0; m < 4; ++m)
        #pragma unroll
        for (int nt = 0; nt < 3; ++nt) acc[m][nt] = (f32x4){0.f, 0.f, 0.f, 0.f};
    for (int kk = 0; kk < 7; ++kk) {
        short8 bf[3];
        #pragma unroll
        for (int nt = 0; nt < 3; ++nt)
            bf[nt] = *(const short8*)(vembT + (size_t)(n0 + nt * 16 + lr) * 224 + kk * 32 + kg * 8);
        #pragma unroll
        for (int m = 0; m < 4; ++m) {
            short8 af = *(const short8*)(As + (m * 16 + lr) * 232 + kk * 32 + kg * 8);
            #pragma unroll
            for (int nt = 0; nt < 3; ++nt)
                acc[m][nt] = __builtin_amdgcn_mfma_f32_16x16x32_bf16(af, bf[nt], acc[m][nt], 0, 0, 0);
        }
    }
    #pragma unroll
    for (int m = 0; m < 4; ++m)
        #pragma unroll
        for (int j = 0; j < 4; ++j) {
            int row = row0 + m * 16 + kg * 4 + j;
            if (row < N) {
                float inv = 1.f / sRS[row - row0];
                #pragma unroll
                for (int nt = 0; nt < 3; ++nt)
                    vnode_emb[(size_t)row * 192 + n0 + nt * 16 + lr] = f2bf(acc[m][nt][j] * inv);
            }
        }
}

// ---------------- et + st + output blend via MFMA ----------------
__global__ __launch_bounds__(256) void k_et_st_mfma(
        const unsigned short* __restrict__ ne, const unsigned short* __restrict__ ve,
        const unsigned short* __restrict__ etWT, const float* __restrict__ etb,
        const unsigned short* __restrict__ stWT, const float* __restrict__ stb,
        const float* __restrict__ stat, const float* __restrict__ lamb,
        float* __restrict__ out, int N) {
    __shared__ unsigned short As[128 * 200];   // rows 0-63: node, 64-127: vnode
    __shared__ unsigned short Hs[64 * 136];    // st input [64 rows][128 cols]
    int t = threadIdx.x, lane = t & 63, w = t >> 6;
    int lr = lane & 15, kg = lane >> 4;
    int row0 = blockIdx.x * 64;
    {
        int r = t >> 2, sg = t & 3;
        const uint4* sn = (const uint4*)(ne + (size_t)(row0 + r) * 192 + sg * 48);
        const uint4* sv = (const uint4*)(ve + (size_t)(row0 + r) * 192 + sg * 48);
        uint4* dn = (uint4*)(As + (size_t)r * 200 + sg * 48);
        uint4* dv = (uint4*)(As + (size_t)(64 + r) * 200 + sg * 48);
        #pragma unroll
        for (int u = 0; u < 6; ++u) { dn[u] = sn[u]; dv[u] = sv[u]; }
    }
    __syncthreads();
    // et layer: wave w -> cols [w*16, w*16+16), both halves; K=192
    int c0 = w * 16;
    f32x4 acc[2][4];
    #pragma unroll
    for (int h = 0; h < 2; ++h)
        #pragma unroll
        for (int m = 0; m < 4; ++m) acc[h][m] = (f32x4){0.f, 0.f, 0.f, 0.f};
    for (int kk = 0; kk < 6; ++kk) {
        short8 bf = *(const short8*)(etWT + (size_t)(c0 + lr) * 192 + kk * 32 + kg * 8);
        #pragma unroll
        for (int h = 0; h < 2; ++h)
            #pragma unroll
            for (int m = 0; m < 4; ++m) {
                short8 af = *(const short8*)(As + (size_t)(h * 64 + m * 16 + lr) * 200 + kk * 32 + kg * 8);
                acc[h][m] = __builtin_amdgcn_mfma_f32_16x16x32_bf16(af, bf, acc[h][m], 0, 0, 0);
            }
    }
    float bb = etb[c0 + lr];
    #pragma unroll
    for (int h = 0; h < 2; ++h)
        #pragma unroll
        for (int m = 0; m < 4; ++m)
            #pragma unroll
            for (int j = 0; j < 4; ++j)
                Hs[(m * 16 + kg * 4 + j) * 136 + h * 64 + c0 + lr] = f2bf(lky(acc[h][m][j] + bb));
    __syncthreads();
    // st layer: wave w -> cols [w*32, w*32+32); K=128
    int c0s = w * 32;
    f32x4 a2[4][2];
    #pragma unroll
    for (int m = 0; m < 4; ++m) { a2[m][0] = (f32x4){0.f,0.f,0.f,0.f}; a2[m][1] = (f32x4){0.f,0.f,0.f,0.f}; }
    for (int kk = 0; kk < 4; ++kk) {
        short8 bf0 = *(const short8*)(stWT + (size_t)(c0s + lr) * 128 + kk * 32 + kg * 8);
        short8 bf1 = *(const short8*)(stWT + (size_t)(c0s + 16 + lr) * 128 + kk * 32 + kg * 8);
        #pragma unroll
        for (int m = 0; m < 4; ++m) {
            short8 af = *(const short8*)(Hs + (m * 16 + lr) * 136 + kk * 32 + kg * 8);
            a2[m][0] = __builtin_amdgcn_mfma_f32_16x16x32_bf16(af, bf0, a2[m][0], 0, 0, 0);
            a2[m][1] = __builtin_amdgcn_mfma_f32_16x16x32_bf16(af, bf1, a2[m][1], 0, 0, 0);
        }
    }
    float lam = lamb[0];
    float sb0 = stb[c0s + lr], sb1 = stb[c0s + 16 + lr];
    #pragma unroll
    for (int m = 0; m < 4; ++m)
        #pragma unroll
        for (int j = 0; j < 4; ++j) {
            int n = row0 + m * 16 + kg * 4 + j;
            if (n < N) {
                int ca = c0s + lr, cb = c0s + 16 + lr;
                float va = lky(a2[m][0][j] + sb0);
                float vb = lky(a2[m][1][j] + sb1);
                out[(size_t)n * 128 + ca] = lam * stat[(size_t)n * 128 + ca] + (1.f - lam) * va;
                out[(size_t)n * 128 + cb] = lam * stat[(size_t)n * 128 + cb] + (1.f - lam) * vb;
            }
        }
}

extern "C" void kernel_launch(void* const* d_in, const int* in_sizes, int n_in,
                              void* d_out, int out_size, void* d_ws, size_t ws_size,
                              hipStream_t stream) {
    const int*   src        = (const int*)d_in[0];
    const int*   tgt        = (const int*)d_in[1];
    const float* ts         = (const float*)d_in[2];
    const float* now_time   = (const float*)d_in[3];
    const float* nodef      = (const float*)d_in[5];
    const float* memory     = (const float*)d_in[6];
    const float* last_upd   = (const float*)d_in[7];
    const float* vmem       = (const float*)d_in[8];
    const float* vlast      = (const float*)d_in[9];
    const float* A_r        = (const float*)d_in[10];
    const float* static_emb = (const float*)d_in[11];
    const float* lamb       = (const float*)d_in[12];
    const float* lambs      = (const float*)d_in[13];
    const float* mf_W1      = (const float*)d_in[14];
    const float* mf_b1      = (const float*)d_in[15];
    const float* mf_W2      = (const float*)d_in[16];
    const float* mf_b2      = (const float*)d_in[17];
    const float* ffr_W1     = (const float*)d_in[18];
    const float* ffr_b1     = (const float*)d_in[19];
    const float* ffr_W2     = (const float*)d_in[20];
    const float* ffr_b2     = (const float*)d_in[21];
    const float* et_W       = (const float*)d_in[22];
    const float* et_b       = (const float*)d_in[23];
    const float* st_W       = (const float*)d_in[24];
    const float* st_b       = (const float*)d_in[25];

    int E = in_sizes[0];
    int N = in_sizes[7];

    float* ws = (float*)d_ws;
    size_t off = 0;
    auto alloc = [&](size_t nf) { float* p = ws + off; off += (nf + 63) & ~(size_t)63; return p; };
    unsigned short* aggb  = (unsigned short*)alloc((size_t)SN * 384);     // SN*3 rows x 256 bf16
    unsigned short* msg_feat = (unsigned short*)alloc((size_t)N * 96);    // bf16
    unsigned short* AexpT   = (unsigned short*)alloc((size_t)224 * SN / 2);
    unsigned short* Aexp_rm = (unsigned short*)alloc((size_t)SN * 224 / 2);
    float* tv_union = alloc((size_t)VCM * 172032);      // temb (N*128) then vpart (VCM*172032)
    float* vmid     = alloc(224 * 768);
    unsigned short* vembT = (unsigned short*)alloc((size_t)192 * 224 / 2 + 64);
    float* t_max    = alloc(N);
    float* rowsum   = alloc(N);
    float* cnt3     = alloc((size_t)SN * 3);
    float* colsum   = alloc(256);
    unsigned short* W1T  = (unsigned short*)alloc(128 * 256 / 2);
    unsigned short* W2T  = (unsigned short*)alloc(64 * 128 / 2);
    unsigned short* etWT = (unsigned short*)alloc(64 * 192 / 2);
    unsigned short* stWT = (unsigned short*)alloc(128 * 128 / 2);
    int*   cnt      = (int*)alloc(N);
    int*   offsets  = (int*)alloc(N + 1);
    int*   cursor   = (int*)alloc(N);
    int*   sorted   = (int*)alloc(E);
    int*   has_msg  = (int*)alloc(N);
    if (off * sizeof(float) > ws_size) return;   // workspace guard

    unsigned int* temb = (unsigned int*)tv_union;   // live: k_prep..k_agg
    float* vpart = tv_union;                        // live: k_vmid_mfma..k_vred
    // overlays: aggb region is dead after k_mf_mfma + k_vmid_mfma
    unsigned short* node_emb  = (unsigned short*)aggb;
    unsigned short* vnode_emb = node_emb + (size_t)N * 192;

    k_init<<<(N + 255) / 256, 256, 0, stream>>>(t_max, cnt, cursor, colsum, N);
    k_tbf<<<(256 * 128 + 255) / 256, 256, 0, stream>>>(mf_W1, W1T, 256, 128);
    k_tbf<<<(128 * 64 + 255) / 256, 256, 0, stream>>>(mf_W2, W2T, 128, 64);
    k_tbf<<<(192 * 64 + 255) / 256, 256, 0, stream>>>(et_W, etWT, 192, 64);
    k_tbf<<<(128 * 128 + 255) / 256, 256, 0, stream>>>(st_W, stWT, 128, 128);
    k_tmax_cnt<<<(E + 255) / 256, 256, 0, stream>>>(src, ts, t_max, cnt, E);
    k_scan<<<1, 1024, 0, stream>>>(cnt, offsets, N);
    k_scatter<<<(E + 255) / 256, 256, 0, stream>>>(src, offsets, cursor, sorted, E);
    k_prep<<<(N + 3) / 4, 256, 0, stream>>>(memory, nodef, temb, N);
    k_aexp<<<SN / 64, 256, 0, stream>>>(A_r, rowsum, colsum, AexpT, Aexp_rm, N);
    k_agg<<<SN / 4, 256, 0, stream>>>(tgt, ts, sorted, offsets, t_max, temb,
                                      lambs, (unsigned int*)aggb, cnt3, has_msg, N);
    k_mf_mfma<<<SN * 3 / 64, 256, 0, stream>>>(aggb, W1T, mf_b1, W2T, mf_b2, msg_feat, N * 3);
    k_vmid_mfma<<<12 * VCM, 256, 0, stream>>>(AexpT, aggb, cnt3, vpart);
    k_vred<<<(224 * 768 + 255) / 256, 256, 0, stream>>>(vpart, colsum, vmid);
    k_ffr<<<42, 256, 0, stream>>>(vmid, ffr_W1, ffr_b1, ffr_W2, ffr_b2, vmem, vlast,
                                  lambs, now_time, vembT);
    k_newmem<<<N, 192, 0, stream>>>(memory, msg_feat, cnt3, t_max, last_upd, has_msg,
                                    lambs, node_emb, N);
    k_vnode_mfma<<<SN / 64, 256, 0, stream>>>(Aexp_rm, vembT, rowsum, vnode_emb, N);
    k_et_st_mfma<<<SN / 64, 256, 0, stream>>>(node_emb, vnode_emb, etWT, et_b, stWT, st_b,
                                              static_emb, lamb, (float*)d_out, N);
}

// Round 7
// 384.976 us; speedup vs baseline: 3.8539x; 1.1043x over previous
//
#include <hip/hip_runtime.h>

static __device__ __forceinline__ float lky(float x) { return x > 0.f ? x : 0.01f * x; }

static __device__ __forceinline__ unsigned short f2bf(float x) {
    unsigned int u = __float_as_uint(x);
    unsigned int r = (u + 0x7FFFu + ((u >> 16) & 1u)) >> 16;
    return (unsigned short)r;
}
static __device__ __forceinline__ float bf2f(unsigned short x) {
    return __uint_as_float((unsigned int)x << 16);
}
static __device__ __forceinline__ unsigned int pack2bf(float lo, float hi) {
    return (unsigned int)f2bf(lo) | ((unsigned int)f2bf(hi) << 16);
}

typedef __attribute__((ext_vector_type(8))) short short8;
typedef __attribute__((ext_vector_type(4))) float f32x4;

constexpr int SN  = 50048;   // padded node count (multiple of 64)
constexpr int KLV = 608;     // K(nodes) per split-K chunk (multiple of 32)
constexpr int VCM = 83;      // ceil(SN/KLV)
constexpr int NSCAN = 53248; // 13 * 4096, scan padding

// ---------------- init ----------------
__global__ void k_init(float* t_max, int* cnt, int* cursor, float* colsum, int N, int NP) {
    int i = blockIdx.x * 256 + threadIdx.x;
    if (i < N) { t_max[i] = -1.0f; cursor[i] = 0; }
    if (i < NP) cnt[i] = 0;
    if (i < 224) colsum[i] = 0.0f;
}

// ---------------- weight transpose to bf16: dst[c*K+k] = src[k*C+c] ----------------
__global__ void k_tbf(const float* __restrict__ src, unsigned short* __restrict__ dst,
                      int K, int C) {
    int i = blockIdx.x * 256 + threadIdx.x;
    if (i >= K * C) return;
    int c = i / K, k = i % K;
    dst[i] = f2bf(src[k * C + c]);
}

// ---------------- per-edge t_max / counts ----------------
__global__ void k_tmax_cnt(const int* __restrict__ src, const float* __restrict__ ts,
                           float* t_max, int* cnt, int E) {
    int e = blockIdx.x * 256 + threadIdx.x;
    if (e >= E) return;
    int s = src[e];
    atomicMax((int*)(t_max + s), __float_as_int(ts[e]));   // ts >= 0, int-monotone
    atomicAdd(cnt + s, 1);
}

// ---------------- exclusive scan over counts (single block, 4096/iter) ----------------
__global__ __launch_bounds__(1024) void k_scan(const int* __restrict__ cnt,
                                               int* __restrict__ offsets, int N) {
    __shared__ int wsum[16];
    __shared__ int s_run;
    int t = threadIdx.x;
    int lane = t & 63, wid = t >> 6;
    if (t == 0) s_run = 0;
    __syncthreads();
    int nchunk = (N + 4095) >> 12;
    for (int c = 0; c < nchunk; ++c) {
        int i0 = (c << 12) + t * 4;
        int4 v = *(const int4*)(cnt + i0);     // cnt zero-padded to NSCAN
        int s = v.x + v.y + v.z + v.w;
        int x = s;
        #pragma unroll
        for (int d = 1; d < 64; d <<= 1) {
            int y = __shfl_up(x, d, 64);
            if (lane >= d) x += y;
        }
        if (lane == 63) wsum[wid] = x;
        __syncthreads();
        int wbase = 0;
        #pragma unroll
        for (int w = 0; w < 16; ++w) wbase += (w < wid) ? wsum[w] : 0;
        int run = s_run;
        int base = run + wbase + x - s;
        if (i0 + 3 < N) {
            int4 o;
            o.x = base; o.y = base + v.x; o.z = o.y + v.y; o.w = o.z + v.z;
            *(int4*)(offsets + i0) = o;
        } else {
            int o = base;
            if (i0 < N) offsets[i0] = o;
            o += v.x;
            if (i0 + 1 < N) offsets[i0 + 1] = o;
            o += v.y;
            if (i0 + 2 < N) offsets[i0 + 2] = o;
            o += v.z;
            if (i0 + 3 < N) offsets[i0 + 3] = o;
        }
        __syncthreads();
        if (t == 1023) s_run = run + wbase + x;
        __syncthreads();
    }
    if (t == 0) offsets[N] = s_run;
}

// ---------------- scatter edges into per-node buckets ----------------
__global__ void k_scatter(const int* __restrict__ src, const int* __restrict__ offsets,
                          int* cursor, int* sorted, int E) {
    int e = blockIdx.x * 256 + threadIdx.x;
    if (e >= E) return;
    int s = src[e];
    int pos = offsets[s] + atomicAdd(cursor + s, 1);
    sorted[pos] = e;
}

// ---------------- precompute normalized target embedding, bf16 [N][256] ----------------
__global__ __launch_bounds__(256) void k_prep(
        const float* __restrict__ memory, const float* __restrict__ nodef,
        unsigned int* __restrict__ temb, int N) {
    int wid = threadIdx.x >> 6, lane = threadIdx.x & 63;
    int n = blockIdx.x * 4 + wid;
    if (n >= N) return;
    const float* mrow = memory + (size_t)n * 195;
    float d0 = mrow[64], d1 = mrow[129], d2 = mrow[194];
    int f = 2 * lane;
    float den = (f < 64) ? d0 : d1;
    int offA = (f < 64) ? f : f + 1;
    float va0 = mrow[offA] / den;
    float va1 = mrow[offA + 1] / den;
    float vb0, vb1;
    if (lane < 32) {
        vb0 = mrow[130 + 2 * lane] / d2;
        vb1 = mrow[131 + 2 * lane] / d2;
    } else {
        const float* nf = nodef + (size_t)n * 64 + 2 * (lane - 32);
        vb0 = nf[0]; vb1 = nf[1];
    }
    temb[(size_t)n * 128 + lane]      = pack2bf(va0, va1);
    temb[(size_t)n * 128 + 64 + lane] = pack2bf(vb0, vb1);
}

// ---------------- A_r pass: rowsum, colsum, bf16 Aexp_rm + AexpT (throughput form) ----------------
__global__ __launch_bounds__(256) void k_aexp(
        const float* __restrict__ A_r,
        float* __restrict__ rowsum, float* __restrict__ colsum,
        unsigned short* __restrict__ AexpT, unsigned short* __restrict__ Aexp_rm, int N) {
    __shared__ unsigned short sE[64][228];   // 456B row stride: 8B-aligned, ~2-way banks
    int t = threadIdx.x;
    int n0 = blockIdx.x * 64;
    int maxq = min(64, N - n0) * 56;
    const float4* src = (const float4*)(A_r + (size_t)n0 * 224);
    #pragma unroll
    for (int k = 0; k < 14; ++k) {
        int i = t + k * 256;
        float4 v = (i < maxq) ? src[i] : (float4){-1e30f, -1e30f, -1e30f, -1e30f};
        int row = i / 56, cq = i % 56;
        uint2 pk;
        pk.x = pack2bf(__expf(v.x), __expf(v.y));
        pk.y = pack2bf(__expf(v.z), __expf(v.w));
        *(uint2*)&sE[row][cq * 4] = pk;
    }
    __syncthreads();
    // rowsum: 4 threads per row, 2 shuffles
    {
        int row = t >> 2, q = t & 3;
        const uint2* p = (const uint2*)&sE[row][q * 56];
        float s = 0.f;
        #pragma unroll
        for (int c = 0; c < 7; ++c) {
            uint2 u = p[c];
            s += __uint_as_float(u.x << 16) + __uint_as_float(u.x & 0xffff0000u)
               + __uint_as_float(u.y << 16) + __uint_as_float(u.y & 0xffff0000u);
        }
        s += __shfl_xor(s, 1, 64);
        s += __shfl_xor(s, 2, 64);
        if (q == 0 && n0 + row < N) rowsum[n0 + row] = s;
    }
    // colsum partials
    if (t < 224) {
        float s = 0.f;
        #pragma unroll 8
        for (int r = 0; r < 64; ++r) s += bf2f(sE[r][t]);
        atomicAdd(colsum + t, s);
    }
    // row-major write, packed uints, coalesced
    {
        unsigned int* dst = (unsigned int*)Aexp_rm;
        for (int i = t; i < 64 * 112; i += 256) {
            int n = i / 112, cp = i % 112;
            dst[(size_t)(n0 + n) * 112 + cp] = *(const unsigned int*)&sE[n][2 * cp];
        }
    }
    // transposed write: wave-coalesced 128B runs per r-row
    {
        unsigned int* dst = (unsigned int*)AexpT;
        for (int u = t; u < 224 * 32; u += 256) {
            int r = u >> 5, np = u & 31;
            unsigned int lo = sE[2 * np][r];
            unsigned int hi = sE[2 * np + 1][r];
            dst[(size_t)r * (SN / 2) + (n0 >> 1) + np] = lo | (hi << 16);
        }
    }
}

// ---------------- per-node aggregation: one wave per node, bf16 temb gather ----------------
__global__ __launch_bounds__(256) void k_agg(
        const int* __restrict__ tgt, const float* __restrict__ ts,
        const int* __restrict__ sorted, const int* __restrict__ offsets,
        const float* __restrict__ t_max, const unsigned int* __restrict__ temb,
        const float* __restrict__ lambs,
        unsigned int* __restrict__ aggb, float* __restrict__ cnt3,
        int* __restrict__ has_msg, int N) {
    int wid = threadIdx.x >> 6, lane = threadIdx.x & 63;
    int n = blockIdx.x * 4 + wid;      // n < SN (grid = SN/4)
    size_t rb = (size_t)n * 3;
    if (n >= N) {                       // zero-fill padding rows
        #pragma unroll
        for (int l = 0; l < 3; ++l) {
            unsigned int* row = aggb + (rb + l) * 128;
            row[lane] = 0; row[64 + lane] = 0;
            if (lane == 0) cnt3[rb + l] = 0.f;
        }
        return;
    }
    int beg = offsets[n], end = offsets[n + 1];
    float lb0 = lambs[0], lb1 = lambs[1], lb2 = lambs[2];
    float tm = t_max[n];
    float aa0[3], aa1[3], ab0[3], ab1[3], accc[3];
    #pragma unroll
    for (int l = 0; l < 3; ++l) { aa0[l] = aa1[l] = ab0[l] = ab1[l] = accc[l] = 0.f; }
    for (int idx = beg; idx < end; ++idx) {
        int e = sorted[idx];
        int tt = tgt[e];
        float d = tm - ts[e];
        unsigned int ua = temb[(size_t)tt * 128 + lane];
        unsigned int ub = temb[(size_t)tt * 128 + 64 + lane];
        float a0 = __uint_as_float(ua << 16);
        float a1 = __uint_as_float(ua & 0xffff0000u);
        float b0 = __uint_as_float(ub << 16);
        float b1 = __uint_as_float(ub & 0xffff0000u);
        float w0 = __expf(-lb0 * d), w1 = __expf(-lb1 * d), w2 = __expf(-lb2 * d);
        aa0[0] += w0 * a0; aa1[0] += w0 * a1; ab0[0] += w0 * b0; ab1[0] += w0 * b1; accc[0] += w0;
        aa0[1] += w1 * a0; aa1[1] += w1 * a1; ab0[1] += w1 * b0; ab1[1] += w1 * b1; accc[1] += w1;
        aa0[2] += w2 * a0; aa1[2] += w2 * a1; ab0[2] += w2 * b0; ab1[2] += w2 * b1; accc[2] += w2;
    }
    #pragma unroll
    for (int l = 0; l < 3; ++l) {
        unsigned int* row = aggb + (rb + l) * 128;
        row[lane]      = pack2bf(aa0[l], aa1[l]);
        row[64 + lane] = pack2bf(ab0[l], ab1[l]);
        if (lane == 0) cnt3[rb + l] = accc[l];
    }
    if (lane == 0) has_msg[n] = (end > beg) ? 1 : 0;
}

// ---------------- mf MLP via MFMA: (3N,256) bf16 -> relu(128) -> relu(64) bf16 ----------------
__global__ __launch_bounds__(256) void k_mf_mfma(
        const unsigned short* __restrict__ aggb,
        const unsigned short* __restrict__ W1T, const float* __restrict__ b1,
        const unsigned short* __restrict__ W2T, const float* __restrict__ b2,
        unsigned short* __restrict__ msg_feat, int NROWS) {
    __shared__ unsigned short As[64 * 264];
    __shared__ unsigned short Hs[64 * 136];
    int t = threadIdx.x, lane = t & 63, w = t >> 6;
    int lr = lane & 15, kg = lane >> 4;
    int row0 = blockIdx.x * 64;
    {   // stage A: 64 rows x 256 bf16, 4 threads/row
        int r = t >> 2, s4 = t & 3;
        const uint4* src = (const uint4*)(aggb + (size_t)(row0 + r) * 256 + s4 * 64);
        uint4* dst = (uint4*)(As + r * 264 + s4 * 64);
        #pragma unroll
        for (int u = 0; u < 8; ++u) dst[u] = src[u];
    }
    __syncthreads();
    // layer 1: wave w -> cols [w*32, w*32+32)
    int n0 = w * 32;
    f32x4 acc[4][2];
    #pragma unroll
    for (int m = 0; m < 4; ++m) {
        acc[m][0] = (f32x4){0.f, 0.f, 0.f, 0.f};
        acc[m][1] = (f32x4){0.f, 0.f, 0.f, 0.f};
    }
    for (int kk = 0; kk < 8; ++kk) {
        short8 bf0 = *(const short8*)(W1T + (size_t)(n0 + lr) * 256 + kk * 32 + kg * 8);
        short8 bf1 = *(const short8*)(W1T + (size_t)(n0 + 16 + lr) * 256 + kk * 32 + kg * 8);
        #pragma unroll
        for (int m = 0; m < 4; ++m) {
            short8 af = *(const short8*)(As + (m * 16 + lr) * 264 + kk * 32 + kg * 8);
            acc[m][0] = __builtin_amdgcn_mfma_f32_16x16x32_bf16(af, bf0, acc[m][0], 0, 0, 0);
            acc[m][1] = __builtin_amdgcn_mfma_f32_16x16x32_bf16(af, bf1, acc[m][1], 0, 0, 0);
        }
    }
    float bb0 = b1[n0 + lr], bb1 = b1[n0 + 16 + lr];
    #pragma unroll
    for (int m = 0; m < 4; ++m)
        #pragma unroll
        for (int j = 0; j < 4; ++j) {
            int row = m * 16 + kg * 4 + j;
            Hs[row * 136 + n0 + lr]      = f2bf(fmaxf(acc[m][0][j] + bb0, 0.f));
            Hs[row * 136 + n0 + 16 + lr] = f2bf(fmaxf(acc[m][1][j] + bb1, 0.f));
        }
    __syncthreads();
    // layer 2: wave w -> cols [w*16, w*16+16)
    int c0 = w * 16;
    f32x4 a2[4];
    #pragma unroll
    for (int m = 0; m < 4; ++m) a2[m] = (f32x4){0.f, 0.f, 0.f, 0.f};
    for (int kk = 0; kk < 4; ++kk) {
        short8 bf = *(const short8*)(W2T + (size_t)(c0 + lr) * 128 + kk * 32 + kg * 8);
        #pragma unroll
        for (int m = 0; m < 4; ++m) {
            short8 af = *(const short8*)(Hs + (m * 16 + lr) * 136 + kk * 32 + kg * 8);
            a2[m] = __builtin_amdgcn_mfma_f32_16x16x32_bf16(af, bf, a2[m], 0, 0, 0);
        }
    }
    float b2v = b2[c0 + lr];
    #pragma unroll
    for (int m = 0; m < 4; ++m)
        #pragma unroll
        for (int j = 0; j < 4; ++j) {
            int row = row0 + m * 16 + kg * 4 + j;
            if (row < NROWS)
                msg_feat[(size_t)row * 64 + c0 + lr] = f2bf(fmaxf(a2[m][j] + b2v, 0.f));
        }
}

// ---------------- vmid via bf16 MFMA, split-K; B LDS-staged (transposed, XOR-swizzled) ----------------
__global__ __launch_bounds__(256) void k_vmid_mfma(
        const unsigned short* __restrict__ AexpT, const unsigned short* __restrict__ aggb,
        const float* __restrict__ cnt3, float* __restrict__ vpart) {
    __shared__ unsigned short As[112 * 40];   // 112 rows x 32 shorts (stride 40 = 80B, uniform banks)
    __shared__ unsigned int BsT[128 * 20];    // [col][np-uint] stride 20; np ^= ((col>>3)&3)<<2
    int bx = blockIdx.x;
    int chunk = bx / 12, tile = bx % 12;
    int r0 = (tile & 1) * 112;
    int ft = tile >> 1;                 // 0..5
    int l = ft >> 1, fo = (ft & 1) * 128;
    int t = threadIdx.x, lane = t & 63, w = t >> 6;
    int lr = lane & 15, kg = lane >> 4;
    int np = t >> 4, sg = t & 15;       // B staging: node-pair, col-segment(8 cols)
    f32x4 acc[7][2];
    #pragma unroll
    for (int q = 0; q < 7; ++q) {
        acc[q][0] = (f32x4){0.f, 0.f, 0.f, 0.f};
        acc[q][1] = (f32x4){0.f, 0.f, 0.f, 0.f};
    }
    int nbeg = chunk * KLV;
    int nsteps = min(KLV, SN - nbeg) >> 5;
    int c0 = w * 32 + lr, c1 = c0 + 16;
    int rb0 = c0 * 20 + (kg ^ ((c0 >> 3) & 3)) * 4;
    int rb1 = c1 * 20 + (kg ^ ((c1 >> 3) & 3)) * 4;
    int swz = np ^ ((sg & 3) << 2);
    for (int s = 0; s < nsteps; ++s) {
        int n0 = nbeg + s * 32;
        if (t < 224) {                   // stage A: 2 threads/row, 32 shorts/row
            int srow = t >> 1, sseg = t & 1;
            const uint4* ap = (const uint4*)(AexpT + (size_t)(r0 + srow) * SN + n0) + sseg * 2;
            uint4 v0 = ap[0];
            uint4 v1 = ap[1];
            *(uint4*)&As[srow * 40 + sseg * 16]     = v0;
            *(uint4*)&As[srow * 40 + sseg * 16 + 8] = v1;
        }
        {   // stage B: nodes (2np, 2np+1) x cols [sg*8, sg*8+8), scaled by 1/den, k-pair packed
            int na = n0 + 2 * np;
            size_t ra = ((size_t)na * 3 + l) * 256 + fo + sg * 8;
            uint4 va = *(const uint4*)(aggb + ra);
            uint4 vb = *(const uint4*)(aggb + ra + 768);
            float da = 1.f / fmaxf(cnt3[(size_t)na * 3 + l], 1e-6f);
            float db = 1.f / fmaxf(cnt3[(size_t)na * 3 + l + 3], 1e-6f);
            const unsigned short* pa = (const unsigned short*)&va;
            const unsigned short* pb = (const unsigned short*)&vb;
            unsigned int* dst = BsT + sg * 160 + swz;
            #pragma unroll
            for (int j = 0; j < 8; ++j)
                dst[j * 20] = pack2bf(bf2f(pa[j]) * da, bf2f(pb[j]) * db);
        }
        __syncthreads();
        short8 b0 = *(const short8*)((const unsigned short*)(BsT + rb0));
        short8 b1 = *(const short8*)((const unsigned short*)(BsT + rb1));
        #pragma unroll
        for (int q = 0; q < 7; ++q) {
            short8 af = *(const short8*)&As[(q * 16 + lr) * 40 + kg * 8];
            acc[q][0] = __builtin_amdgcn_mfma_f32_16x16x32_bf16(af, b0, acc[q][0], 0, 0, 0);
            acc[q][1] = __builtin_amdgcn_mfma_f32_16x16x32_bf16(af, b1, acc[q][1], 0, 0, 0);
        }
        __syncthreads();
    }
    float* outp = vpart + (size_t)chunk * 172032;
    #pragma unroll
    for (int q = 0; q < 7; ++q) {
        int row = r0 + q * 16 + kg * 4;
        #pragma unroll
        for (int p = 0; p < 2; ++p) {
            int col = l * 256 + fo + w * 32 + p * 16 + lr;
            #pragma unroll
            for (int j = 0; j < 4; ++j)
                outp[(size_t)(row + j) * 768 + col] = acc[q][p][j];
        }
    }
}

// ---------------- reduce vpart over chunks, divide by colsum ----------------
__global__ void k_vred(const float* __restrict__ vpart, const float* __restrict__ colsum,
                       float* __restrict__ vmid) {
    int idx = blockIdx.x * 256 + threadIdx.x;
    if (idx >= 224 * 768) return;
    float s = 0.f;
    for (int c = 0; c < VCM; ++c) s += vpart[(long)c * (224 * 768) + idx];
    vmid[idx] = s / colsum[idx / 768];
}

// ---------------- ffr MLP (672 rows) + virtual-memory decay -> vembT (bf16) ----------------
__global__ __launch_bounds__(256) void k_ffr(
        const float* __restrict__ vmid, const float* __restrict__ W1, const float* __restrict__ b1,
        const float* __restrict__ W2, const float* __restrict__ b2,
        const float* __restrict__ vmem, const float* __restrict__ vlast,
        const float* __restrict__ lambs, const float* __restrict__ now_time,
        unsigned short* __restrict__ vembT) {
    __shared__ float sin_[16][260];
    __shared__ float svh[16][260];
    int row0 = blockIdx.x * 16;
    int t = threadIdx.x;
    #pragma unroll
    for (int k = 0; k < 16; ++k) {
        int idx = t + k * 256;
        int r = idx >> 8, f = idx & 255;
        sin_[r][f] = vmid[(long)(row0 + r) * 256 + f];
    }
    __syncthreads();
    {   // layer 1: 16 x 256, 4r x 4c
        int cg = t & 63, rg = t >> 6;
        int c0 = cg * 4, r0 = rg * 4;
        float acc[4][4];
        #pragma unroll
        for (int i = 0; i < 4; ++i)
            #pragma unroll
            for (int j = 0; j < 4; ++j) acc[i][j] = 0.f;
        for (int f0 = 0; f0 < 256; f0 += 4) {
            float4 a[4];
            #pragma unroll
            for (int i = 0; i < 4; ++i) a[i] = *(const float4*)&sin_[r0 + i][f0];
            #pragma unroll
            for (int ff = 0; ff < 4; ++ff) {
                float4 w = *(const float4*)&W1[(long)(f0 + ff) * 256 + c0];
                #pragma unroll
                for (int i = 0; i < 4; ++i) {
                    float av = (&a[i].x)[ff];
                    acc[i][0] += av * w.x; acc[i][1] += av * w.y;
                    acc[i][2] += av * w.z; acc[i][3] += av * w.w;
                }
            }
        }
        #pragma unroll
        for (int i = 0; i < 4; ++i)
            #pragma unroll
            for (int j = 0; j < 4; ++j)
                svh[r0 + i][c0 + j] = lky(acc[i][j] + b1[c0 + j]);
    }
    __syncthreads();
    {   // layer 2: 16 x 64, 2r x 2c + decay epilogue
        int cg = t & 31, rg = t >> 5;
        int c0 = cg * 2, r0 = rg * 2;
        float acc[2][2];
        acc[0][0] = acc[0][1] = acc[1][0] = acc[1][1] = 0.f;
        for (int f0 = 0; f0 < 256; f0 += 4) {
            float4 a[2];
            #pragma unroll
            for (int i = 0; i < 2; ++i) a[i] = *(const float4*)&svh[r0 + i][f0];
            #pragma unroll
            for (int ff = 0; ff < 4; ++ff) {
                float2 w = *(const float2*)&W2[(long)(f0 + ff) * 64 + c0];
                #pragma unroll
                for (int i = 0; i < 2; ++i) {
                    float av = (&a[i].x)[ff];
                    acc[i][0] += av * w.x; acc[i][1] += av * w.y;
                }
            }
        }
        float nowv = now_time[0];
        #pragma unroll
        for (int i = 0; i < 2; ++i) {
            int row = row0 + r0 + i;           // row = rr*3 + l
            int rr = row / 3, l = row % 3;
            float vd = __expf(-lambs[l] * (nowv - vlast[rr]));
            #pragma unroll
            for (int j = 0; j < 2; ++j) {
                float v = lky(acc[i][j] + b2[c0 + j]);
                int m = c0 + j;
                vembT[(size_t)(l * 64 + m) * 224 + rr] =
                    f2bf(vmem[(long)rr * 192 + l * 64 + m] * vd + v);
            }
        }
    }
}

// ---------------- new_mem -> node_emb (bf16) ----------------
__global__ void k_newmem(const float* __restrict__ memory,
        const unsigned short* __restrict__ msg_feat,
        const float* __restrict__ cnt3, const float* __restrict__ t_max,
        const float* __restrict__ last_update, const int* __restrict__ has_msg,
        const float* __restrict__ lambs, unsigned short* __restrict__ node_emb, int N) {
    int n = blockIdx.x;
    int j = threadIdx.x;                 // 0..191
    int l = j >> 6, m = j & 63;
    int has = has_msg[n];
    float dt = has ? (t_max[n] - last_update[n]) : 0.f;
    float decay = __expf(-lambs[l] * dt);
    long mb = (long)n * 195 + l * 65;
    float num = memory[mb + m];
    float den = memory[mb + 64];
    if (has) {
        num = num * decay + bf2f(msg_feat[(size_t)n * 192 + j]);
        den = den * decay + cnt3[(size_t)n * 3 + l];
    }
    node_emb[(size_t)n * 192 + j] = f2bf(num / fmaxf(den, 1e-6f));
}

// ---------------- vnode_emb = row-softmax(A_r) @ v_emb via MFMA ----------------
__global__ __launch_bounds__(256) void k_vnode_mfma(
        const unsigned short* __restrict__ Aexp_rm, const unsigned short* __restrict__ vembT,
        const float* __restrict__ rowsum, unsigned short* __restrict__ vnode_emb, int N) {
    __shared__ unsigned short As[64 * 232];
    __shared__ float sRS[64];
    int t = threadIdx.x, lane = t & 63, w = t >> 6;
    int lr = lane & 15, kg = lane >> 4;
    int row0 = blockIdx.x * 64;
    {
        int r = t >> 2, sg = t & 3;
        const uint4* src = (const uint4*)(Aexp_rm + (size_t)(row0 + r) * 224 + sg * 56);
        uint4* dst = (uint4*)(As + r * 232 + sg * 56);
        #pragma unroll
        for (int u = 0; u < 7; ++u) dst[u] = src[u];
    }
    if (t < 64) sRS[t] = rowsum[min(row0 + t, N - 1)];
    __syncthreads();
    int n0 = w * 48;                      // 192 cols / 4 waves
    f32x4 acc[4][3];
    #pragma unroll
    for (int m = 0; m < 4; ++m)
        #pragma unroll
        for (int nt = 0; nt < 3; ++nt) acc[m][nt] = (f32x4){0.f, 0.f, 0.f, 0.f};
    for (int kk = 0; kk < 7; ++kk) {
        short8 bf[3];
        #pragma unroll
        for (int nt = 0; nt < 3; ++nt)
            bf[nt] = *(const short8*)(vembT + (size_t)(n0 + nt * 16 + lr) * 224 + kk * 32 + kg * 8);
        #pragma unroll
        for (int m = 0; m < 4; ++m) {
            short8 af = *(const short8*)(As + (m * 16 + lr) * 232 + kk * 32 + kg * 8);
            #pragma unroll
            for (int nt = 0; nt < 3; ++nt)
                acc[m][nt] = __builtin_amdgcn_mfma_f32_16x16x32_bf16(af, bf[nt], acc[m][nt], 0, 0, 0);
        }
    }
    #pragma unroll
    for (int m = 0; m < 4; ++m)
        #pragma unroll
        for (int j = 0; j < 4; ++j) {
            int row = row0 + m * 16 + kg * 4 + j;
            if (row < N) {
                float inv = 1.f / sRS[row - row0];
                #pragma unroll
                for (int nt = 0; nt < 3; ++nt)
                    vnode_emb[(size_t)row * 192 + n0 + nt * 16 + lr] = f2bf(acc[m][nt][j] * inv);
            }
        }
}

// ---------------- et + st + output blend via MFMA ----------------
__global__ __launch_bounds__(256) void k_et_st_mfma(
        const unsigned short* __restrict__ ne, const unsigned short* __restrict__ ve,
        const unsigned short* __restrict__ etWT, const float* __restrict__ etb,
        const unsigned short* __restrict__ stWT, const float* __restrict__ stb,
        const float* __restrict__ stat, const float* __restrict__ lamb,
        float* __restrict__ out, int N) {
    __shared__ unsigned short As[128 * 200];   // rows 0-63: node, 64-127: vnode
    __shared__ unsigned short Hs[64 * 136];    // st input [64 rows][128 cols]
    int t = threadIdx.x, lane = t & 63, w = t >> 6;
    int lr = lane & 15, kg = lane >> 4;
    int row0 = blockIdx.x * 64;
    {
        int r = t >> 2, sg = t & 3;
        const uint4* sn = (const uint4*)(ne + (size_t)(row0 + r) * 192 + sg * 48);
        const uint4* sv = (const uint4*)(ve + (size_t)(row0 + r) * 192 + sg * 48);
        uint4* dn = (uint4*)(As + (size_t)r * 200 + sg * 48);
        uint4* dv = (uint4*)(As + (size_t)(64 + r) * 200 + sg * 48);
        #pragma unroll
        for (int u = 0; u < 6; ++u) { dn[u] = sn[u]; dv[u] = sv[u]; }
    }
    __syncthreads();
    // et layer: wave w -> cols [w*16, w*16+16), both halves; K=192
    int c0 = w * 16;
    f32x4 acc[2][4];
    #pragma unroll
    for (int h = 0; h < 2; ++h)
        #pragma unroll
        for (int m = 0; m < 4; ++m) acc[h][m] = (f32x4){0.f, 0.f, 0.f, 0.f};
    for (int kk = 0; kk < 6; ++kk) {
        short8 bf = *(const short8*)(etWT + (size_t)(c0 + lr) * 192 + kk * 32 + kg * 8);
        #pragma unroll
        for (int h = 0; h < 2; ++h)
            #pragma unroll
            for (int m = 0; m < 4; ++m) {
                short8 af = *(const short8*)(As + (size_t)(h * 64 + m * 16 + lr) * 200 + kk * 32 + kg * 8);
                acc[h][m] = __builtin_amdgcn_mfma_f32_16x16x32_bf16(af, bf, acc[h][m], 0, 0, 0);
            }
    }
    float bb = etb[c0 + lr];
    #pragma unroll
    for (int h = 0; h < 2; ++h)
        #pragma unroll
        for (int m = 0; m < 4; ++m)
            #pragma unroll
            for (int j = 0; j < 4; ++j)
                Hs[(m * 16 + kg * 4 + j) * 136 + h * 64 + c0 + lr] = f2bf(lky(acc[h][m][j] + bb));
    __syncthreads();
    // st layer: wave w -> cols [w*32, w*32+32); K=128
    int c0s = w * 32;
    f32x4 a2[4][2];
    #pragma unroll
    for (int m = 0; m < 4; ++m) { a2[m][0] = (f32x4){0.f,0.f,0.f,0.f}; a2[m][1] = (f32x4){0.f,0.f,0.f,0.f}; }
    for (int kk = 0; kk < 4; ++kk) {
        short8 bf0 = *(const short8*)(stWT + (size_t)(c0s + lr) * 128 + kk * 32 + kg * 8);
        short8 bf1 = *(const short8*)(stWT + (size_t)(c0s + 16 + lr) * 128 + kk * 32 + kg * 8);
        #pragma unroll
        for (int m = 0; m < 4; ++m) {
            short8 af = *(const short8*)(Hs + (m * 16 + lr) * 136 + kk * 32 + kg * 8);
            a2[m][0] = __builtin_amdgcn_mfma_f32_16x16x32_bf16(af, bf0, a2[m][0], 0, 0, 0);
            a2[m][1] = __builtin_amdgcn_mfma_f32_16x16x32_bf16(af, bf1, a2[m][1], 0, 0, 0);
        }
    }
    float lam = lamb[0];
    float sb0 = stb[c0s + lr], sb1 = stb[c0s + 16 + lr];
    #pragma unroll
    for (int m = 0; m < 4; ++m)
        #pragma unroll
        for (int j = 0; j < 4; ++j) {
            int n = row0 + m * 16 + kg * 4 + j;
            if (n < N) {
                int ca = c0s + lr, cb = c0s + 16 + lr;
                float va = lky(a2[m][0][j] + sb0);
                float vb = lky(a2[m][1][j] + sb1);
                out[(size_t)n * 128 + ca] = lam * stat[(size_t)n * 128 + ca] + (1.f - lam) * va;
                out[(size_t)n * 128 + cb] = lam * stat[(size_t)n * 128 + cb] + (1.f - lam) * vb;
            }
        }
}

extern "C" void kernel_launch(void* const* d_in, const int* in_sizes, int n_in,
                              void* d_out, int out_size, void* d_ws, size_t ws_size,
                              hipStream_t stream) {
    const int*   src        = (const int*)d_in[0];
    const int*   tgt        = (const int*)d_in[1];
    const float* ts         = (const float*)d_in[2];
    const float* now_time   = (const float*)d_in[3];
    const float* nodef      = (const float*)d_in[5];
    const float* memory     = (const float*)d_in[6];
    const float* last_upd   = (const float*)d_in[7];
    const float* vmem       = (const float*)d_in[8];
    const float* vlast      = (const float*)d_in[9];
    const float* A_r        = (const float*)d_in[10];
    const float* static_emb = (const float*)d_in[11];
    const float* lamb       = (const float*)d_in[12];
    const float* lambs      = (const float*)d_in[13];
    const float* mf_W1      = (const float*)d_in[14];
    const float* mf_b1      = (const float*)d_in[15];
    const float* mf_W2      = (const float*)d_in[16];
    const float* mf_b2      = (const float*)d_in[17];
    const float* ffr_W1     = (const float*)d_in[18];
    const float* ffr_b1     = (const float*)d_in[19];
    const float* ffr_W2     = (const float*)d_in[20];
    const float* ffr_b2     = (const float*)d_in[21];
    const float* et_W       = (const float*)d_in[22];
    const float* et_b       = (const float*)d_in[23];
    const float* st_W       = (const float*)d_in[24];
    const float* st_b       = (const float*)d_in[25];

    int E = in_sizes[0];
    int N = in_sizes[7];

    float* ws = (float*)d_ws;
    size_t off = 0;
    auto alloc = [&](size_t nf) { float* p = ws + off; off += (nf + 63) & ~(size_t)63; return p; };
    unsigned short* aggb  = (unsigned short*)alloc((size_t)SN * 384);     // SN*3 rows x 256 bf16
    unsigned short* msg_feat = (unsigned short*)alloc((size_t)N * 96);    // bf16
    unsigned short* AexpT   = (unsigned short*)alloc((size_t)224 * SN / 2);
    unsigned short* Aexp_rm = (unsigned short*)alloc((size_t)SN * 224 / 2);
    float* tv_union = alloc((size_t)VCM * 172032);      // temb (N*128) then vpart (VCM*172032)
    float* vmid     = alloc(224 * 768);
    unsigned short* vembT = (unsigned short*)alloc((size_t)192 * 224 / 2 + 64);
    float* t_max    = alloc(N);
    float* rowsum   = alloc(N);
    float* cnt3     = alloc((size_t)SN * 3);
    float* colsum   = alloc(256);
    unsigned short* W1T  = (unsigned short*)alloc(128 * 256 / 2);
    unsigned short* W2T  = (unsigned short*)alloc(64 * 128 / 2);
    unsigned short* etWT = (unsigned short*)alloc(64 * 192 / 2);
    unsigned short* stWT = (unsigned short*)alloc(128 * 128 / 2);
    int*   cnt      = (int*)alloc(NSCAN);               // padded+zeroed for int4 scan
    int*   offsets  = (int*)alloc(N + 1);
    int*   cursor   = (int*)alloc(N);
    int*   sorted   = (int*)alloc(E);
    int*   has_msg  = (int*)alloc(N);
    if (off * sizeof(float) > ws_size) return;   // workspace guard

    unsigned int* temb = (unsigned int*)tv_union;   // live: k_prep..k_agg
    float* vpart = tv_union;                        // live: k_vmid_mfma..k_vred
    // overlays: aggb region is dead after k_mf_mfma + k_vmid_mfma
    unsigned short* node_emb  = (unsigned short*)aggb;
    unsigned short* vnode_emb = node_emb + (size_t)N * 192;

    k_init<<<(NSCAN + 255) / 256, 256, 0, stream>>>(t_max, cnt, cursor, colsum, N, NSCAN);
    k_tbf<<<(256 * 128 + 255) / 256, 256, 0, stream>>>(mf_W1, W1T, 256, 128);
    k_tbf<<<(128 * 64 + 255) / 256, 256, 0, stream>>>(mf_W2, W2T, 128, 64);
    k_tbf<<<(192 * 64 + 255) / 256, 256, 0, stream>>>(et_W, etWT, 192, 64);
    k_tbf<<<(128 * 128 + 255) / 256, 256, 0, stream>>>(st_W, stWT, 128, 128);
    k_tmax_cnt<<<(E + 255) / 256, 256, 0, stream>>>(src, ts, t_max, cnt, E);
    k_scan<<<1, 1024, 0, stream>>>(cnt, offsets, N);
    k_scatter<<<(E + 255) / 256, 256, 0, stream>>>(src, offsets, cursor, sorted, E);
    k_prep<<<(N + 3) / 4, 256, 0, stream>>>(memory, nodef, temb, N);
    k_aexp<<<SN / 64, 256, 0, stream>>>(A_r, rowsum, colsum, AexpT, Aexp_rm, N);
    k_agg<<<SN / 4, 256, 0, stream>>>(tgt, ts, sorted, offsets, t_max, temb,
                                      lambs, (unsigned int*)aggb, cnt3, has_msg, N);
    k_mf_mfma<<<SN * 3 / 64, 256, 0, stream>>>(aggb, W1T, mf_b1, W2T, mf_b2, msg_feat, N * 3);
    k_vmid_mfma<<<12 * VCM, 256, 0, stream>>>(AexpT, aggb, cnt3, vpart);
    k_vred<<<(224 * 768 + 255) / 256, 256, 0, stream>>>(vpart, colsum, vmid);
    k_ffr<<<42, 256, 0, stream>>>(vmid, ffr_W1, ffr_b1, ffr_W2, ffr_b2, vmem, vlast,
                                  lambs, now_time, vembT);
    k_newmem<<<N, 192, 0, stream>>>(memory, msg_feat, cnt3, t_max, last_upd, has_msg,
                                    lambs, node_emb, N);
    k_vnode_mfma<<<SN / 64, 256, 0, stream>>>(Aexp_rm, vembT, rowsum, vnode_emb, N);
    k_et_st_mfma<<<SN / 64, 256, 0, stream>>>(node_emb, vnode_emb, etWT, et_b, stWT, st_b,
                                              static_emb, lamb, (float*)d_out, N);
}